// Round 1
// baseline (1027.120 us; speedup 1.0000x reference)
//
#include <hip/hip_runtime.h>
#include <stdint.h>

#define NN 20000
#define NE 160000
#define NG 500
#define FIN 128
#define HID 512
#define NCLS 10

typedef __attribute__((ext_vector_type(8))) short short8;
typedef __attribute__((ext_vector_type(4))) float f32x4;
typedef __attribute__((ext_vector_type(4))) unsigned short ushort4v;

__device__ __forceinline__ float bf2f(unsigned int u){
  union{unsigned int i; float f;} x; x.i = u<<16; return x.f;
}
__device__ __forceinline__ unsigned short f2bf(float f){
  union{float f; unsigned int i;} x; x.f=f;
  unsigned int r = x.i + 0x7fffu + ((x.i>>16)&1u);
  return (unsigned short)(r>>16);
}

__device__ __forceinline__ void gload16(unsigned short* lds, const unsigned short* g){
  __builtin_amdgcn_global_load_lds((const __attribute__((address_space(1))) unsigned int*)g,
                                   (__attribute__((address_space(3))) unsigned int*)lds,
                                   16, 0, 0);
}

__global__ void sentinel_k(float* out){ out[0] = 12345.0f; }

// ---------------- weight transpose+cast: W[K][N] f32 -> Wt[N][K] bf16 ----------------
__global__ void w2bt(const float* __restrict__ W, unsigned short* __restrict__ Wt, int K, int Nn){
  int idx = blockIdx.x*blockDim.x + threadIdx.x;
  if (idx < K*Nn){
    int k = idx / Nn, n = idx - k*Nn;
    Wt[(size_t)n*K + k] = f2bf(W[idx]);
  }
}

// ---------------- BN stats: column sums + sumsq (atomic), optional per-row scale ----------------
__global__ void bnstats(const float* __restrict__ X, const float* __restrict__ scale, int sstride,
                        int M, int F, float* __restrict__ sums){
  int t = threadIdx.x;
  int chunk = (M + gridDim.x - 1) / gridDim.x;
  int r0 = blockIdx.x*chunk, r1 = r0 + chunk; if (r1 > M) r1 = M;
  float s0=0.f, q0=0.f, s1=0.f, q1=0.f;
  for (int r=r0; r<r1; ++r){
    float sc = scale ? scale[(size_t)r*sstride] : 1.0f;
    if (t < F){ float v = X[(size_t)r*F + t]*sc; s0 += v; q0 += v*v; }
    if (F > 256){ float v = X[(size_t)r*F + t + 256]*sc; s1 += v; q1 += v*v; }
  }
  if (t < F){ atomicAdd(&sums[t], s0); atomicAdd(&sums[F+t], q0); }
  if (F > 256){ atomicAdd(&sums[t+256], s1); atomicAdd(&sums[F+t+256], q1); }
}

__global__ void bnfin(const float* __restrict__ sums, int M, int F, float* __restrict__ mstat){
  int c = blockIdx.x*blockDim.x + threadIdx.x;
  if (c < F){
    float m = sums[c] / (float)M;
    float v = sums[F+c] / (float)M - m*m;
    mstat[c] = m;
    mstat[F+c] = rsqrtf(v + 1e-5f);
  }
}

// ---------------- fused (scale)->BN->bf16 cast ----------------
__global__ void bncast(const float* __restrict__ X, const float* __restrict__ scale, int sstride,
                       const float* __restrict__ mstat, int M, int F, unsigned short* __restrict__ out){
  int idx = blockIdx.x*blockDim.x + threadIdx.x;
  int total4 = M*F/4;
  if (idx >= total4) return;
  int base = idx*4;
  int r = base / F;
  int c = base - r*F;
  float sc = scale ? scale[(size_t)r*sstride] : 1.0f;
  float4 v = *(const float4*)&X[base];
  ushort4v o;
  o[0] = f2bf((v.x*sc - mstat[c+0])*mstat[F+c+0] + 1e-4f);
  o[1] = f2bf((v.y*sc - mstat[c+1])*mstat[F+c+1] + 1e-4f);
  o[2] = f2bf((v.z*sc - mstat[c+2])*mstat[F+c+2] + 1e-4f);
  o[3] = f2bf((v.w*sc - mstat[c+3])*mstat[F+c+3] + 1e-4f);
  *(ushort4v*)&out[base] = o;
}

// ---------------- CSR build ----------------
__global__ void csr_count(const int* __restrict__ ei, int* __restrict__ cnt){
  int e = blockIdx.x*blockDim.x + threadIdx.x;
  if (e < NE) atomicAdd(&cnt[ei[e]], 1);
}

__global__ void scan_rowptr(const int* __restrict__ cnt, int* __restrict__ rowp, float* __restrict__ dis1){
  __shared__ int buf[1024];
  __shared__ int carry;
  const int t = threadIdx.x;
  if (t == 0){ carry = 0; rowp[0] = 0; }
  __syncthreads();
  for (int base=0; base<NN; base+=1024){
    int i = base + t;
    int v = 0;
    if (i < NN){ v = cnt[i] + 1; dis1[i] = rsqrtf((float)v); }
    buf[t] = v;
    __syncthreads();
    for (int off=1; off<1024; off<<=1){
      int xv = (t >= off) ? buf[t-off] : 0;
      __syncthreads();
      buf[t] += xv;
      __syncthreads();
    }
    if (i < NN) rowp[i+1] = carry + buf[t];
    __syncthreads();
    if (t == 0) carry += buf[1023];
    __syncthreads();
  }
}

__global__ void csr_fill(const int* __restrict__ ei, const int* __restrict__ rowp,
                         const int* __restrict__ cnt, int* __restrict__ fillc,
                         int* __restrict__ ccol, int* __restrict__ crow, int* __restrict__ ceid){
  int id = blockIdx.x*blockDim.x + threadIdx.x;
  if (id < NE){
    int r = ei[id], c = ei[NE + id];
    int pos = atomicAdd(&fillc[r], 1);
    int idx = rowp[r] + pos;
    ccol[idx] = c; crow[idx] = r; ceid[idx] = id;
  } else if (id < NE + NN){
    int i = id - NE;
    int idx = rowp[i] + cnt[i];     // self-loop gets the fixed last slot
    ccol[idx] = i; crow[idx] = i; ceid[idx] = -1;
  }
}

__global__ void w1_kernel(const int* __restrict__ crow, const int* __restrict__ ccol,
                          const float* __restrict__ dis1, float* __restrict__ w1){
  int j = blockIdx.x*blockDim.x + threadIdx.x;
  if (j < NE + NN) w1[j] = dis1[crow[j]] * dis1[ccol[j]];
}

// ---------------- attention ----------------
__global__ void att_node(const float* __restrict__ X, const float* __restrict__ nW,
                         const float* __restrict__ nb, const float* __restrict__ eW,
                         float* __restrict__ na, float* __restrict__ eab){
  int wv = blockIdx.x*4 + (threadIdx.x >> 6);
  int l = threadIdx.x & 63;
  if (wv >= NN) return;
  const float* xr = X + (size_t)wv*HID;
  float s0=0,s1=0,s2=0,s3=0,s4=0,s5=0;
#pragma unroll
  for (int j=0; j<8; ++j){
    int k = l*8 + j;
    float xv = xr[k];
    s0 += xv * nW[2*k];       s1 += xv * nW[2*k+1];
    s2 += xv * eW[2*k];       s3 += xv * eW[2*k+1];
    s4 += xv * eW[2*(512+k)]; s5 += xv * eW[2*(512+k)+1];
  }
  for (int m=1; m<64; m<<=1){
    s0 += __shfl_xor(s0,m); s1 += __shfl_xor(s1,m); s2 += __shfl_xor(s2,m);
    s3 += __shfl_xor(s3,m); s4 += __shfl_xor(s4,m); s5 += __shfl_xor(s5,m);
  }
  if (l == 0){
    float z0 = s0 + nb[0], z1 = s1 + nb[1];
    float mx = fmaxf(z0,z1);
    float e0 = expf(z0-mx), e1 = expf(z1-mx);
    float inv = 1.0f/(e0+e1);
    na[2*wv] = e0*inv; na[2*wv+1] = e1*inv;
    eab[4*wv] = s2; eab[4*wv+1] = s3; eab[4*wv+2] = s4; eab[4*wv+3] = s5;
  }
}

__global__ void fill1(float* __restrict__ a, float* __restrict__ b){
  int i = blockIdx.x*blockDim.x + threadIdx.x;
  if (i < NN){ a[i] = 1.0f; b[i] = 1.0f; }
}

__global__ void att_edge(const int* __restrict__ ei, const float* __restrict__ eab,
                         const float* __restrict__ eb, float* __restrict__ att,
                         float* __restrict__ degc, float* __restrict__ dego){
  int e = blockIdx.x*blockDim.x + threadIdx.x;
  if (e >= NE) return;
  int r = ei[e], c = ei[NE+e];
  float z0 = eab[4*r]   + eab[4*c+2] + eb[0];
  float z1 = eab[4*r+1] + eab[4*c+3] + eb[1];
  float mx = fmaxf(z0,z1);
  float e0 = expf(z0-mx), e1 = expf(z1-mx);
  float inv = 1.0f/(e0+e1);
  float a0 = e0*inv, a1 = e1*inv;
  att[2*e] = a0; att[2*e+1] = a1;
  atomicAdd(&degc[r], a0);
  atomicAdd(&dego[r], a1);
}

__global__ void wco_kernel(const int* __restrict__ crow, const int* __restrict__ ccol,
                           const int* __restrict__ ceid, const float* __restrict__ att,
                           const float* __restrict__ degc, const float* __restrict__ dego,
                           float* __restrict__ wcv, float* __restrict__ wov){
  int j = blockIdx.x*blockDim.x + threadIdx.x;
  if (j >= NE + NN) return;
  int r = crow[j], c = ccol[j], e = ceid[j];
  float a0 = (e < 0) ? 1.0f : att[2*e];
  float a1 = (e < 0) ? 1.0f : att[2*e+1];
  wcv[j] = rsqrtf(degc[r]) * a0 * rsqrtf(degc[c]);
  wov[j] = rsqrtf(dego[r]) * a1 * rsqrtf(dego[c]);
}

// ---------------- CSR aggregation: out[r] = sum_j w[j] * A[col[j]]  (bf16 in/out, f32 acc) ----------------
__global__ void aggregate(const unsigned short* __restrict__ A, const int* __restrict__ rowp,
                          const int* __restrict__ ccol, const float* __restrict__ wv,
                          unsigned short* __restrict__ out){
  int r = blockIdx.x;
  int t = threadIdx.x;
  int s = rowp[r], e = rowp[r+1];
  float a0 = 0.f, a1 = 0.f;
  for (int j=s; j<e; ++j){
    int c = ccol[j];
    float w = wv[j];
    unsigned int v = *(const unsigned int*)&A[(size_t)c*HID + t*2];
    a0 += w * bf2f(v & 0xffffu);
    a1 += w * bf2f(v >> 16);
  }
  unsigned int o = (unsigned int)f2bf(a0) | ((unsigned int)f2bf(a1) << 16);
  *(unsigned int*)&out[(size_t)r*HID + t*2] = o;
}

// ---------------- bf16 MFMA GEMM: C[M,512] = A[M,K] @ Bt[N=512,K]^T + bias (opt relu) ----------------
__global__ __launch_bounds__(256) void gemm_bt(const unsigned short* __restrict__ A,
                                               const unsigned short* __restrict__ Bt,
                                               float* __restrict__ C,
                                               const float* __restrict__ bias,
                                               int M, int K, int relu){
  __shared__ unsigned short As[128*32];
  __shared__ unsigned short Bs[128*32];
  const int tid = threadIdx.x;
  const int w = tid >> 6, l = tid & 63;
  const int m0 = blockIdx.x*128, n0 = blockIdx.y*128;
  const int wm = w >> 1, wn = w & 1;
  const int lr = l & 15, lh = l >> 4;

  f32x4 acc[4][4];
#pragma unroll
  for (int i=0;i<4;i++)
#pragma unroll
    for (int j=0;j<4;j++) acc[i][j] = 0.0f;

  const int q0 = w*2, q1 = w*2+1;
  const int sub = l >> 2;        // 0..15
  const int kc  = (l & 3)*8;     // 0,8,16,24
  int ma0 = m0 + q0*16 + sub; if (ma0 >= M) ma0 = M-1;
  int ma1 = m0 + q1*16 + sub; if (ma1 >= M) ma1 = M-1;
  const int nb0 = n0 + q0*16 + sub;
  const int nb1 = n0 + q1*16 + sub;

  for (int k0=0; k0<K; k0+=32){
    gload16(&As[q0*512], A + (size_t)ma0*K + k0 + kc);
    gload16(&As[q1*512], A + (size_t)ma1*K + k0 + kc);
    gload16(&Bs[q0*512], Bt + (size_t)nb0*K + k0 + kc);
    gload16(&Bs[q1*512], Bt + (size_t)nb1*K + k0 + kc);
    __syncthreads();
    short8 af[4], bfr[4];
#pragma unroll
    for (int fm=0; fm<4; ++fm) af[fm]  = *(const short8*)&As[(wm*64 + fm*16 + lr)*32 + lh*8];
#pragma unroll
    for (int fn=0; fn<4; ++fn) bfr[fn] = *(const short8*)&Bs[(wn*64 + fn*16 + lr)*32 + lh*8];
#pragma unroll
    for (int fm=0; fm<4; ++fm)
#pragma unroll
      for (int fn=0; fn<4; ++fn)
        acc[fm][fn] = __builtin_amdgcn_mfma_f32_16x16x32_bf16(af[fm], bfr[fn], acc[fm][fn], 0, 0, 0);
    __syncthreads();
  }
#pragma unroll
  for (int fm=0; fm<4; ++fm){
#pragma unroll
    for (int j=0; j<4; ++j){
      int row = m0 + wm*64 + fm*16 + lh*4 + j;
      if (row < M){
#pragma unroll
        for (int fn=0; fn<4; ++fn){
          int col = n0 + wn*64 + fn*16 + lr;
          float v = acc[fm][fn][j] + bias[col];
          if (relu) v = fmaxf(v, 0.f);
          C[(size_t)row*HID + col] = v;
        }
      }
    }
  }
}

// ---------------- pooling (batch sorted -> binary search bounds) ----------------
__global__ void pool_kernel(const float* __restrict__ X, const int* __restrict__ batch,
                            float* __restrict__ out){
  int g = blockIdx.x;
  int t = threadIdx.x;
  int lo = 0, hi = NN;
  while (lo < hi){ int mid = (lo+hi) >> 1; if (batch[mid] < g) lo = mid+1; else hi = mid; }
  int s = lo;
  lo = 0; hi = NN;
  while (lo < hi){ int mid = (lo+hi) >> 1; if (batch[mid] < g+1) lo = mid+1; else hi = mid; }
  int e = lo;
  float a0 = 0.f, a1 = 0.f;
  for (int i=s; i<e; ++i){
    float2 v = *(const float2*)&X[(size_t)i*HID + t*2];
    a0 += v.x; a1 += v.y;
  }
  out[(size_t)g*HID + t*2]     = a0;
  out[(size_t)g*HID + t*2 + 1] = a1;
}

__global__ void addperm(const float* __restrict__ gc, const float* __restrict__ go,
                        const int* __restrict__ perm, float* __restrict__ gco){
  int g = blockIdx.x;
  int t = threadIdx.x;
  int ps = perm[g];
  for (int k=t; k<HID; k+=256)
    gco[(size_t)g*HID + k] = gc[(size_t)ps*HID + k] + go[(size_t)g*HID + k];
}

// ---------------- final: BN -> fc2 -> log_softmax (fp32) ----------------
__global__ void readout_final(const float* __restrict__ T, const float* __restrict__ mstat,
                              const float* __restrict__ W2, const float* __restrict__ b2,
                              float* __restrict__ out){
  int g = blockIdx.x;
  int l = threadIdx.x;   // 64 threads
  float acc[NCLS];
#pragma unroll
  for (int c=0; c<NCLS; ++c) acc[c] = 0.f;
  const float* tr = T + (size_t)g*HID;
#pragma unroll
  for (int j=0; j<8; ++j){
    int k = l*8 + j;
    float v = (tr[k] - mstat[k]) * mstat[HID+k] + 1e-4f;
#pragma unroll
    for (int c=0; c<NCLS; ++c) acc[c] += v * W2[k*NCLS + c];
  }
  for (int m=1; m<64; m<<=1){
#pragma unroll
    for (int c=0; c<NCLS; ++c) acc[c] += __shfl_xor(acc[c], m);
  }
  if (l == 0){
    float z[NCLS];
    float mx = -1e30f;
#pragma unroll
    for (int c=0; c<NCLS; ++c){ z[c] = acc[c] + b2[c]; mx = fmaxf(mx, z[c]); }
    float s = 0.f;
#pragma unroll
    for (int c=0; c<NCLS; ++c) s += expf(z[c]-mx);
    float lse = mx + logf(s);
#pragma unroll
    for (int c=0; c<NCLS; ++c) out[(size_t)g*NCLS + c] = z[c] - lse;
  }
}

extern "C" void kernel_launch(void* const* d_in, const int* in_sizes, int n_in,
                              void* d_out, int out_size, void* d_ws, size_t ws_size,
                              hipStream_t stream){
  (void)in_sizes; (void)n_in; (void)out_size;
  const float* x      = (const float*)d_in[0];
  const int*   ei     = (const int*)d_in[1];
  const int*   batch  = (const int*)d_in[2];
  const int*   perm   = (const int*)d_in[3];
  const float* convfW = (const float*)d_in[4];
  const float* convfB = (const float*)d_in[5];
  const float* convsW = (const float*)d_in[6];
  const float* convsB = (const float*)d_in[7];
  const float* eattW  = (const float*)d_in[8];
  const float* eattB  = (const float*)d_in[9];
  const float* nattW  = (const float*)d_in[10];
  const float* nattB  = (const float*)d_in[11];
  const float* ctxW   = (const float*)d_in[12];
  const float* ctxB   = (const float*)d_in[13];
  const float* objW   = (const float*)d_in[14];
  const float* objB   = (const float*)d_in[15];
  const float* fc1W[3] = {(const float*)d_in[16], (const float*)d_in[20], (const float*)d_in[24]};
  const float* fc1B[3] = {(const float*)d_in[17], (const float*)d_in[21], (const float*)d_in[25]};
  const float* fc2W[3] = {(const float*)d_in[18], (const float*)d_in[22], (const float*)d_in[26]};
  const float* fc2B[3] = {(const float*)d_in[19], (const float*)d_in[23], (const float*)d_in[27]};
  float* out = (float*)d_out;

  char* p = (char*)d_ws;
  auto alloc = [&](size_t bytes)->char*{ char* r = p; p += (bytes + 255) & ~((size_t)255); return r; };
  const int T = NE + NN;
  float* Xa = (float*)alloc((size_t)NN*HID*4);
  float* Xb = (float*)alloc((size_t)NN*HID*4);
  unsigned short* Abf = (unsigned short*)alloc((size_t)NN*HID*2);
  unsigned short* Gbf = (unsigned short*)alloc((size_t)NN*HID*2);
  unsigned short* WtF = (unsigned short*)alloc((size_t)HID*FIN*2);
  unsigned short* WtL = (unsigned short*)alloc((size_t)3*HID*HID*2);
  unsigned short* WtC = (unsigned short*)alloc((size_t)HID*HID*2);
  unsigned short* WtO = (unsigned short*)alloc((size_t)HID*HID*2);
  unsigned short* WtR = (unsigned short*)alloc((size_t)3*HID*HID*2);
  int* cnt   = (int*)alloc((size_t)NN*4);
  int* fillc = (int*)alloc((size_t)NN*4);
  int* rowp  = (int*)alloc((size_t)(NN+1)*4);
  int* ccol  = (int*)alloc((size_t)T*4);
  int* crow  = (int*)alloc((size_t)T*4);
  int* ceid  = (int*)alloc((size_t)T*4);
  float* w1  = (float*)alloc((size_t)T*4);
  float* wcv = (float*)alloc((size_t)T*4);
  float* wov = (float*)alloc((size_t)T*4);
  float* dis1 = (float*)alloc((size_t)NN*4);
  float* degc = (float*)alloc((size_t)NN*4);
  float* dego = (float*)alloc((size_t)NN*4);
  float* sums = (float*)alloc(2*HID*4);
  float* mstat= (float*)alloc(2*HID*4);
  float* na   = (float*)alloc((size_t)NN*2*4);
  float* eab  = (float*)alloc((size_t)NN*4*4);
  float* att  = (float*)alloc((size_t)NE*2*4);
  float* gc   = (float*)alloc((size_t)NG*HID*4);
  float* go   = (float*)alloc((size_t)NG*HID*4);
  float* gco  = (float*)alloc((size_t)NG*HID*4);
  if ((size_t)(p - (char*)d_ws) > ws_size){
    sentinel_k<<<1,1,0,stream>>>(out);
    return;
  }

  // weights -> bf16 transposed
  w2bt<<<(FIN*HID+255)/256,256,0,stream>>>(convfW, WtF, FIN, HID);
  for (int i=0;i<3;i++)
    w2bt<<<(HID*HID+255)/256,256,0,stream>>>(convsW+(size_t)i*HID*HID, WtL+(size_t)i*HID*HID, HID, HID);
  w2bt<<<(HID*HID+255)/256,256,0,stream>>>(ctxW, WtC, HID, HID);
  w2bt<<<(HID*HID+255)/256,256,0,stream>>>(objW, WtO, HID, HID);
  for (int i=0;i<3;i++)
    w2bt<<<(HID*HID+255)/256,256,0,stream>>>(fc1W[i], WtR+(size_t)i*HID*HID, HID, HID);

  // CSR (destination-sorted adjacency incl. self-loops)
  hipMemsetAsync(cnt, 0, (size_t)NN*4, stream);
  csr_count<<<(NE+255)/256,256,0,stream>>>(ei, cnt);
  scan_rowptr<<<1,1024,0,stream>>>(cnt, rowp, dis1);
  hipMemsetAsync(fillc, 0, (size_t)NN*4, stream);
  csr_fill<<<(T+255)/256,256,0,stream>>>(ei, rowp, cnt, fillc, ccol, crow, ceid);
  w1_kernel<<<(T+255)/256,256,0,stream>>>(crow, ccol, dis1, w1);

  // conv_feat: relu(bn(x) @ Wf + bf)
  hipMemsetAsync(sums, 0, 2*HID*4, stream);
  bnstats<<<256,256,0,stream>>>(x, nullptr, 0, NN, FIN, sums);
  bnfin<<<1,HID,0,stream>>>(sums, NN, FIN, mstat);
  bncast<<<((NN*FIN/4)+255)/256,256,0,stream>>>(x, nullptr, 0, mstat, NN, FIN, Abf);
  gemm_bt<<<dim3((NN+127)/128,4),256,0,stream>>>(Abf, WtF, Xa, convfB, NN, FIN, 1);

  // 3 GCN layers: relu( Agg(bn(X)) @ W + b )
  for (int i=0;i<3;i++){
    hipMemsetAsync(sums, 0, 2*HID*4, stream);
    bnstats<<<256,256,0,stream>>>(Xa, nullptr, 0, NN, HID, sums);
    bnfin<<<1,HID,0,stream>>>(sums, NN, HID, mstat);
    bncast<<<((NN*HID/4)+255)/256,256,0,stream>>>(Xa, nullptr, 0, mstat, NN, HID, Abf);
    aggregate<<<NN,256,0,stream>>>(Abf, rowp, ccol, w1, Gbf);
    gemm_bt<<<dim3((NN+127)/128,4),256,0,stream>>>(Gbf, WtL+(size_t)i*HID*HID, Xb, convsB+(size_t)i*HID, NN, HID, 1);
    float* tmp = Xa; Xa = Xb; Xb = tmp;
  }

  // attention
  att_node<<<(NN+3)/4,256,0,stream>>>(Xa, nattW, nattB, eattW, na, eab);
  fill1<<<(NN+255)/256,256,0,stream>>>(degc, dego);
  att_edge<<<(NE+255)/256,256,0,stream>>>(ei, eab, eattB, att, degc, dego);
  wco_kernel<<<(T+255)/256,256,0,stream>>>(crow, ccol, ceid, att, degc, dego, wcv, wov);

  // context branch
  hipMemsetAsync(sums, 0, 2*HID*4, stream);
  bnstats<<<256,256,0,stream>>>(Xa, na, 2, NN, HID, sums);
  bnfin<<<1,HID,0,stream>>>(sums, NN, HID, mstat);
  bncast<<<((NN*HID/4)+255)/256,256,0,stream>>>(Xa, na, 2, mstat, NN, HID, Abf);
  aggregate<<<NN,256,0,stream>>>(Abf, rowp, ccol, wcv, Gbf);
  gemm_bt<<<dim3((NN+127)/128,4),256,0,stream>>>(Gbf, WtC, Xb, ctxB, NN, HID, 1);
  pool_kernel<<<NG,256,0,stream>>>(Xb, batch, gc);

  // object branch
  hipMemsetAsync(sums, 0, 2*HID*4, stream);
  bnstats<<<256,256,0,stream>>>(Xa, na+1, 2, NN, HID, sums);
  bnfin<<<1,HID,0,stream>>>(sums, NN, HID, mstat);
  bncast<<<((NN*HID/4)+255)/256,256,0,stream>>>(Xa, na+1, 2, mstat, NN, HID, Abf);
  aggregate<<<NN,256,0,stream>>>(Abf, rowp, ccol, wov, Gbf);
  gemm_bt<<<dim3((NN+127)/128,4),256,0,stream>>>(Gbf, WtO, Xb, objB, NN, HID, 1);
  pool_kernel<<<NG,256,0,stream>>>(Xb, batch, go);

  // xco = gc[perm] + go
  addperm<<<NG,256,0,stream>>>(gc, go, perm, gco);

  // readouts
  const float* gin[3] = {gc, go, gco};
  for (int r=0;r<3;r++){
    hipMemsetAsync(sums, 0, 2*HID*4, stream);
    bnstats<<<256,256,0,stream>>>(gin[r], nullptr, 0, NG, HID, sums);
    bnfin<<<1,HID,0,stream>>>(sums, NG, HID, mstat);
    bncast<<<((NG*HID/4)+255)/256,256,0,stream>>>(gin[r], nullptr, 0, mstat, NG, HID, Abf);
    gemm_bt<<<dim3((NG+127)/128,4),256,0,stream>>>(Abf, WtR+(size_t)r*HID*HID, Xb, fc1B[r], NG, HID, 1);
    hipMemsetAsync(sums, 0, 2*HID*4, stream);
    bnstats<<<256,256,0,stream>>>(Xb, nullptr, 0, NG, HID, sums);
    bnfin<<<1,HID,0,stream>>>(sums, NG, HID, mstat);
    readout_final<<<NG,64,0,stream>>>(Xb, mstat, fc2W[r], fc2B[r], out + (size_t)r*NG*NCLS);
  }
}

// Round 2
// 962.263 us; speedup vs baseline: 1.0674x; 1.0674x over previous
//
#include <hip/hip_runtime.h>
#include <stdint.h>

#define NN 20000
#define NE 160000
#define NG 500
#define FIN 128
#define HID 512
#define NCLS 10
#define BNG 256

typedef __attribute__((ext_vector_type(8))) short short8;
typedef __attribute__((ext_vector_type(4))) float f32x4;
typedef __attribute__((ext_vector_type(4))) unsigned short ushort4v;

__device__ __forceinline__ float bf2f(unsigned int u){
  union{unsigned int i; float f;} x; x.i = u<<16; return x.f;
}
__device__ __forceinline__ unsigned short f2bf(float f){
  union{float f; unsigned int i;} x; x.f=f;
  unsigned int r = x.i + 0x7fffu + ((x.i>>16)&1u);
  return (unsigned short)(r>>16);
}

__device__ __forceinline__ void gload16(unsigned short* lds, const unsigned short* g){
  __builtin_amdgcn_global_load_lds((const __attribute__((address_space(1))) unsigned int*)g,
                                   (__attribute__((address_space(3))) unsigned int*)lds,
                                   16, 0, 0);
}

__global__ void sentinel_k(float* out){ out[0] = 12345.0f; }

// ---------------- weight transpose+cast: W[K][N] f32 -> Wt[N][K] bf16 ----------------
__global__ void w2bt(const float* __restrict__ W, unsigned short* __restrict__ Wt, int K, int Nn){
  int idx = blockIdx.x*blockDim.x + threadIdx.x;
  if (idx < K*Nn){
    int k = idx / Nn, n = idx - k*Nn;
    Wt[(size_t)n*K + k] = f2bf(W[idx]);
  }
}

// ---------------- BN stats stage 1: per-block partial column sums/sumsq ----------------
__global__ __launch_bounds__(1024) void bnstats_p(const float* __restrict__ X, const float* __restrict__ scale,
                                                  int sstride, int M, int F, float* __restrict__ partials){
  __shared__ float lds[1024*9];
  const int t = threadIdx.x;
  const int cg = F >> 2;           // column groups of 4
  const int cid = t & (cg-1);
  const int rid = t / cg;          // 0..rpb-1
  const int rpb = 1024 / cg;
  float s0=0,s1=0,s2=0,s3=0,q0=0,q1=0,q2=0,q3=0;
  const int rowsPer = (M + BNG - 1)/BNG;
  int r0 = blockIdx.x*rowsPer, r1 = r0 + rowsPer; if (r1 > M) r1 = M;
  for (int r = r0 + rid; r < r1; r += rpb){
    float sc = scale ? scale[(size_t)r*sstride] : 1.0f;
    float4 v = *(const float4*)&X[(size_t)r*F + cid*4];
    float a0=v.x*sc, a1=v.y*sc, a2=v.z*sc, a3=v.w*sc;
    s0+=a0; q0+=a0*a0; s1+=a1; q1+=a1*a1; s2+=a2; q2+=a2*a2; s3+=a3; q3+=a3*a3;
  }
  int base = (rid*cg + cid)*9;
  lds[base+0]=s0; lds[base+1]=s1; lds[base+2]=s2; lds[base+3]=s3;
  lds[base+4]=q0; lds[base+5]=q1; lds[base+6]=q2; lds[base+7]=q3;
  __syncthreads();
  if (t < cg*8){
    int ci = t >> 3, i = t & 7;
    float acc = 0.f;
    for (int g=0; g<rpb; ++g) acc += lds[(g*cg + ci)*9 + i];
    int col = ci*4 + (i & 3);
    partials[(size_t)blockIdx.x*(2*F) + ((i < 4) ? col : F + col)] = acc;
  }
}

// ---------------- BN stats stage 2: reduce partials -> mean, rstd ----------------
__global__ void bnfin_red(const float* __restrict__ partials, int M, int F, float* __restrict__ mstat){
  __shared__ float lds[4][64][2];
  int t = threadIdx.x;
  int cl = t & 63, ch = t >> 6;
  int c = blockIdx.x*64 + cl;
  float s = 0.f, q = 0.f;
  if (c < F){
    for (int b = ch*64; b < ch*64 + 64; ++b){
      s += partials[(size_t)b*(2*F) + c];
      q += partials[(size_t)b*(2*F) + F + c];
    }
  }
  lds[ch][cl][0] = s; lds[ch][cl][1] = q;
  __syncthreads();
  if (ch == 0 && c < F){
    s = lds[0][cl][0]+lds[1][cl][0]+lds[2][cl][0]+lds[3][cl][0];
    q = lds[0][cl][1]+lds[1][cl][1]+lds[2][cl][1]+lds[3][cl][1];
    float m = s/(float)M;
    float v = q/(float)M - m*m;
    mstat[c] = m;
    mstat[F+c] = rsqrtf(v + 1e-5f);
  }
}

// ---------------- fused (scale)->BN->bf16 cast ----------------
__global__ void bncast(const float* __restrict__ X, const float* __restrict__ scale, int sstride,
                       const float* __restrict__ mstat, int M, int F, unsigned short* __restrict__ out){
  int idx = blockIdx.x*blockDim.x + threadIdx.x;
  int total4 = M*F/4;
  if (idx >= total4) return;
  int base = idx*4;
  int r = base / F;
  int c = base - r*F;
  float sc = scale ? scale[(size_t)r*sstride] : 1.0f;
  float4 v = *(const float4*)&X[base];
  ushort4v o;
  o[0] = f2bf((v.x*sc - mstat[c+0])*mstat[F+c+0] + 1e-4f);
  o[1] = f2bf((v.y*sc - mstat[c+1])*mstat[F+c+1] + 1e-4f);
  o[2] = f2bf((v.z*sc - mstat[c+2])*mstat[F+c+2] + 1e-4f);
  o[3] = f2bf((v.w*sc - mstat[c+3])*mstat[F+c+3] + 1e-4f);
  *(ushort4v*)&out[base] = o;
}

// ---------------- CSR build ----------------
__global__ void csr_count(const int* __restrict__ ei, int* __restrict__ cnt){
  int e = blockIdx.x*blockDim.x + threadIdx.x;
  if (e < NE) atomicAdd(&cnt[ei[e]], 1);
}

__global__ void scan_rowptr(const int* __restrict__ cnt, int* __restrict__ rowp, float* __restrict__ dis1){
  __shared__ int buf[1024];
  __shared__ int carry;
  const int t = threadIdx.x;
  if (t == 0){ carry = 0; rowp[0] = 0; }
  __syncthreads();
  for (int base=0; base<NN; base+=1024){
    int i = base + t;
    int v = 0;
    if (i < NN){ v = cnt[i] + 1; dis1[i] = rsqrtf((float)v); }
    buf[t] = v;
    __syncthreads();
    for (int off=1; off<1024; off<<=1){
      int xv = (t >= off) ? buf[t-off] : 0;
      __syncthreads();
      buf[t] += xv;
      __syncthreads();
    }
    if (i < NN) rowp[i+1] = carry + buf[t];
    __syncthreads();
    if (t == 0) carry += buf[1023];
    __syncthreads();
  }
}

__global__ void csr_fill(const int* __restrict__ ei, const int* __restrict__ rowp,
                         const int* __restrict__ cnt, int* __restrict__ fillc,
                         int* __restrict__ ccol, int* __restrict__ crow, int* __restrict__ ceid){
  int id = blockIdx.x*blockDim.x + threadIdx.x;
  if (id < NE){
    int r = ei[id], c = ei[NE + id];
    int pos = atomicAdd(&fillc[r], 1);
    int idx = rowp[r] + pos;
    ccol[idx] = c; crow[idx] = r; ceid[idx] = id;
  } else if (id < NE + NN){
    int i = id - NE;
    int idx = rowp[i] + cnt[i];     // self-loop gets the fixed last slot
    ccol[idx] = i; crow[idx] = i; ceid[idx] = -1;
  }
}

__global__ void w1_kernel(const int* __restrict__ crow, const int* __restrict__ ccol,
                          const float* __restrict__ dis1, float* __restrict__ w1){
  int j = blockIdx.x*blockDim.x + threadIdx.x;
  if (j < NE + NN) w1[j] = dis1[crow[j]] * dis1[ccol[j]];
}

// ---------------- attention ----------------
__global__ void att_node(const float* __restrict__ X, const float* __restrict__ nW,
                         const float* __restrict__ nb, const float* __restrict__ eW,
                         float* __restrict__ na, float* __restrict__ eab){
  int wv = blockIdx.x*4 + (threadIdx.x >> 6);
  int l = threadIdx.x & 63;
  if (wv >= NN) return;
  const float* xr = X + (size_t)wv*HID;
  float s0=0,s1=0,s2=0,s3=0,s4=0,s5=0;
#pragma unroll
  for (int j=0; j<8; ++j){
    int k = l*8 + j;
    float xv = xr[k];
    s0 += xv * nW[2*k];       s1 += xv * nW[2*k+1];
    s2 += xv * eW[2*k];       s3 += xv * eW[2*k+1];
    s4 += xv * eW[2*(512+k)]; s5 += xv * eW[2*(512+k)+1];
  }
  for (int m=1; m<64; m<<=1){
    s0 += __shfl_xor(s0,m); s1 += __shfl_xor(s1,m); s2 += __shfl_xor(s2,m);
    s3 += __shfl_xor(s3,m); s4 += __shfl_xor(s4,m); s5 += __shfl_xor(s5,m);
  }
  if (l == 0){
    float z0 = s0 + nb[0], z1 = s1 + nb[1];
    float mx = fmaxf(z0,z1);
    float e0 = expf(z0-mx), e1 = expf(z1-mx);
    float inv = 1.0f/(e0+e1);
    na[2*wv] = e0*inv; na[2*wv+1] = e1*inv;
    eab[4*wv] = s2; eab[4*wv+1] = s3; eab[4*wv+2] = s4; eab[4*wv+3] = s5;
  }
}

__global__ void fill1(float* __restrict__ a, float* __restrict__ b){
  int i = blockIdx.x*blockDim.x + threadIdx.x;
  if (i < NN){ a[i] = 1.0f; b[i] = 1.0f; }
}

__global__ void att_edge(const int* __restrict__ ei, const float* __restrict__ eab,
                         const float* __restrict__ eb, float* __restrict__ att,
                         float* __restrict__ degc, float* __restrict__ dego){
  int e = blockIdx.x*blockDim.x + threadIdx.x;
  if (e >= NE) return;
  int r = ei[e], c = ei[NE+e];
  float z0 = eab[4*r]   + eab[4*c+2] + eb[0];
  float z1 = eab[4*r+1] + eab[4*c+3] + eb[1];
  float mx = fmaxf(z0,z1);
  float e0 = expf(z0-mx), e1 = expf(z1-mx);
  float inv = 1.0f/(e0+e1);
  float a0 = e0*inv, a1 = e1*inv;
  att[2*e] = a0; att[2*e+1] = a1;
  atomicAdd(&degc[r], a0);
  atomicAdd(&dego[r], a1);
}

__global__ void wco_kernel(const int* __restrict__ crow, const int* __restrict__ ccol,
                           const int* __restrict__ ceid, const float* __restrict__ att,
                           const float* __restrict__ degc, const float* __restrict__ dego,
                           float* __restrict__ wcv, float* __restrict__ wov){
  int j = blockIdx.x*blockDim.x + threadIdx.x;
  if (j >= NE + NN) return;
  int r = crow[j], c = ccol[j], e = ceid[j];
  float a0 = (e < 0) ? 1.0f : att[2*e];
  float a1 = (e < 0) ? 1.0f : att[2*e+1];
  wcv[j] = rsqrtf(degc[r]) * a0 * rsqrtf(degc[c]);
  wov[j] = rsqrtf(dego[r]) * a1 * rsqrtf(dego[c]);
}

// ---------------- CSR aggregation: out[r] = sum_j w[j] * A[col[j]]  (bf16 in/out, f32 acc) ----------------
__global__ void aggregate(const unsigned short* __restrict__ A, const int* __restrict__ rowp,
                          const int* __restrict__ ccol, const float* __restrict__ wv,
                          unsigned short* __restrict__ out){
  int r = blockIdx.x;
  int t = threadIdx.x;
  int s = rowp[r], e = rowp[r+1];
  float a0 = 0.f, a1 = 0.f;
  for (int j=s; j<e; ++j){
    int c = ccol[j];
    float w = wv[j];
    unsigned int v = *(const unsigned int*)&A[(size_t)c*HID + t*2];
    a0 += w * bf2f(v & 0xffffu);
    a1 += w * bf2f(v >> 16);
  }
  unsigned int o = (unsigned int)f2bf(a0) | ((unsigned int)f2bf(a1) << 16);
  *(unsigned int*)&out[(size_t)r*HID + t*2] = o;
}

// ---------------- bf16 MFMA GEMM: C[M,512] = A[M,K] @ Bt[N=512,K]^T + bias (opt relu) ----------------
__global__ __launch_bounds__(256) void gemm_bt(const unsigned short* __restrict__ A,
                                               const unsigned short* __restrict__ Bt,
                                               float* __restrict__ C,
                                               const float* __restrict__ bias,
                                               int M, int K, int relu){
  __shared__ unsigned short As[128*32];
  __shared__ unsigned short Bs[128*32];
  const int tid = threadIdx.x;
  const int w = tid >> 6, l = tid & 63;
  const int m0 = blockIdx.x*128, n0 = blockIdx.y*128;
  const int wm = w >> 1, wn = w & 1;
  const int lr = l & 15, lh = l >> 4;

  f32x4 acc[4][4];
#pragma unroll
  for (int i=0;i<4;i++)
#pragma unroll
    for (int j=0;j<4;j++) acc[i][j] = 0.0f;

  const int q0 = w*2, q1 = w*2+1;
  const int sub = l >> 2;        // 0..15
  const int kc  = (l & 3)*8;     // 0,8,16,24
  int ma0 = m0 + q0*16 + sub; if (ma0 >= M) ma0 = M-1;
  int ma1 = m0 + q1*16 + sub; if (ma1 >= M) ma1 = M-1;
  const int nb0 = n0 + q0*16 + sub;
  const int nb1 = n0 + q1*16 + sub;

  for (int k0=0; k0<K; k0+=32){
    gload16(&As[q0*512], A + (size_t)ma0*K + k0 + kc);
    gload16(&As[q1*512], A + (size_t)ma1*K + k0 + kc);
    gload16(&Bs[q0*512], Bt + (size_t)nb0*K + k0 + kc);
    gload16(&Bs[q1*512], Bt + (size_t)nb1*K + k0 + kc);
    __syncthreads();
    short8 af[4], bfr[4];
#pragma unroll
    for (int fm=0; fm<4; ++fm) af[fm]  = *(const short8*)&As[(wm*64 + fm*16 + lr)*32 + lh*8];
#pragma unroll
    for (int fn=0; fn<4; ++fn) bfr[fn] = *(const short8*)&Bs[(wn*64 + fn*16 + lr)*32 + lh*8];
#pragma unroll
    for (int fm=0; fm<4; ++fm)
#pragma unroll
      for (int fn=0; fn<4; ++fn)
        acc[fm][fn] = __builtin_amdgcn_mfma_f32_16x16x32_bf16(af[fm], bfr[fn], acc[fm][fn], 0, 0, 0);
    __syncthreads();
  }
#pragma unroll
  for (int fm=0; fm<4; ++fm){
#pragma unroll
    for (int j=0; j<4; ++j){
      int row = m0 + wm*64 + fm*16 + lh*4 + j;
      if (row < M){
#pragma unroll
        for (int fn=0; fn<4; ++fn){
          int col = n0 + wn*64 + fn*16 + lr;
          float v = acc[fm][fn][j] + bias[col];
          if (relu) v = fmaxf(v, 0.f);
          C[(size_t)row*HID + col] = v;
        }
      }
    }
  }
}

// ---------------- pooling (batch sorted -> binary search bounds) ----------------
__global__ void pool_kernel(const float* __restrict__ X, const int* __restrict__ batch,
                            float* __restrict__ out){
  int g = blockIdx.x;
  int t = threadIdx.x;
  int lo = 0, hi = NN;
  while (lo < hi){ int mid = (lo+hi) >> 1; if (batch[mid] < g) lo = mid+1; else hi = mid; }
  int s = lo;
  lo = 0; hi = NN;
  while (lo < hi){ int mid = (lo+hi) >> 1; if (batch[mid] < g+1) lo = mid+1; else hi = mid; }
  int e = lo;
  float a0 = 0.f, a1 = 0.f;
  for (int i=s; i<e; ++i){
    float2 v = *(const float2*)&X[(size_t)i*HID + t*2];
    a0 += v.x; a1 += v.y;
  }
  out[(size_t)g*HID + t*2]     = a0;
  out[(size_t)g*HID + t*2 + 1] = a1;
}

__global__ void addperm(const float* __restrict__ gc, const float* __restrict__ go,
                        const int* __restrict__ perm, float* __restrict__ gco){
  int g = blockIdx.x;
  int t = threadIdx.x;
  int ps = perm[g];
  for (int k=t; k<HID; k+=256)
    gco[(size_t)g*HID + k] = gc[(size_t)ps*HID + k] + go[(size_t)g*HID + k];
}

// ---------------- final: BN -> fc2 -> log_softmax (fp32) ----------------
__global__ void readout_final(const float* __restrict__ T, const float* __restrict__ mstat,
                              const float* __restrict__ W2, const float* __restrict__ b2,
                              float* __restrict__ out){
  int g = blockIdx.x;
  int l = threadIdx.x;   // 64 threads
  float acc[NCLS];
#pragma unroll
  for (int c=0; c<NCLS; ++c) acc[c] = 0.f;
  const float* tr = T + (size_t)g*HID;
#pragma unroll
  for (int j=0; j<8; ++j){
    int k = l*8 + j;
    float v = (tr[k] - mstat[k]) * mstat[HID+k] + 1e-4f;
#pragma unroll
    for (int c=0; c<NCLS; ++c) acc[c] += v * W2[k*NCLS + c];
  }
  for (int m=1; m<64; m<<=1){
#pragma unroll
    for (int c=0; c<NCLS; ++c) acc[c] += __shfl_xor(acc[c], m);
  }
  if (l == 0){
    float z[NCLS];
    float mx = -1e30f;
#pragma unroll
    for (int c=0; c<NCLS; ++c){ z[c] = acc[c] + b2[c]; mx = fmaxf(mx, z[c]); }
    float s = 0.f;
#pragma unroll
    for (int c=0; c<NCLS; ++c) s += expf(z[c]-mx);
    float lse = mx + logf(s);
#pragma unroll
    for (int c=0; c<NCLS; ++c) out[(size_t)g*NCLS + c] = z[c] - lse;
  }
}

extern "C" void kernel_launch(void* const* d_in, const int* in_sizes, int n_in,
                              void* d_out, int out_size, void* d_ws, size_t ws_size,
                              hipStream_t stream){
  (void)in_sizes; (void)n_in; (void)out_size;
  const float* x      = (const float*)d_in[0];
  const int*   ei     = (const int*)d_in[1];
  const int*   batch  = (const int*)d_in[2];
  const int*   perm   = (const int*)d_in[3];
  const float* convfW = (const float*)d_in[4];
  const float* convfB = (const float*)d_in[5];
  const float* convsW = (const float*)d_in[6];
  const float* convsB = (const float*)d_in[7];
  const float* eattW  = (const float*)d_in[8];
  const float* eattB  = (const float*)d_in[9];
  const float* nattW  = (const float*)d_in[10];
  const float* nattB  = (const float*)d_in[11];
  const float* ctxW   = (const float*)d_in[12];
  const float* ctxB   = (const float*)d_in[13];
  const float* objW   = (const float*)d_in[14];
  const float* objB   = (const float*)d_in[15];
  const float* fc1W[3] = {(const float*)d_in[16], (const float*)d_in[20], (const float*)d_in[24]};
  const float* fc1B[3] = {(const float*)d_in[17], (const float*)d_in[21], (const float*)d_in[25]};
  const float* fc2W[3] = {(const float*)d_in[18], (const float*)d_in[22], (const float*)d_in[26]};
  const float* fc2B[3] = {(const float*)d_in[19], (const float*)d_in[23], (const float*)d_in[27]};
  float* out = (float*)d_out;

  char* p = (char*)d_ws;
  auto alloc = [&](size_t bytes)->char*{ char* r = p; p += (bytes + 255) & ~((size_t)255); return r; };
  const int T = NE + NN;
  float* Xa = (float*)alloc((size_t)NN*HID*4);
  float* Xb = (float*)alloc((size_t)NN*HID*4);
  unsigned short* Abf = (unsigned short*)alloc((size_t)NN*HID*2);
  unsigned short* Gbf = (unsigned short*)alloc((size_t)NN*HID*2);
  unsigned short* WtF = (unsigned short*)alloc((size_t)HID*FIN*2);
  unsigned short* WtL = (unsigned short*)alloc((size_t)3*HID*HID*2);
  unsigned short* WtC = (unsigned short*)alloc((size_t)HID*HID*2);
  unsigned short* WtO = (unsigned short*)alloc((size_t)HID*HID*2);
  unsigned short* WtR = (unsigned short*)alloc((size_t)3*HID*HID*2);
  int* cnt   = (int*)alloc((size_t)NN*4);
  int* fillc = (int*)alloc((size_t)NN*4);
  int* rowp  = (int*)alloc((size_t)(NN+1)*4);
  int* ccol  = (int*)alloc((size_t)T*4);
  int* crow  = (int*)alloc((size_t)T*4);
  int* ceid  = (int*)alloc((size_t)T*4);
  float* w1  = (float*)alloc((size_t)T*4);
  float* wcv = (float*)alloc((size_t)T*4);
  float* wov = (float*)alloc((size_t)T*4);
  float* dis1 = (float*)alloc((size_t)NN*4);
  float* degc = (float*)alloc((size_t)NN*4);
  float* dego = (float*)alloc((size_t)NN*4);
  float* mstat= (float*)alloc(2*HID*4);
  float* na   = (float*)alloc((size_t)NN*2*4);
  float* eab  = (float*)alloc((size_t)NN*4*4);
  float* att  = (float*)alloc((size_t)NE*2*4);   // also aliased as BN partials (disjoint lifetimes)
  float* gc   = (float*)alloc((size_t)NG*HID*4);
  float* go   = (float*)alloc((size_t)NG*HID*4);
  float* gco  = (float*)alloc((size_t)NG*HID*4);
  float* part = att;   // BNG*2*HID*4 = 1MB <= att's 1.28MB; att live only between att_edge and wco_kernel
  if ((size_t)(p - (char*)d_ws) > ws_size){
    sentinel_k<<<1,1,0,stream>>>(out);
    return;
  }

  // weights -> bf16 transposed
  w2bt<<<(FIN*HID+255)/256,256,0,stream>>>(convfW, WtF, FIN, HID);
  for (int i=0;i<3;i++)
    w2bt<<<(HID*HID+255)/256,256,0,stream>>>(convsW+(size_t)i*HID*HID, WtL+(size_t)i*HID*HID, HID, HID);
  w2bt<<<(HID*HID+255)/256,256,0,stream>>>(ctxW, WtC, HID, HID);
  w2bt<<<(HID*HID+255)/256,256,0,stream>>>(objW, WtO, HID, HID);
  for (int i=0;i<3;i++)
    w2bt<<<(HID*HID+255)/256,256,0,stream>>>(fc1W[i], WtR+(size_t)i*HID*HID, HID, HID);

  // CSR (destination-sorted adjacency incl. self-loops)
  hipMemsetAsync(cnt, 0, (size_t)NN*4, stream);
  csr_count<<<(NE+255)/256,256,0,stream>>>(ei, cnt);
  scan_rowptr<<<1,1024,0,stream>>>(cnt, rowp, dis1);
  hipMemsetAsync(fillc, 0, (size_t)NN*4, stream);
  csr_fill<<<(T+255)/256,256,0,stream>>>(ei, rowp, cnt, fillc, ccol, crow, ceid);
  w1_kernel<<<(T+255)/256,256,0,stream>>>(crow, ccol, dis1, w1);

  // conv_feat: relu(bn(x) @ Wf + bf)
  bnstats_p<<<BNG,1024,0,stream>>>(x, nullptr, 0, NN, FIN, part);
  bnfin_red<<<(FIN+63)/64,256,0,stream>>>(part, NN, FIN, mstat);
  bncast<<<((NN*FIN/4)+255)/256,256,0,stream>>>(x, nullptr, 0, mstat, NN, FIN, Abf);
  gemm_bt<<<dim3((NN+127)/128,4),256,0,stream>>>(Abf, WtF, Xa, convfB, NN, FIN, 1);

  // 3 GCN layers: relu( Agg(bn(X)) @ W + b )
  for (int i=0;i<3;i++){
    bnstats_p<<<BNG,1024,0,stream>>>(Xa, nullptr, 0, NN, HID, part);
    bnfin_red<<<(HID+63)/64,256,0,stream>>>(part, NN, HID, mstat);
    bncast<<<((NN*HID/4)+255)/256,256,0,stream>>>(Xa, nullptr, 0, mstat, NN, HID, Abf);
    aggregate<<<NN,256,0,stream>>>(Abf, rowp, ccol, w1, Gbf);
    gemm_bt<<<dim3((NN+127)/128,4),256,0,stream>>>(Gbf, WtL+(size_t)i*HID*HID, Xb, convsB+(size_t)i*HID, NN, HID, 1);
    float* tmp = Xa; Xa = Xb; Xb = tmp;
  }

  // attention
  att_node<<<(NN+3)/4,256,0,stream>>>(Xa, nattW, nattB, eattW, na, eab);
  fill1<<<(NN+255)/256,256,0,stream>>>(degc, dego);
  att_edge<<<(NE+255)/256,256,0,stream>>>(ei, eab, eattB, att, degc, dego);
  wco_kernel<<<(T+255)/256,256,0,stream>>>(crow, ccol, ceid, att, degc, dego, wcv, wov);
  // (att is dead from here on; its memory is reused as `part`)

  // context branch
  bnstats_p<<<BNG,1024,0,stream>>>(Xa, na, 2, NN, HID, part);
  bnfin_red<<<(HID+63)/64,256,0,stream>>>(part, NN, HID, mstat);
  bncast<<<((NN*HID/4)+255)/256,256,0,stream>>>(Xa, na, 2, mstat, NN, HID, Abf);
  aggregate<<<NN,256,0,stream>>>(Abf, rowp, ccol, wcv, Gbf);
  gemm_bt<<<dim3((NN+127)/128,4),256,0,stream>>>(Gbf, WtC, Xb, ctxB, NN, HID, 1);
  pool_kernel<<<NG,256,0,stream>>>(Xb, batch, gc);

  // object branch
  bnstats_p<<<BNG,1024,0,stream>>>(Xa, na+1, 2, NN, HID, part);
  bnfin_red<<<(HID+63)/64,256,0,stream>>>(part, NN, HID, mstat);
  bncast<<<((NN*HID/4)+255)/256,256,0,stream>>>(Xa, na+1, 2, mstat, NN, HID, Abf);
  aggregate<<<NN,256,0,stream>>>(Abf, rowp, ccol, wov, Gbf);
  gemm_bt<<<dim3((NN+127)/128,4),256,0,stream>>>(Gbf, WtO, Xb, objB, NN, HID, 1);
  pool_kernel<<<NG,256,0,stream>>>(Xb, batch, go);

  // xco = gc[perm] + go
  addperm<<<NG,256,0,stream>>>(gc, go, perm, gco);

  // readouts
  const float* gin[3] = {gc, go, gco};
  for (int r=0;r<3;r++){
    bnstats_p<<<BNG,1024,0,stream>>>(gin[r], nullptr, 0, NG, HID, part);
    bnfin_red<<<(HID+63)/64,256,0,stream>>>(part, NG, HID, mstat);
    bncast<<<((NG*HID/4)+255)/256,256,0,stream>>>(gin[r], nullptr, 0, mstat, NG, HID, Abf);
    gemm_bt<<<dim3((NG+127)/128,4),256,0,stream>>>(Abf, WtR+(size_t)r*HID*HID, Xb, fc1B[r], NG, HID, 1);
    bnstats_p<<<BNG,1024,0,stream>>>(Xb, nullptr, 0, NG, HID, part);
    bnfin_red<<<(HID+63)/64,256,0,stream>>>(part, NG, HID, mstat);
    readout_final<<<NG,64,0,stream>>>(Xb, mstat, fc2W[r], fc2B[r], out + (size_t)r*NG*NCLS);
  }
}

// Round 3
// 795.433 us; speedup vs baseline: 1.2913x; 1.2097x over previous
//
#include <hip/hip_runtime.h>
#include <stdint.h>

#define NN 20000
#define NE 160000
#define NG 500
#define FIN 128
#define HID 512
#define NCLS 10
#define BNG 256

typedef __attribute__((ext_vector_type(8))) short short8;
typedef __attribute__((ext_vector_type(4))) float f32x4;
typedef __attribute__((ext_vector_type(4))) unsigned short ushort4v;

__device__ __forceinline__ float bf2f(unsigned int u){
  union{unsigned int i; float f;} x; x.i = u<<16; return x.f;
}
__device__ __forceinline__ unsigned short f2bf(float f){
  union{float f; unsigned int i;} x; x.f=f;
  unsigned int r = x.i + 0x7fffu + ((x.i>>16)&1u);
  return (unsigned short)(r>>16);
}
__device__ __forceinline__ unsigned int pk2(float a, float b){
  return (unsigned int)f2bf(a) | ((unsigned int)f2bf(b) << 16);
}

__device__ __forceinline__ void gload16(unsigned short* lds, const unsigned short* g){
  __builtin_amdgcn_global_load_lds((const __attribute__((address_space(1))) unsigned int*)g,
                                   (__attribute__((address_space(3))) unsigned int*)lds,
                                   16, 0, 0);
}

__device__ __forceinline__ void fma8(float* acc, uint4 v, float w){
  acc[0] += w*bf2f(v.x & 0xffffu); acc[1] += w*bf2f(v.x >> 16);
  acc[2] += w*bf2f(v.y & 0xffffu); acc[3] += w*bf2f(v.y >> 16);
  acc[4] += w*bf2f(v.z & 0xffffu); acc[5] += w*bf2f(v.z >> 16);
  acc[6] += w*bf2f(v.w & 0xffffu); acc[7] += w*bf2f(v.w >> 16);
}

__global__ void sentinel_k(float* out){ out[0] = 12345.0f; }

// ---------------- all weight transposes+casts in one dispatch ----------------
struct W2BT { const float* src[9]; unsigned short* dst[9]; };
__global__ void w2bt_all(W2BT p){
  int idx = blockIdx.x*blockDim.x + threadIdx.x;
  int seg, off, K;
  if (idx < FIN*HID){ seg = 0; off = idx; K = FIN; }
  else {
    int r = idx - FIN*HID;
    if (r >= 8*HID*HID) return;
    seg = 1 + (r >> 18); off = r & (HID*HID-1); K = HID;
  }
  int k = off >> 9, n = off & 511;
  p.dst[seg][(size_t)n*K + k] = f2bf(p.src[seg][off]);
}

// ---------------- init: counters/flags ----------------
__global__ void init_misc(int* __restrict__ cnt, int* __restrict__ fillc,
                          float* __restrict__ degc, float* __restrict__ dego,
                          float* __restrict__ Sc, float* __restrict__ So){
  int i = blockIdx.x*blockDim.x + threadIdx.x;
  if (i < NN){ cnt[i]=0; fillc[i]=0; degc[i]=1.0f; dego[i]=1.0f; Sc[i]=0.f; So[i]=0.f; }
}

// ---------------- BN stats stage 1: per-block partial column sums/sumsq ----------------
__global__ __launch_bounds__(1024) void bnstats_p(const float* __restrict__ X, int M, int F,
                                                  float* __restrict__ partials){
  __shared__ float lds[1024*9];
  const int t = threadIdx.x;
  const int cg = F >> 2;
  const int cid = t & (cg-1);
  const int rid = t / cg;
  const int rpb = 1024 / cg;
  float s0=0,s1=0,s2=0,s3=0,q0=0,q1=0,q2=0,q3=0;
  const int rowsPer = (M + BNG - 1)/BNG;
  int r0 = blockIdx.x*rowsPer, r1 = r0 + rowsPer; if (r1 > M) r1 = M;
  for (int r = r0 + rid; r < r1; r += rpb){
    float4 v = *(const float4*)&X[(size_t)r*F + cid*4];
    s0+=v.x; q0+=v.x*v.x; s1+=v.y; q1+=v.y*v.y; s2+=v.z; q2+=v.z*v.z; s3+=v.w; q3+=v.w*v.w;
  }
  int base = (rid*cg + cid)*9;
  lds[base+0]=s0; lds[base+1]=s1; lds[base+2]=s2; lds[base+3]=s3;
  lds[base+4]=q0; lds[base+5]=q1; lds[base+6]=q2; lds[base+7]=q3;
  __syncthreads();
  if (t < cg*8){
    int ci = t >> 3, i = t & 7;
    float acc = 0.f;
    for (int g=0; g<rpb; ++g) acc += lds[(g*cg + ci)*9 + i];
    int col = ci*4 + (i & 3);
    partials[(size_t)blockIdx.x*(2*F) + ((i < 4) ? col : F + col)] = acc;
  }
}

// ---------------- dual BN stats: stats of na0*X and na1*X in one pass ----------------
__global__ __launch_bounds__(1024) void bnstats_dual(const float* __restrict__ X,
                                                     const float* __restrict__ na,
                                                     float* __restrict__ partials){
  __shared__ float lds[1024*17];
  const int t = threadIdx.x;
  const int cid = t & 127;
  const int rid = t >> 7;           // 0..7
  float sC[4]={0,0,0,0}, qC[4]={0,0,0,0}, sO[4]={0,0,0,0}, qO[4]={0,0,0,0};
  const int rowsPer = (NN + BNG - 1)/BNG;
  int r0 = blockIdx.x*rowsPer, r1 = r0 + rowsPer; if (r1 > NN) r1 = NN;
  for (int r = r0 + rid; r < r1; r += 8){
    float a0 = na[2*r], a1 = na[2*r+1];
    float4 v = *(const float4*)&X[(size_t)r*HID + cid*4];
    float e[4] = {v.x, v.y, v.z, v.w};
#pragma unroll
    for (int i=0;i<4;i++){
      float vc = e[i]*a0, vo = e[i]*a1;
      sC[i]+=vc; qC[i]+=vc*vc; sO[i]+=vo; qO[i]+=vo*vo;
    }
  }
  int base = (rid*128 + cid)*17;
#pragma unroll
  for (int i=0;i<4;i++){
    lds[base+i]=sC[i]; lds[base+4+i]=qC[i]; lds[base+8+i]=sO[i]; lds[base+12+i]=qO[i];
  }
  __syncthreads();
  for (int idx = t; idx < 2048; idx += 1024){
    int ci = idx >> 4, i = idx & 15;
    float acc = 0.f;
    for (int g=0; g<8; ++g) acc += lds[(g*128 + ci)*17 + i];
    int grp = i >> 2, col = ci*4 + (i & 3);
    partials[(size_t)blockIdx.x*2048 + grp*HID + col] = acc;
  }
}

// ---------------- BN stats stage 2: reduce partials -> mean, rstd ----------------
__global__ void bnfin_red(const float* __restrict__ partials, int stride, int off,
                          int M, int F, float* __restrict__ mstat){
  __shared__ float lds[4][64][2];
  int t = threadIdx.x;
  int cl = t & 63, ch = t >> 6;
  int c = blockIdx.x*64 + cl;
  float s = 0.f, q = 0.f;
  if (c < F){
    for (int b = ch*64; b < ch*64 + 64; ++b){
      s += partials[(size_t)b*stride + off + c];
      q += partials[(size_t)b*stride + off + F + c];
    }
  }
  lds[ch][cl][0] = s; lds[ch][cl][1] = q;
  __syncthreads();
  if (ch == 0 && c < F){
    s = lds[0][cl][0]+lds[1][cl][0]+lds[2][cl][0]+lds[3][cl][0];
    q = lds[0][cl][1]+lds[1][cl][1]+lds[2][cl][1]+lds[3][cl][1];
    float m = s/(float)M;
    float v = q/(float)M - m*m;
    mstat[c] = m;
    mstat[F+c] = rsqrtf(v + 1e-5f);
  }
}

// ---------------- (BN ->) bf16 cast; mstat==nullptr means raw cast ----------------
__global__ void bncast(const float* __restrict__ X, const float* __restrict__ mstat,
                       int M, int F, unsigned short* __restrict__ out){
  int idx = blockIdx.x*blockDim.x + threadIdx.x;
  int total4 = M*F/4;
  if (idx >= total4) return;
  int base = idx*4;
  int c = base & (F-1);
  float4 v = *(const float4*)&X[base];
  ushort4v o;
  if (mstat){
    o[0] = f2bf((v.x - mstat[c+0])*mstat[F+c+0] + 1e-4f);
    o[1] = f2bf((v.y - mstat[c+1])*mstat[F+c+1] + 1e-4f);
    o[2] = f2bf((v.z - mstat[c+2])*mstat[F+c+2] + 1e-4f);
    o[3] = f2bf((v.w - mstat[c+3])*mstat[F+c+3] + 1e-4f);
  } else {
    o[0] = f2bf(v.x); o[1] = f2bf(v.y); o[2] = f2bf(v.z); o[3] = f2bf(v.w);
  }
  *(ushort4v*)&out[base] = o;
}

// ---------------- CSR build ----------------
__global__ void csr_count(const int* __restrict__ ei, int* __restrict__ cnt){
  int e = blockIdx.x*blockDim.x + threadIdx.x;
  if (e < NE) atomicAdd(&cnt[ei[e]], 1);
}

__global__ __launch_bounds__(1024) void scan1(const int* __restrict__ cnt, int* __restrict__ rowp,
                                              float* __restrict__ dis1, int* __restrict__ bsum){
  __shared__ int buf[1024];
  int t = threadIdx.x;
  int i = blockIdx.x*1024 + t;
  int v = 0;
  if (i < NN){ v = cnt[i] + 1; dis1[i] = rsqrtf((float)v); }
  buf[t] = v;
  __syncthreads();
  for (int off=1; off<1024; off<<=1){
    int xv = (t >= off) ? buf[t-off] : 0;
    __syncthreads();
    buf[t] += xv;
    __syncthreads();
  }
  if (i < NN) rowp[i+1] = buf[t];
  if (t == 1023) bsum[blockIdx.x] = buf[1023];
}

__global__ void scan2(int* __restrict__ bsum, int nb){
  if (threadIdx.x == 0){
    int a = 0;
    for (int b=0; b<nb; ++b){ int t = bsum[b]; bsum[b] = a; a += t; }
  }
}

__global__ __launch_bounds__(1024) void scan3(int* __restrict__ rowp, const int* __restrict__ bsum){
  int i = blockIdx.x*1024 + threadIdx.x;
  if (i < NN) rowp[i+1] += bsum[i>>10];
  if (i == 0) rowp[0] = 0;
}

__global__ void csr_fill(const int* __restrict__ ei, const int* __restrict__ rowp,
                         const int* __restrict__ cnt, int* __restrict__ fillc,
                         int* __restrict__ ccol, int* __restrict__ crow, int* __restrict__ ceid){
  int id = blockIdx.x*blockDim.x + threadIdx.x;
  if (id < NE){
    int r = ei[id], c = ei[NE + id];
    int pos = atomicAdd(&fillc[r], 1);
    int idx = rowp[r] + pos;
    ccol[idx] = c; crow[idx] = r; ceid[idx] = id;
  } else if (id < NE + NN){
    int i = id - NE;
    int idx = rowp[i] + cnt[i];
    ccol[idx] = i; crow[idx] = i; ceid[idx] = -1;
  }
}

__global__ void w1_kernel(const int* __restrict__ crow, const int* __restrict__ ccol,
                          const float* __restrict__ dis1, float* __restrict__ w1){
  int j = blockIdx.x*blockDim.x + threadIdx.x;
  if (j < NE + NN) w1[j] = dis1[crow[j]] * dis1[ccol[j]];
}

// ---------------- attention ----------------
__global__ void att_node(const float* __restrict__ X, const float* __restrict__ nW,
                         const float* __restrict__ nb, const float* __restrict__ eW,
                         float* __restrict__ na, float* __restrict__ eab){
  int wv = blockIdx.x*4 + (threadIdx.x >> 6);
  int l = threadIdx.x & 63;
  if (wv >= NN) return;
  const float4* xr = (const float4*)(X + (size_t)wv*HID);
  float4 u0 = xr[l*2], u1 = xr[l*2+1];
  float xv[8] = {u0.x,u0.y,u0.z,u0.w,u1.x,u1.y,u1.z,u1.w};
  float s0=0,s1=0,s2=0,s3=0,s4=0,s5=0;
#pragma unroll
  for (int j=0; j<8; ++j){
    int k = l*8 + j;
    float x = xv[j];
    s0 += x * nW[2*k];       s1 += x * nW[2*k+1];
    s2 += x * eW[2*k];       s3 += x * eW[2*k+1];
    s4 += x * eW[2*(512+k)]; s5 += x * eW[2*(512+k)+1];
  }
  for (int m=1; m<64; m<<=1){
    s0 += __shfl_xor(s0,m); s1 += __shfl_xor(s1,m); s2 += __shfl_xor(s2,m);
    s3 += __shfl_xor(s3,m); s4 += __shfl_xor(s4,m); s5 += __shfl_xor(s5,m);
  }
  if (l == 0){
    float z0 = s0 + nb[0], z1 = s1 + nb[1];
    float mx = fmaxf(z0,z1);
    float e0 = expf(z0-mx), e1 = expf(z1-mx);
    float inv = 1.0f/(e0+e1);
    na[2*wv] = e0*inv; na[2*wv+1] = e1*inv;
    eab[4*wv] = s2; eab[4*wv+1] = s3; eab[4*wv+2] = s4; eab[4*wv+3] = s5;
  }
}

__global__ void att_edge(const int* __restrict__ ei, const float* __restrict__ eab,
                         const float* __restrict__ eb, float* __restrict__ att,
                         float* __restrict__ degc, float* __restrict__ dego){
  int e = blockIdx.x*blockDim.x + threadIdx.x;
  if (e >= NE) return;
  int r = ei[e], c = ei[NE+e];
  float z0 = eab[4*r]   + eab[4*c+2] + eb[0];
  float z1 = eab[4*r+1] + eab[4*c+3] + eb[1];
  float mx = fmaxf(z0,z1);
  float e0 = expf(z0-mx), e1 = expf(z1-mx);
  float inv = 1.0f/(e0+e1);
  float a0 = e0*inv, a1 = e1*inv;
  att[2*e] = a0; att[2*e+1] = a1;
  atomicAdd(&degc[r], a0);
  atomicAdd(&dego[r], a1);
}

// norm weights; fold source node-attention into the edge weight; per-row plain-weight sums
__global__ void wco_kernel(const int* __restrict__ crow, const int* __restrict__ ccol,
                           const int* __restrict__ ceid, const float* __restrict__ att,
                           const float* __restrict__ degc, const float* __restrict__ dego,
                           const float* __restrict__ na,
                           float* __restrict__ wcv, float* __restrict__ wov,
                           float* __restrict__ Sc, float* __restrict__ So){
  int j = blockIdx.x*blockDim.x + threadIdx.x;
  if (j >= NE + NN) return;
  int r = crow[j], c = ccol[j], e = ceid[j];
  float a0 = (e < 0) ? 1.0f : att[2*e];
  float a1 = (e < 0) ? 1.0f : att[2*e+1];
  float wc = rsqrtf(degc[r]) * a0 * rsqrtf(degc[c]);
  float wo = rsqrtf(dego[r]) * a1 * rsqrtf(dego[c]);
  wcv[j] = wc * na[2*c];
  wov[j] = wo * na[2*c+1];
  atomicAdd(&Sc[r], wc);
  atomicAdd(&So[r], wo);
}

// ---------------- wave-per-row CSR aggregation (bf16 table, f32 acc) ----------------
__global__ __launch_bounds__(256) void aggregate_w(const unsigned short* __restrict__ A,
                                                   const int* __restrict__ rowp,
                                                   const int* __restrict__ ccol,
                                                   const float* __restrict__ wv,
                                                   unsigned short* __restrict__ out){
  int row = blockIdx.x*4 + (threadIdx.x >> 6);
  int l = threadIdx.x & 63;
  const uint4* Av = (const uint4*)A;
  int s = rowp[row], e = rowp[row+1];
  float acc[8] = {0,0,0,0,0,0,0,0};
  int j = s;
  for (; j+1 < e; j += 2){
    int c0 = ccol[j], c1 = ccol[j+1];
    float w0 = wv[j], w1 = wv[j+1];
    uint4 v0 = Av[(size_t)c0*64 + l];
    uint4 v1 = Av[(size_t)c1*64 + l];
    fma8(acc, v0, w0);
    fma8(acc, v1, w1);
  }
  if (j < e){
    uint4 v = Av[(size_t)ccol[j]*64 + l];
    fma8(acc, v, wv[j]);
  }
  uint4 o;
  o.x = pk2(acc[0],acc[1]); o.y = pk2(acc[2],acc[3]);
  o.z = pk2(acc[4],acc[5]); o.w = pk2(acc[6],acc[7]);
  ((uint4*)out)[(size_t)row*64 + l] = o;
}

// dual aggregation over shared raw table, with per-branch BN affine applied in epilogue:
// out_rc = rs_c * sum_j w'_j x[col_j,c] + S_r*(1e-4 - m_c*rs_c)
__global__ __launch_bounds__(256) void aggregate_dual(const unsigned short* __restrict__ A,
                                                      const int* __restrict__ rowp,
                                                      const int* __restrict__ ccol,
                                                      const float* __restrict__ wc,
                                                      const float* __restrict__ wo,
                                                      const float* __restrict__ Sc,
                                                      const float* __restrict__ So,
                                                      const float* __restrict__ mstatC,
                                                      const float* __restrict__ mstatO,
                                                      unsigned short* __restrict__ outC,
                                                      unsigned short* __restrict__ outO){
  int row = blockIdx.x*4 + (threadIdx.x >> 6);
  int l = threadIdx.x & 63;
  const uint4* Av = (const uint4*)A;
  int s = rowp[row], e = rowp[row+1];
  float aC[8] = {0,0,0,0,0,0,0,0};
  float aO[8] = {0,0,0,0,0,0,0,0};
  int j = s;
  for (; j+1 < e; j += 2){
    int c0 = ccol[j], c1 = ccol[j+1];
    float wc0 = wc[j], wc1 = wc[j+1];
    float wo0 = wo[j], wo1 = wo[j+1];
    uint4 v0 = Av[(size_t)c0*64 + l];
    uint4 v1 = Av[(size_t)c1*64 + l];
    fma8(aC, v0, wc0); fma8(aO, v0, wo0);
    fma8(aC, v1, wc1); fma8(aO, v1, wo1);
  }
  if (j < e){
    uint4 v = Av[(size_t)ccol[j]*64 + l];
    fma8(aC, v, wc[j]); fma8(aO, v, wo[j]);
  }
  float ScR = Sc[row], SoR = So[row];
  const float4* mC = (const float4*)mstatC;          // [0..127]=mean4, [128..255]=rstd4
  const float4* mO = (const float4*)mstatO;
  float4 mc0 = mC[l*2], mc1 = mC[l*2+1], rc0 = mC[128+l*2], rc1 = mC[128+l*2+1];
  float4 mo0 = mO[l*2], mo1 = mO[l*2+1], ro0 = mO[128+l*2], ro1 = mO[128+l*2+1];
  float mcv[8] = {mc0.x,mc0.y,mc0.z,mc0.w,mc1.x,mc1.y,mc1.z,mc1.w};
  float rcv[8] = {rc0.x,rc0.y,rc0.z,rc0.w,rc1.x,rc1.y,rc1.z,rc1.w};
  float mov[8] = {mo0.x,mo0.y,mo0.z,mo0.w,mo1.x,mo1.y,mo1.z,mo1.w};
  float rov[8] = {ro0.x,ro0.y,ro0.z,ro0.w,ro1.x,ro1.y,ro1.z,ro1.w};
  float gC[8], gO[8];
#pragma unroll
  for (int i=0;i<8;i++){
    gC[i] = rcv[i]*aC[i] + ScR*(1e-4f - mcv[i]*rcv[i]);
    gO[i] = rov[i]*aO[i] + SoR*(1e-4f - mov[i]*rov[i]);
  }
  uint4 oc, oo;
  oc.x = pk2(gC[0],gC[1]); oc.y = pk2(gC[2],gC[3]); oc.z = pk2(gC[4],gC[5]); oc.w = pk2(gC[6],gC[7]);
  oo.x = pk2(gO[0],gO[1]); oo.y = pk2(gO[2],gO[3]); oo.z = pk2(gO[4],gO[5]); oo.w = pk2(gO[6],gO[7]);
  ((uint4*)outC)[(size_t)row*64 + l] = oc;
  ((uint4*)outO)[(size_t)row*64 + l] = oo;
}

// ---------------- bf16 MFMA GEMM: C[M,512] = A[M,K] @ Bt[N=512,K]^T + bias (opt relu) ----------------
__global__ __launch_bounds__(256) void gemm_bt(const unsigned short* __restrict__ A,
                                               const unsigned short* __restrict__ Bt,
                                               float* __restrict__ C,
                                               const float* __restrict__ bias,
                                               int M, int K, int relu){
  __shared__ unsigned short As[128*32];
  __shared__ unsigned short Bs[128*32];
  const int tid = threadIdx.x;
  const int w = tid >> 6, l = tid & 63;
  const int m0 = blockIdx.x*128, n0 = blockIdx.y*128;
  const int wm = w >> 1, wn = w & 1;
  const int lr = l & 15, lh = l >> 4;

  f32x4 acc[4][4];
#pragma unroll
  for (int i=0;i<4;i++)
#pragma unroll
    for (int j=0;j<4;j++) acc[i][j] = 0.0f;

  const int q0 = w*2, q1 = w*2+1;
  const int sub = l >> 2;
  const int kc  = (l & 3)*8;
  int ma0 = m0 + q0*16 + sub; if (ma0 >= M) ma0 = M-1;
  int ma1 = m0 + q1*16 + sub; if (ma1 >= M) ma1 = M-1;
  const int nb0 = n0 + q0*16 + sub;
  const int nb1 = n0 + q1*16 + sub;

  for (int k0=0; k0<K; k0+=32){
    gload16(&As[q0*512], A + (size_t)ma0*K + k0 + kc);
    gload16(&As[q1*512], A + (size_t)ma1*K + k0 + kc);
    gload16(&Bs[q0*512], Bt + (size_t)nb0*K + k0 + kc);
    gload16(&Bs[q1*512], Bt + (size_t)nb1*K + k0 + kc);
    __syncthreads();
    short8 af[4], bfr[4];
#pragma unroll
    for (int fm=0; fm<4; ++fm) af[fm]  = *(const short8*)&As[(wm*64 + fm*16 + lr)*32 + lh*8];
#pragma unroll
    for (int fn=0; fn<4; ++fn) bfr[fn] = *(const short8*)&Bs[(wn*64 + fn*16 + lr)*32 + lh*8];
#pragma unroll
    for (int fm=0; fm<4; ++fm)
#pragma unroll
      for (int fn=0; fn<4; ++fn)
        acc[fm][fn] = __builtin_amdgcn_mfma_f32_16x16x32_bf16(af[fm], bfr[fn], acc[fm][fn], 0, 0, 0);
    __syncthreads();
  }
#pragma unroll
  for (int fm=0; fm<4; ++fm){
#pragma unroll
    for (int j=0; j<4; ++j){
      int row = m0 + wm*64 + fm*16 + lh*4 + j;
      if (row < M){
#pragma unroll
        for (int fn=0; fn<4; ++fn){
          int col = n0 + wn*64 + fn*16 + lr;
          float v = acc[fm][fn][j] + bias[col];
          if (relu) v = fmaxf(v, 0.f);
          C[(size_t)row*HID + col] = v;
        }
      }
    }
  }
}

// ---------------- pooling ----------------
__global__ void pool_kernel(const float* __restrict__ X, const int* __restrict__ batch,
                            float* __restrict__ out){
  int g = blockIdx.x;
  int t = threadIdx.x;
  int lo = 0, hi = NN;
  while (lo < hi){ int mid = (lo+hi) >> 1; if (batch[mid] < g) lo = mid+1; else hi = mid; }
  int s = lo;
  lo = 0; hi = NN;
  while (lo < hi){ int mid = (lo+hi) >> 1; if (batch[mid] < g+1) lo = mid+1; else hi = mid; }
  int e = lo;
  float a0 = 0.f, a1 = 0.f;
  for (int i=s; i<e; ++i){
    float2 v = *(const float2*)&X[(size_t)i*HID + t*2];
    a0 += v.x; a1 += v.y;
  }
  out[(size_t)g*HID + t*2]     = a0;
  out[(size_t)g*HID + t*2 + 1] = a1;
}

__global__ void addperm(const float* __restrict__ gc, const float* __restrict__ go,
                        const int* __restrict__ perm, float* __restrict__ gco){
  int g = blockIdx.x;
  int t = threadIdx.x;
  int ps = perm[g];
  for (int k=t; k<HID; k+=256)
    gco[(size_t)g*HID + k] = gc[(size_t)ps*HID + k] + go[(size_t)g*HID + k];
}

// ---------------- final: BN -> fc2 -> log_softmax (fp32) ----------------
__global__ void readout_final(const float* __restrict__ T, const float* __restrict__ mstat,
                              const float* __restrict__ W2, const float* __restrict__ b2,
                              float* __restrict__ out){
  int g = blockIdx.x;
  int l = threadIdx.x;
  float acc[NCLS];
#pragma unroll
  for (int c=0; c<NCLS; ++c) acc[c] = 0.f;
  const float* tr = T + (size_t)g*HID;
#pragma unroll
  for (int j=0; j<8; ++j){
    int k = l*8 + j;
    float v = (tr[k] - mstat[k]) * mstat[HID+k] + 1e-4f;
#pragma unroll
    for (int c=0; c<NCLS; ++c) acc[c] += v * W2[k*NCLS + c];
  }
  for (int m=1; m<64; m<<=1){
#pragma unroll
    for (int c=0; c<NCLS; ++c) acc[c] += __shfl_xor(acc[c], m);
  }
  if (l == 0){
    float z[NCLS];
    float mx = -1e30f;
#pragma unroll
    for (int c=0; c<NCLS; ++c){ z[c] = acc[c] + b2[c]; mx = fmaxf(mx, z[c]); }
    float s = 0.f;
#pragma unroll
    for (int c=0; c<NCLS; ++c) s += expf(z[c]-mx);
    float lse = mx + logf(s);
#pragma unroll
    for (int c=0; c<NCLS; ++c) out[(size_t)g*NCLS + c] = z[c] - lse;
  }
}

extern "C" void kernel_launch(void* const* d_in, const int* in_sizes, int n_in,
                              void* d_out, int out_size, void* d_ws, size_t ws_size,
                              hipStream_t stream){
  (void)in_sizes; (void)n_in; (void)out_size;
  const float* x      = (const float*)d_in[0];
  const int*   ei     = (const int*)d_in[1];
  const int*   batch  = (const int*)d_in[2];
  const int*   perm   = (const int*)d_in[3];
  const float* convfW = (const float*)d_in[4];
  const float* convfB = (const float*)d_in[5];
  const float* convsW = (const float*)d_in[6];
  const float* convsB = (const float*)d_in[7];
  const float* eattW  = (const float*)d_in[8];
  const float* eattB  = (const float*)d_in[9];
  const float* nattW  = (const float*)d_in[10];
  const float* nattB  = (const float*)d_in[11];
  const float* ctxW   = (const float*)d_in[12];
  const float* ctxB   = (const float*)d_in[13];
  const float* objW   = (const float*)d_in[14];
  const float* objB   = (const float*)d_in[15];
  const float* fc1W[3] = {(const float*)d_in[16], (const float*)d_in[20], (const float*)d_in[24]};
  const float* fc1B[3] = {(const float*)d_in[17], (const float*)d_in[21], (const float*)d_in[25]};
  const float* fc2W[3] = {(const float*)d_in[18], (const float*)d_in[22], (const float*)d_in[26]};
  const float* fc2B[3] = {(const float*)d_in[19], (const float*)d_in[23], (const float*)d_in[27]};
  float* out = (float*)d_out;

  char* p = (char*)d_ws;
  auto alloc = [&](size_t bytes)->char*{ char* r = p; p += (bytes + 255) & ~((size_t)255); return r; };
  const int T = NE + NN;
  float* Xa = (float*)alloc((size_t)NN*HID*4);
  float* Xb = (float*)alloc((size_t)NN*HID*4);
  unsigned short* Abf = (unsigned short*)alloc((size_t)NN*HID*2);
  unsigned short* Gbf = (unsigned short*)alloc((size_t)NN*HID*2);
  unsigned short* WtF = (unsigned short*)alloc((size_t)HID*FIN*2);
  unsigned short* WtL = (unsigned short*)alloc((size_t)3*HID*HID*2);
  unsigned short* WtC = (unsigned short*)alloc((size_t)HID*HID*2);
  unsigned short* WtO = (unsigned short*)alloc((size_t)HID*HID*2);
  unsigned short* WtR = (unsigned short*)alloc((size_t)3*HID*HID*2);
  int* cnt   = (int*)alloc((size_t)NN*4);
  int* fillc = (int*)alloc((size_t)NN*4);
  int* rowp  = (int*)alloc((size_t)(NN+1)*4);
  int* bsum  = (int*)alloc(32*4);
  int* ccol  = (int*)alloc((size_t)T*4);
  int* crow  = (int*)alloc((size_t)T*4);
  int* ceid  = (int*)alloc((size_t)T*4);
  float* w1  = (float*)alloc((size_t)T*4);
  float* wcv = (float*)alloc((size_t)T*4);
  float* wov = (float*)alloc((size_t)T*4);
  float* dis1 = (float*)alloc((size_t)NN*4);
  float* degc = (float*)alloc((size_t)NN*4);
  float* dego = (float*)alloc((size_t)NN*4);
  float* Sc   = (float*)alloc((size_t)NN*4);
  float* So   = (float*)alloc((size_t)NN*4);
  float* mstat = (float*)alloc(2*HID*4);
  float* mstatC= (float*)alloc(2*HID*4);
  float* mstatO= (float*)alloc(2*HID*4);
  float* na   = (float*)alloc((size_t)NN*2*4);
  float* eab  = (float*)alloc((size_t)NN*4*4);
  float* att  = (float*)alloc((size_t)NE*2*4);
  float* gc   = (float*)alloc((size_t)NG*HID*4);
  float* go   = (float*)alloc((size_t)NG*HID*4);
  float* gco  = (float*)alloc((size_t)NG*HID*4);
  float* part = (float*)Gbf;   // BN partials alias Gbf (disjoint lifetimes: partials consumed before aggregate writes Gbf)
  if ((size_t)(p - (char*)d_ws) > ws_size){
    sentinel_k<<<1,1,0,stream>>>(out);
    return;
  }

  // weights -> bf16 transposed (one dispatch)
  W2BT wp;
  wp.src[0]=convfW; wp.dst[0]=WtF;
  for (int i=0;i<3;i++){ wp.src[1+i]=convsW+(size_t)i*HID*HID; wp.dst[1+i]=WtL+(size_t)i*HID*HID; }
  wp.src[4]=ctxW; wp.dst[4]=WtC;
  wp.src[5]=objW; wp.dst[5]=WtO;
  for (int i=0;i<3;i++){ wp.src[6+i]=fc1W[i]; wp.dst[6+i]=WtR+(size_t)i*HID*HID; }
  w2bt_all<<<(FIN*HID + 8*HID*HID + 255)/256, 256, 0, stream>>>(wp);

  init_misc<<<(NN+255)/256,256,0,stream>>>(cnt, fillc, degc, dego, Sc, So);

  // CSR build
  csr_count<<<(NE+255)/256,256,0,stream>>>(ei, cnt);
  scan1<<<(NN+1023)/1024,1024,0,stream>>>(cnt, rowp, dis1, bsum);
  scan2<<<1,64,0,stream>>>(bsum, (NN+1023)/1024);
  scan3<<<(NN+1023)/1024,1024,0,stream>>>(rowp, bsum);
  csr_fill<<<(T+255)/256,256,0,stream>>>(ei, rowp, cnt, fillc, ccol, crow, ceid);
  w1_kernel<<<(T+255)/256,256,0,stream>>>(crow, ccol, dis1, w1);

  // conv_feat: relu(bn(x) @ Wf + bf)
  bnstats_p<<<BNG,1024,0,stream>>>(x, NN, FIN, part);
  bnfin_red<<<(FIN+63)/64,256,0,stream>>>(part, 2*FIN, 0, NN, FIN, mstat);
  bncast<<<((NN*FIN/4)+255)/256,256,0,stream>>>(x, mstat, NN, FIN, Abf);
  gemm_bt<<<dim3((NN+127)/128,4),256,0,stream>>>(Abf, WtF, Xa, convfB, NN, FIN, 1);

  // 3 GCN layers
  for (int i=0;i<3;i++){
    bnstats_p<<<BNG,1024,0,stream>>>(Xa, NN, HID, part);
    bnfin_red<<<(HID+63)/64,256,0,stream>>>(part, 2*HID, 0, NN, HID, mstat);
    bncast<<<((NN*HID/4)+255)/256,256,0,stream>>>(Xa, mstat, NN, HID, Abf);
    aggregate_w<<<NN/4,256,0,stream>>>(Abf, rowp, ccol, w1, Gbf);
    gemm_bt<<<dim3((NN+127)/128,4),256,0,stream>>>(Gbf, WtL+(size_t)i*HID*HID, Xb, convsB+(size_t)i*HID, NN, HID, 1);
    float* tmp = Xa; Xa = Xb; Xb = tmp;
  }

  // attention
  att_node<<<(NN+3)/4,256,0,stream>>>(Xa, nattW, nattB, eattW, na, eab);
  att_edge<<<(NE+255)/256,256,0,stream>>>(ei, eab, eattB, att, degc, dego);
  wco_kernel<<<(T+255)/256,256,0,stream>>>(crow, ccol, ceid, att, degc, dego, na, wcv, wov, Sc, So);

  // ctx + obj branches (shared raw table + dual aggregate with BN affine folded in)
  bnstats_dual<<<BNG,1024,0,stream>>>(Xa, na, part);
  bnfin_red<<<(HID+63)/64,256,0,stream>>>(part, 4*HID, 0,     NN, HID, mstatC);
  bnfin_red<<<(HID+63)/64,256,0,stream>>>(part, 4*HID, 2*HID, NN, HID, mstatO);
  bncast<<<((NN*HID/4)+255)/256,256,0,stream>>>(Xa, nullptr, NN, HID, Abf);
  unsigned short* GbfO = (unsigned short*)Xa;   // Xa dead after the cast; reuse as second output
  aggregate_dual<<<NN/4,256,0,stream>>>(Abf, rowp, ccol, wcv, wov, Sc, So, mstatC, mstatO, Gbf, GbfO);
  gemm_bt<<<dim3((NN+127)/128,4),256,0,stream>>>(Gbf, WtC, Xb, ctxB, NN, HID, 1);
  pool_kernel<<<NG,256,0,stream>>>(Xb, batch, gc);
  gemm_bt<<<dim3((NN+127)/128,4),256,0,stream>>>(GbfO, WtO, Xb, objB, NN, HID, 1);
  pool_kernel<<<NG,256,0,stream>>>(Xb, batch, go);

  // xco = gc[perm] + go
  addperm<<<NG,256,0,stream>>>(gc, go, perm, gco);

  // readouts
  const float* gin[3] = {gc, go, gco};
  for (int r=0;r<3;r++){
    bnstats_p<<<BNG,1024,0,stream>>>(gin[r], NG, HID, part);
    bnfin_red<<<(HID+63)/64,256,0,stream>>>(part, 2*HID, 0, NG, HID, mstat);
    bncast<<<((NG*HID/4)+255)/256,256,0,stream>>>(gin[r], mstat, NG, HID, Abf);
    gemm_bt<<<dim3((NG+127)/128,4),256,0,stream>>>(Abf, WtR+(size_t)r*HID*HID, Xb, fc1B[r], NG, HID, 1);
    bnstats_p<<<BNG,1024,0,stream>>>(Xb, NG, HID, part);
    bnfin_red<<<(HID+63)/64,256,0,stream>>>(part, 2*HID, 0, NG, HID, mstat);
    readout_final<<<NG,64,0,stream>>>(Xb, mstat, fc2W[r], fc2B[r], out + (size_t)r*NG*NCLS);
  }
}

// Round 4
// 631.990 us; speedup vs baseline: 1.6252x; 1.2586x over previous
//
#include <hip/hip_runtime.h>
#include <stdint.h>

#define NN 20000
#define NE 160000
#define NG 500
#define FIN 128
#define HID 512
#define NCLS 10
#define BNG 256

typedef __attribute__((ext_vector_type(8))) short short8;
typedef __attribute__((ext_vector_type(4))) float f32x4;
typedef __attribute__((ext_vector_type(4))) unsigned short ushort4v;

__device__ __forceinline__ float bf2f(unsigned int u){
  union{unsigned int i; float f;} x; x.i = u<<16; return x.f;
}
__device__ __forceinline__ unsigned short f2bf(float f){
  union{float f; unsigned int i;} x; x.f=f;
  unsigned int r = x.i + 0x7fffu + ((x.i>>16)&1u);
  return (unsigned short)(r>>16);
}
__device__ __forceinline__ unsigned int pk2(float a, float b){
  return (unsigned int)f2bf(a) | ((unsigned int)f2bf(b) << 16);
}

__device__ __forceinline__ void gload16(unsigned short* lds, const unsigned short* g){
  __builtin_amdgcn_global_load_lds((const __attribute__((address_space(1))) unsigned int*)g,
                                   (__attribute__((address_space(3))) unsigned int*)lds,
                                   16, 0, 0);
}

__device__ __forceinline__ void fma8(float* acc, uint4 v, float w){
  acc[0] += w*bf2f(v.x & 0xffffu); acc[1] += w*bf2f(v.x >> 16);
  acc[2] += w*bf2f(v.y & 0xffffu); acc[3] += w*bf2f(v.y >> 16);
  acc[4] += w*bf2f(v.z & 0xffffu); acc[5] += w*bf2f(v.z >> 16);
  acc[6] += w*bf2f(v.w & 0xffffu); acc[7] += w*bf2f(v.w >> 16);
}

__global__ void sentinel_k(float* out){ out[0] = 12345.0f; }

// ---------------- all weight transposes+casts in one dispatch ----------------
struct W2BT { const float* src[9]; unsigned short* dst[9]; };
__global__ void w2bt_all(W2BT p){
  int idx = blockIdx.x*blockDim.x + threadIdx.x;
  int seg, off, K;
  if (idx < FIN*HID){ seg = 0; off = idx; K = FIN; }
  else {
    int r = idx - FIN*HID;
    if (r >= 8*HID*HID) return;
    seg = 1 + (r >> 18); off = r & (HID*HID-1); K = HID;
  }
  int k = off >> 9, n = off & 511;
  p.dst[seg][(size_t)n*K + k] = f2bf(p.src[seg][off]);
}

// ---------------- init: counters/flags + zero the 6 gemm-stats buffers ----------------
__global__ void init_misc(int* __restrict__ cnt, int* __restrict__ fillc,
                          float* __restrict__ degc, float* __restrict__ dego,
                          float* __restrict__ Sc, float* __restrict__ So,
                          float* __restrict__ stats6){
  int i = blockIdx.x*blockDim.x + threadIdx.x;
  if (i < NN){ cnt[i]=0; fillc[i]=0; degc[i]=1.0f; dego[i]=1.0f; Sc[i]=0.f; So[i]=0.f; }
  if (i < 6*1024) stats6[i] = 0.f;
}

// ---------------- BN stats stage 1 (f32 input; used for conv input + readout BN1) ----------------
__global__ __launch_bounds__(1024) void bnstats_p(const float* __restrict__ X, int M, int F,
                                                  float* __restrict__ partials){
  __shared__ float lds[1024*9];
  const int t = threadIdx.x;
  const int cg = F >> 2;
  const int cid = t & (cg-1);
  const int rid = t / cg;
  const int rpb = 1024 / cg;
  float s0=0,s1=0,s2=0,s3=0,q0=0,q1=0,q2=0,q3=0;
  const int rowsPer = (M + BNG - 1)/BNG;
  int r0 = blockIdx.x*rowsPer, r1 = r0 + rowsPer; if (r1 > M) r1 = M;
  for (int r = r0 + rid; r < r1; r += rpb){
    float4 v = *(const float4*)&X[(size_t)r*F + cid*4];
    s0+=v.x; q0+=v.x*v.x; s1+=v.y; q1+=v.y*v.y; s2+=v.z; q2+=v.z*v.z; s3+=v.w; q3+=v.w*v.w;
  }
  int base = (rid*cg + cid)*9;
  lds[base+0]=s0; lds[base+1]=s1; lds[base+2]=s2; lds[base+3]=s3;
  lds[base+4]=q0; lds[base+5]=q1; lds[base+6]=q2; lds[base+7]=q3;
  __syncthreads();
  if (t < cg*8){
    int ci = t >> 3, i = t & 7;
    float acc = 0.f;
    for (int g=0; g<rpb; ++g) acc += lds[(g*cg + ci)*9 + i];
    int col = ci*4 + (i & 3);
    partials[(size_t)blockIdx.x*(2*F) + ((i < 4) ? col : F + col)] = acc;
  }
}

// ---------------- dual BN stats on bf16 X: stats of na0*X and na1*X in one pass ----------------
__global__ __launch_bounds__(1024) void bnstats_dual(const unsigned short* __restrict__ X,
                                                     const float* __restrict__ na,
                                                     float* __restrict__ partials){
  __shared__ float lds[1024*17];
  const int t = threadIdx.x;
  const int cid = t & 127;
  const int rid = t >> 7;
  float sC[4]={0,0,0,0}, qC[4]={0,0,0,0}, sO[4]={0,0,0,0}, qO[4]={0,0,0,0};
  const int rowsPer = (NN + BNG - 1)/BNG;
  int r0 = blockIdx.x*rowsPer, r1 = r0 + rowsPer; if (r1 > NN) r1 = NN;
  for (int r = r0 + rid; r < r1; r += 8){
    float a0 = na[2*r], a1 = na[2*r+1];
    uint2 u = *(const uint2*)&X[(size_t)r*HID + cid*4];
    float e[4] = {bf2f(u.x & 0xffffu), bf2f(u.x >> 16), bf2f(u.y & 0xffffu), bf2f(u.y >> 16)};
#pragma unroll
    for (int i=0;i<4;i++){
      float vc = e[i]*a0, vo = e[i]*a1;
      sC[i]+=vc; qC[i]+=vc*vc; sO[i]+=vo; qO[i]+=vo*vo;
    }
  }
  int base = (rid*128 + cid)*17;
#pragma unroll
  for (int i=0;i<4;i++){
    lds[base+i]=sC[i]; lds[base+4+i]=qC[i]; lds[base+8+i]=sO[i]; lds[base+12+i]=qO[i];
  }
  __syncthreads();
  for (int idx = t; idx < 2048; idx += 1024){
    int ci = idx >> 4, i = idx & 15;
    float acc = 0.f;
    for (int g=0; g<8; ++g) acc += lds[(g*128 + ci)*17 + i];
    int grp = i >> 2, col = ci*4 + (i & 3);
    partials[(size_t)blockIdx.x*2048 + grp*HID + col] = acc;
  }
}

// ---------------- BN stats stage 2: reduce partials -> mean, rstd ----------------
__global__ void bnfin_red(const float* __restrict__ partials, int stride, int off,
                          int M, int F, float* __restrict__ mstat){
  __shared__ float lds[4][64][2];
  int t = threadIdx.x;
  int cl = t & 63, ch = t >> 6;
  int c = blockIdx.x*64 + cl;
  float s = 0.f, q = 0.f;
  if (c < F){
    for (int b = ch*64; b < ch*64 + 64; ++b){
      s += partials[(size_t)b*stride + off + c];
      q += partials[(size_t)b*stride + off + F + c];
    }
  }
  lds[ch][cl][0] = s; lds[ch][cl][1] = q;
  __syncthreads();
  if (ch == 0 && c < F){
    s = lds[0][cl][0]+lds[1][cl][0]+lds[2][cl][0]+lds[3][cl][0];
    q = lds[0][cl][1]+lds[1][cl][1]+lds[2][cl][1]+lds[3][cl][1];
    float m = s/(float)M;
    float v = q/(float)M - m*m;
    mstat[c] = m;
    mstat[F+c] = rsqrtf(v + 1e-5f);
  }
}

// ---------------- BN->bf16 cast (f32 input; conv input + readout BN1) ----------------
__global__ void bncast(const float* __restrict__ X, const float* __restrict__ mstat,
                       int M, int F, unsigned short* __restrict__ out){
  int idx = blockIdx.x*blockDim.x + threadIdx.x;
  int total4 = M*F/4;
  if (idx >= total4) return;
  int base = idx*4;
  int c = base & (F-1);
  float4 v = *(const float4*)&X[base];
  ushort4v o;
  o[0] = f2bf((v.x - mstat[c+0])*mstat[F+c+0] + 1e-4f);
  o[1] = f2bf((v.y - mstat[c+1])*mstat[F+c+1] + 1e-4f);
  o[2] = f2bf((v.z - mstat[c+2])*mstat[F+c+2] + 1e-4f);
  o[3] = f2bf((v.w - mstat[c+3])*mstat[F+c+3] + 1e-4f);
  *(ushort4v*)&out[base] = o;
}

// ---------------- CSR build ----------------
__global__ void csr_count(const int* __restrict__ ei, int* __restrict__ cnt){
  int e = blockIdx.x*blockDim.x + threadIdx.x;
  if (e < NE) atomicAdd(&cnt[ei[e]], 1);
}

__global__ __launch_bounds__(1024) void scan1(const int* __restrict__ cnt, int* __restrict__ rowp,
                                              float* __restrict__ dis1, int* __restrict__ bsum){
  __shared__ int buf[1024];
  int t = threadIdx.x;
  int i = blockIdx.x*1024 + t;
  int v = 0;
  if (i < NN){ v = cnt[i] + 1; dis1[i] = rsqrtf((float)v); }
  buf[t] = v;
  __syncthreads();
  for (int off=1; off<1024; off<<=1){
    int xv = (t >= off) ? buf[t-off] : 0;
    __syncthreads();
    buf[t] += xv;
    __syncthreads();
  }
  if (i < NN) rowp[i+1] = buf[t];
  if (t == 1023) bsum[blockIdx.x] = buf[1023];
}

__global__ void scan2(int* __restrict__ bsum, int nb){
  if (threadIdx.x == 0){
    int a = 0;
    for (int b=0; b<nb; ++b){ int t = bsum[b]; bsum[b] = a; a += t; }
  }
}

__global__ __launch_bounds__(1024) void scan3(int* __restrict__ rowp, const int* __restrict__ bsum){
  int i = blockIdx.x*1024 + threadIdx.x;
  if (i < NN) rowp[i+1] += bsum[i>>10];
  if (i == 0) rowp[0] = 0;
}

__global__ void csr_fill(const int* __restrict__ ei, const int* __restrict__ rowp,
                         const int* __restrict__ cnt, int* __restrict__ fillc,
                         int* __restrict__ ccol, int* __restrict__ crow, int* __restrict__ ceid){
  int id = blockIdx.x*blockDim.x + threadIdx.x;
  if (id < NE){
    int r = ei[id], c = ei[NE + id];
    int pos = atomicAdd(&fillc[r], 1);
    int idx = rowp[r] + pos;
    ccol[idx] = c; crow[idx] = r; ceid[idx] = id;
  } else if (id < NE + NN){
    int i = id - NE;
    int idx = rowp[i] + cnt[i];
    ccol[idx] = i; crow[idx] = i; ceid[idx] = -1;
  }
}

__global__ void w1_kernel(const int* __restrict__ crow, const int* __restrict__ ccol,
                          const float* __restrict__ dis1, float* __restrict__ w1){
  int j = blockIdx.x*blockDim.x + threadIdx.x;
  if (j < NE + NN) w1[j] = dis1[crow[j]] * dis1[ccol[j]];
}

// ---------------- attention (bf16 X) ----------------
__global__ void att_node(const unsigned short* __restrict__ X, const float* __restrict__ nW,
                         const float* __restrict__ nb, const float* __restrict__ eW,
                         float* __restrict__ na, float* __restrict__ eab){
  int wv = blockIdx.x*4 + (threadIdx.x >> 6);
  int l = threadIdx.x & 63;
  if (wv >= NN) return;
  uint4 u = ((const uint4*)(X + (size_t)wv*HID))[l];
  float xv[8] = {bf2f(u.x&0xffffu), bf2f(u.x>>16), bf2f(u.y&0xffffu), bf2f(u.y>>16),
                 bf2f(u.z&0xffffu), bf2f(u.z>>16), bf2f(u.w&0xffffu), bf2f(u.w>>16)};
  float s0=0,s1=0,s2=0,s3=0,s4=0,s5=0;
#pragma unroll
  for (int j=0; j<8; ++j){
    int k = l*8 + j;
    float x = xv[j];
    s0 += x * nW[2*k];       s1 += x * nW[2*k+1];
    s2 += x * eW[2*k];       s3 += x * eW[2*k+1];
    s4 += x * eW[2*(512+k)]; s5 += x * eW[2*(512+k)+1];
  }
  for (int m=1; m<64; m<<=1){
    s0 += __shfl_xor(s0,m); s1 += __shfl_xor(s1,m); s2 += __shfl_xor(s2,m);
    s3 += __shfl_xor(s3,m); s4 += __shfl_xor(s4,m); s5 += __shfl_xor(s5,m);
  }
  if (l == 0){
    float z0 = s0 + nb[0], z1 = s1 + nb[1];
    float mx = fmaxf(z0,z1);
    float e0 = expf(z0-mx), e1 = expf(z1-mx);
    float inv = 1.0f/(e0+e1);
    na[2*wv] = e0*inv; na[2*wv+1] = e1*inv;
    eab[4*wv] = s2; eab[4*wv+1] = s3; eab[4*wv+2] = s4; eab[4*wv+3] = s5;
  }
}

__global__ void att_edge(const int* __restrict__ ei, const float* __restrict__ eab,
                         const float* __restrict__ eb, float* __restrict__ att,
                         float* __restrict__ degc, float* __restrict__ dego){
  int e = blockIdx.x*blockDim.x + threadIdx.x;
  if (e >= NE) return;
  int r = ei[e], c = ei[NE+e];
  float z0 = eab[4*r]   + eab[4*c+2] + eb[0];
  float z1 = eab[4*r+1] + eab[4*c+3] + eb[1];
  float mx = fmaxf(z0,z1);
  float e0 = expf(z0-mx), e1 = expf(z1-mx);
  float inv = 1.0f/(e0+e1);
  float a0 = e0*inv, a1 = e1*inv;
  att[2*e] = a0; att[2*e+1] = a1;
  atomicAdd(&degc[r], a0);
  atomicAdd(&dego[r], a1);
}

__global__ void wco_kernel(const int* __restrict__ crow, const int* __restrict__ ccol,
                           const int* __restrict__ ceid, const float* __restrict__ att,
                           const float* __restrict__ degc, const float* __restrict__ dego,
                           const float* __restrict__ na,
                           float* __restrict__ wcv, float* __restrict__ wov,
                           float* __restrict__ Sc, float* __restrict__ So){
  int j = blockIdx.x*blockDim.x + threadIdx.x;
  if (j >= NE + NN) return;
  int r = crow[j], c = ccol[j], e = ceid[j];
  float a0 = (e < 0) ? 1.0f : att[2*e];
  float a1 = (e < 0) ? 1.0f : att[2*e+1];
  float wc = rsqrtf(degc[r]) * a0 * rsqrtf(degc[c]);
  float wo = rsqrtf(dego[r]) * a1 * rsqrtf(dego[c]);
  wcv[j] = wc * na[2*c];
  wov[j] = wo * na[2*c+1];
  atomicAdd(&Sc[r], wc);
  atomicAdd(&So[r], wo);
}

// ---------------- wave-per-row aggregation over raw bf16 X, BN affine in epilogue ----------------
// out_rc = rs_c * sum_j w_j x[col_j,c] + (sum_j w_j)*(1e-4 - m_c*rs_c);  m,rs from raw stats
__global__ __launch_bounds__(256) void aggregate_bn(const unsigned short* __restrict__ A,
                                                    const int* __restrict__ rowp,
                                                    const int* __restrict__ ccol,
                                                    const float* __restrict__ wv,
                                                    const float* __restrict__ stats,
                                                    float invM,
                                                    unsigned short* __restrict__ out){
  int row = blockIdx.x*4 + (threadIdx.x >> 6);
  int l = threadIdx.x & 63;
  const uint4* Av = (const uint4*)A;
  int s = rowp[row], e = rowp[row+1];
  float acc[8] = {0,0,0,0,0,0,0,0};
  float sw = 0.f;
  int j = s;
  for (; j+1 < e; j += 2){
    int c0 = ccol[j], c1 = ccol[j+1];
    float w0 = wv[j], w1 = wv[j+1];
    uint4 v0 = Av[(size_t)c0*64 + l];
    uint4 v1 = Av[(size_t)c1*64 + l];
    fma8(acc, v0, w0);
    fma8(acc, v1, w1);
    sw += w0 + w1;
  }
  if (j < e){
    uint4 v = Av[(size_t)ccol[j]*64 + l];
    fma8(acc, v, wv[j]);
    sw += wv[j];
  }
  float g[8];
#pragma unroll
  for (int i=0;i<8;i++){
    int c = l*8 + i;
    float m = stats[c]*invM;
    float rs = rsqrtf(stats[512+c]*invM - m*m + 1e-5f);
    g[i] = rs*acc[i] + sw*(1e-4f - m*rs);
  }
  uint4 o;
  o.x = pk2(g[0],g[1]); o.y = pk2(g[2],g[3]); o.z = pk2(g[4],g[5]); o.w = pk2(g[6],g[7]);
  ((uint4*)out)[(size_t)row*64 + l] = o;
}

// dual aggregation (ctx+obj) over shared raw table; BN affine (precomputed mstat) in epilogue
__global__ __launch_bounds__(256) void aggregate_dual(const unsigned short* __restrict__ A,
                                                      const int* __restrict__ rowp,
                                                      const int* __restrict__ ccol,
                                                      const float* __restrict__ wc,
                                                      const float* __restrict__ wo,
                                                      const float* __restrict__ Sc,
                                                      const float* __restrict__ So,
                                                      const float* __restrict__ mstatC,
                                                      const float* __restrict__ mstatO,
                                                      unsigned short* __restrict__ outC,
                                                      unsigned short* __restrict__ outO){
  int row = blockIdx.x*4 + (threadIdx.x >> 6);
  int l = threadIdx.x & 63;
  const uint4* Av = (const uint4*)A;
  int s = rowp[row], e = rowp[row+1];
  float aC[8] = {0,0,0,0,0,0,0,0};
  float aO[8] = {0,0,0,0,0,0,0,0};
  int j = s;
  for (; j+1 < e; j += 2){
    int c0 = ccol[j], c1 = ccol[j+1];
    float wc0 = wc[j], wc1 = wc[j+1];
    float wo0 = wo[j], wo1 = wo[j+1];
    uint4 v0 = Av[(size_t)c0*64 + l];
    uint4 v1 = Av[(size_t)c1*64 + l];
    fma8(aC, v0, wc0); fma8(aO, v0, wo0);
    fma8(aC, v1, wc1); fma8(aO, v1, wo1);
  }
  if (j < e){
    uint4 v = Av[(size_t)ccol[j]*64 + l];
    fma8(aC, v, wc[j]); fma8(aO, v, wo[j]);
  }
  float ScR = Sc[row], SoR = So[row];
  float gC[8], gO[8];
#pragma unroll
  for (int i=0;i<8;i++){
    int c = l*8 + i;
    float mc = mstatC[c], rc = mstatC[512+c];
    float mo = mstatO[c], ro = mstatO[512+c];
    gC[i] = rc*aC[i] + ScR*(1e-4f - mc*rc);
    gO[i] = ro*aO[i] + SoR*(1e-4f - mo*ro);
  }
  uint4 oc, oo;
  oc.x = pk2(gC[0],gC[1]); oc.y = pk2(gC[2],gC[3]); oc.z = pk2(gC[4],gC[5]); oc.w = pk2(gC[6],gC[7]);
  oo.x = pk2(gO[0],gO[1]); oo.y = pk2(gO[2],gO[3]); oo.z = pk2(gO[4],gO[5]); oo.w = pk2(gO[6],gO[7]);
  ((uint4*)outC)[(size_t)row*64 + l] = oc;
  ((uint4*)outO)[(size_t)row*64 + l] = oo;
}

// ---------------- bf16 MFMA GEMM: O[M,512] = relu(A[M,K] @ Bt^T + bias) -> bf16, optional col stats ----------------
__global__ __launch_bounds__(256) void gemm_bt(const unsigned short* __restrict__ A,
                                               const unsigned short* __restrict__ Bt,
                                               unsigned short* __restrict__ O,
                                               const float* __restrict__ bias,
                                               float* __restrict__ stats,
                                               int M, int K, int relu){
  __shared__ unsigned short As[128*32];
  __shared__ unsigned short Bs[128*32];
  const int tid = threadIdx.x;
  const int w = tid >> 6, l = tid & 63;
  const int m0 = blockIdx.x*128, n0 = blockIdx.y*128;
  const int wm = w >> 1, wn = w & 1;
  const int lr = l & 15, lh = l >> 4;

  f32x4 acc[4][4];
#pragma unroll
  for (int i=0;i<4;i++)
#pragma unroll
    for (int j=0;j<4;j++) acc[i][j] = 0.0f;

  const int q0 = w*2, q1 = w*2+1;
  const int sub = l >> 2;
  const int kc  = (l & 3)*8;
  int ma0 = m0 + q0*16 + sub; if (ma0 >= M) ma0 = M-1;
  int ma1 = m0 + q1*16 + sub; if (ma1 >= M) ma1 = M-1;
  const int nb0 = n0 + q0*16 + sub;
  const int nb1 = n0 + q1*16 + sub;

  for (int k0=0; k0<K; k0+=32){
    gload16(&As[q0*512], A + (size_t)ma0*K + k0 + kc);
    gload16(&As[q1*512], A + (size_t)ma1*K + k0 + kc);
    gload16(&Bs[q0*512], Bt + (size_t)nb0*K + k0 + kc);
    gload16(&Bs[q1*512], Bt + (size_t)nb1*K + k0 + kc);
    __syncthreads();
    short8 af[4], bfr[4];
#pragma unroll
    for (int fm=0; fm<4; ++fm) af[fm]  = *(const short8*)&As[(wm*64 + fm*16 + lr)*32 + lh*8];
#pragma unroll
    for (int fn=0; fn<4; ++fn) bfr[fn] = *(const short8*)&Bs[(wn*64 + fn*16 + lr)*32 + lh*8];
#pragma unroll
    for (int fm=0; fm<4; ++fm)
#pragma unroll
      for (int fn=0; fn<4; ++fn)
        acc[fm][fn] = __builtin_amdgcn_mfma_f32_16x16x32_bf16(af[fm], bfr[fn], acc[fm][fn], 0, 0, 0);
    __syncthreads();
  }
  float bv[4], cs[4]={0,0,0,0}, cq[4]={0,0,0,0};
  int col[4];
#pragma unroll
  for (int fn=0; fn<4; ++fn){ col[fn] = n0 + wn*64 + fn*16 + lr; bv[fn] = bias[col[fn]]; }
#pragma unroll
  for (int fm=0; fm<4; ++fm){
#pragma unroll
    for (int j=0; j<4; ++j){
      int row = m0 + wm*64 + fm*16 + lh*4 + j;
      if (row < M){
#pragma unroll
        for (int fn=0; fn<4; ++fn){
          float v = acc[fm][fn][j] + bv[fn];
          if (relu) v = fmaxf(v, 0.f);
          O[(size_t)row*HID + col[fn]] = f2bf(v);
          cs[fn] += v; cq[fn] += v*v;
        }
      }
    }
  }
  if (stats){
#pragma unroll
    for (int m=16; m<64; m<<=1){
#pragma unroll
      for (int fn=0; fn<4; ++fn){ cs[fn] += __shfl_xor(cs[fn], m); cq[fn] += __shfl_xor(cq[fn], m); }
    }
    if (lh == 0){
#pragma unroll
      for (int fn=0; fn<4; ++fn){
        atomicAdd(&stats[col[fn]], cs[fn]);
        atomicAdd(&stats[512+col[fn]], cq[fn]);
      }
    }
  }
}

// ---------------- pooling (bf16 X) ----------------
__global__ void pool_kernel(const unsigned short* __restrict__ X, const int* __restrict__ batch,
                            float* __restrict__ out){
  int g = blockIdx.x;
  int t = threadIdx.x;
  int lo = 0, hi = NN;
  while (lo < hi){ int mid = (lo+hi) >> 1; if (batch[mid] < g) lo = mid+1; else hi = mid; }
  int s = lo;
  lo = 0; hi = NN;
  while (lo < hi){ int mid = (lo+hi) >> 1; if (batch[mid] < g+1) lo = mid+1; else hi = mid; }
  int e = lo;
  float a0 = 0.f, a1 = 0.f;
  for (int i=s; i<e; ++i){
    unsigned int v = *(const unsigned int*)&X[(size_t)i*HID + t*2];
    a0 += bf2f(v & 0xffffu); a1 += bf2f(v >> 16);
  }
  out[(size_t)g*HID + t*2]     = a0;
  out[(size_t)g*HID + t*2 + 1] = a1;
}

__global__ void addperm(const float* __restrict__ gc, const float* __restrict__ go,
                        const int* __restrict__ perm, float* __restrict__ gco){
  int g = blockIdx.x;
  int t = threadIdx.x;
  int ps = perm[g];
  for (int k=t; k<HID; k+=256)
    gco[(size_t)g*HID + k] = gc[(size_t)ps*HID + k] + go[(size_t)g*HID + k];
}

// ---------------- final: BN (from raw stats) -> fc2 -> log_softmax (bf16 in, fp32 math) ----------------
__global__ void readout_final(const unsigned short* __restrict__ T, const float* __restrict__ stats,
                              float invM, const float* __restrict__ W2, const float* __restrict__ b2,
                              float* __restrict__ out){
  int g = blockIdx.x;
  int l = threadIdx.x;
  float acc[NCLS];
#pragma unroll
  for (int c=0; c<NCLS; ++c) acc[c] = 0.f;
  uint4 u = ((const uint4*)(T + (size_t)g*HID))[l];
  float xv[8] = {bf2f(u.x&0xffffu), bf2f(u.x>>16), bf2f(u.y&0xffffu), bf2f(u.y>>16),
                 bf2f(u.z&0xffffu), bf2f(u.z>>16), bf2f(u.w&0xffffu), bf2f(u.w>>16)};
#pragma unroll
  for (int j=0; j<8; ++j){
    int k = l*8 + j;
    float m = stats[k]*invM;
    float rs = rsqrtf(stats[512+k]*invM - m*m + 1e-5f);
    float v = (xv[j] - m)*rs + 1e-4f;
#pragma unroll
    for (int c=0; c<NCLS; ++c) acc[c] += v * W2[k*NCLS + c];
  }
  for (int m=1; m<64; m<<=1){
#pragma unroll
    for (int c=0; c<NCLS; ++c) acc[c] += __shfl_xor(acc[c], m);
  }
  if (l == 0){
    float z[NCLS];
    float mx = -1e30f;
#pragma unroll
    for (int c=0; c<NCLS; ++c){ z[c] = acc[c] + b2[c]; mx = fmaxf(mx, z[c]); }
    float s = 0.f;
#pragma unroll
    for (int c=0; c<NCLS; ++c) s += expf(z[c]-mx);
    float lse = mx + logf(s);
#pragma unroll
    for (int c=0; c<NCLS; ++c) out[(size_t)g*NCLS + c] = z[c] - lse;
  }
}

extern "C" void kernel_launch(void* const* d_in, const int* in_sizes, int n_in,
                              void* d_out, int out_size, void* d_ws, size_t ws_size,
                              hipStream_t stream){
  (void)in_sizes; (void)n_in; (void)out_size;
  const float* x      = (const float*)d_in[0];
  const int*   ei     = (const int*)d_in[1];
  const int*   batch  = (const int*)d_in[2];
  const int*   perm   = (const int*)d_in[3];
  const float* convfW = (const float*)d_in[4];
  const float* convfB = (const float*)d_in[5];
  const float* convsW = (const float*)d_in[6];
  const float* convsB = (const float*)d_in[7];
  const float* eattW  = (const float*)d_in[8];
  const float* eattB  = (const float*)d_in[9];
  const float* nattW  = (const float*)d_in[10];
  const float* nattB  = (const float*)d_in[11];
  const float* ctxW   = (const float*)d_in[12];
  const float* ctxB   = (const float*)d_in[13];
  const float* objW   = (const float*)d_in[14];
  const float* objB   = (const float*)d_in[15];
  const float* fc1W[3] = {(const float*)d_in[16], (const float*)d_in[20], (const float*)d_in[24]};
  const float* fc1B[3] = {(const float*)d_in[17], (const float*)d_in[21], (const float*)d_in[25]};
  const float* fc2W[3] = {(const float*)d_in[18], (const float*)d_in[22], (const float*)d_in[26]};
  const float* fc2B[3] = {(const float*)d_in[19], (const float*)d_in[23], (const float*)d_in[27]};
  float* out = (float*)d_out;

  char* p = (char*)d_ws;
  auto alloc = [&](size_t bytes)->char*{ char* r = p; p += (bytes + 255) & ~((size_t)255); return r; };
  const int T = NE + NN;
  unsigned short* Xbf = (unsigned short*)alloc((size_t)NN*HID*2);
  unsigned short* Gbf = (unsigned short*)alloc((size_t)NN*HID*2);
  unsigned short* GbfO= (unsigned short*)alloc((size_t)NN*HID*2);
  unsigned short* Abf = (unsigned short*)alloc((size_t)NN*FIN*2);
  unsigned short* WtF = (unsigned short*)alloc((size_t)HID*FIN*2);
  unsigned short* WtL = (unsigned short*)alloc((size_t)3*HID*HID*2);
  unsigned short* WtC = (unsigned short*)alloc((size_t)HID*HID*2);
  unsigned short* WtO = (unsigned short*)alloc((size_t)HID*HID*2);
  unsigned short* WtR = (unsigned short*)alloc((size_t)3*HID*HID*2);
  int* cnt   = (int*)alloc((size_t)NN*4);
  int* fillc = (int*)alloc((size_t)NN*4);
  int* rowp  = (int*)alloc((size_t)(NN+1)*4);
  int* bsum  = (int*)alloc(32*4);
  int* ccol  = (int*)alloc((size_t)T*4);
  int* crow  = (int*)alloc((size_t)T*4);
  int* ceid  = (int*)alloc((size_t)T*4);
  float* w1  = (float*)alloc((size_t)T*4);
  float* wcv = (float*)alloc((size_t)T*4);
  float* wov = (float*)alloc((size_t)T*4);
  float* dis1 = (float*)alloc((size_t)NN*4);
  float* degc = (float*)alloc((size_t)NN*4);
  float* dego = (float*)alloc((size_t)NN*4);
  float* Sc   = (float*)alloc((size_t)NN*4);
  float* So   = (float*)alloc((size_t)NN*4);
  float* stats6 = (float*)alloc(6*1024*4);   // [0]=conv_out [1]=L0 [2]=L1 [3..5]=fc1_c/o/co
  float* mstat  = (float*)alloc(2*HID*4);
  float* mstatC = (float*)alloc(2*HID*4);
  float* mstatO = (float*)alloc(2*HID*4);
  float* na   = (float*)alloc((size_t)NN*2*4);
  float* eab  = (float*)alloc((size_t)NN*4*4);
  float* att  = (float*)alloc((size_t)NE*2*4);
  float* gc   = (float*)alloc((size_t)NG*HID*4);
  float* go   = (float*)alloc((size_t)NG*HID*4);
  float* gco  = (float*)alloc((size_t)NG*HID*4);
  float* part = (float*)alloc((size_t)BNG*2048*4);
  if ((size_t)(p - (char*)d_ws) > ws_size){
    sentinel_k<<<1,1,0,stream>>>(out);
    return;
  }
  const float invNN = 1.0f/(float)NN;
  const float invNG = 1.0f/(float)NG;

  // weights -> bf16 transposed (one dispatch)
  W2BT wp;
  wp.src[0]=convfW; wp.dst[0]=WtF;
  for (int i=0;i<3;i++){ wp.src[1+i]=convsW+(size_t)i*HID*HID; wp.dst[1+i]=WtL+(size_t)i*HID*HID; }
  wp.src[4]=ctxW; wp.dst[4]=WtC;
  wp.src[5]=objW; wp.dst[5]=WtO;
  for (int i=0;i<3;i++){ wp.src[6+i]=fc1W[i]; wp.dst[6+i]=WtR+(size_t)i*HID*HID; }
  w2bt_all<<<(FIN*HID + 8*HID*HID + 255)/256, 256, 0, stream>>>(wp);

  init_misc<<<(NN+255)/256,256,0,stream>>>(cnt, fillc, degc, dego, Sc, So, stats6);

  // CSR build
  csr_count<<<(NE+255)/256,256,0,stream>>>(ei, cnt);
  scan1<<<(NN+1023)/1024,1024,0,stream>>>(cnt, rowp, dis1, bsum);
  scan2<<<1,64,0,stream>>>(bsum, (NN+1023)/1024);
  scan3<<<(NN+1023)/1024,1024,0,stream>>>(rowp, bsum);
  csr_fill<<<(T+255)/256,256,0,stream>>>(ei, rowp, cnt, fillc, ccol, crow, ceid);
  w1_kernel<<<(T+255)/256,256,0,stream>>>(crow, ccol, dis1, w1);

  // conv_feat: relu(bn(x) @ Wf + bf) -> Xbf (bf16), stats -> stats6[0]
  bnstats_p<<<BNG,1024,0,stream>>>(x, NN, FIN, part);
  bnfin_red<<<(FIN+63)/64,256,0,stream>>>(part, 2*FIN, 0, NN, FIN, mstat);
  bncast<<<((NN*FIN/4)+255)/256,256,0,stream>>>(x, mstat, NN, FIN, Abf);
  gemm_bt<<<dim3((NN+127)/128,4),256,0,stream>>>(Abf, WtF, Xbf, convfB, stats6, NN, FIN, 1);

  // 3 GCN layers: aggregate(raw X, BN folded) -> gemm (stats for next layer's BN)
  for (int i=0;i<3;i++){
    aggregate_bn<<<NN/4,256,0,stream>>>(Xbf, rowp, ccol, w1, stats6 + i*1024, invNN, Gbf);
    gemm_bt<<<dim3((NN+127)/128,4),256,0,stream>>>(Gbf, WtL+(size_t)i*HID*HID, Xbf,
                                                   convsB+(size_t)i*HID,
                                                   (i<2) ? (stats6 + (i+1)*1024) : nullptr,
                                                   NN, HID, 1);
  }

  // attention
  att_node<<<(NN+3)/4,256,0,stream>>>(Xbf, nattW, nattB, eattW, na, eab);
  att_edge<<<(NE+255)/256,256,0,stream>>>(ei, eab, eattB, att, degc, dego);
  wco_kernel<<<(T+255)/256,256,0,stream>>>(crow, ccol, ceid, att, degc, dego, na, wcv, wov, Sc, So);

  // ctx + obj branches: dual stats on bf16 X, dual aggregate, 2 gemms, 2 pools
  bnstats_dual<<<BNG,1024,0,stream>>>(Xbf, na, part);
  bnfin_red<<<(HID+63)/64,256,0,stream>>>(part, 4*HID, 0,     NN, HID, mstatC);
  bnfin_red<<<(HID+63)/64,256,0,stream>>>(part, 4*HID, 2*HID, NN, HID, mstatO);
  aggregate_dual<<<NN/4,256,0,stream>>>(Xbf, rowp, ccol, wcv, wov, Sc, So, mstatC, mstatO, Gbf, GbfO);
  gemm_bt<<<dim3((NN+127)/128,4),256,0,stream>>>(Gbf, WtC, Xbf, ctxB, nullptr, NN, HID, 1);
  pool_kernel<<<NG,256,0,stream>>>(Xbf, batch, gc);
  gemm_bt<<<dim3((NN+127)/128,4),256,0,stream>>>(GbfO, WtO, Xbf, objB, nullptr, NN, HID, 1);
  pool_kernel<<<NG,256,0,stream>>>(Xbf, batch, go);

  // xco = gc[perm] + go
  addperm<<<NG,256,0,stream>>>(gc, go, perm, gco);

  // readouts: BN1 (f32 path) -> fc1 gemm (emits stats) -> readout_final (BN2 inline)
  const float* gin[3] = {gc, go, gco};
  for (int r=0;r<3;r++){
    bnstats_p<<<BNG,1024,0,stream>>>(gin[r], NG, HID, part);
    bnfin_red<<<(HID+63)/64,256,0,stream>>>(part, 2*HID, 0, NG, HID, mstat);
    bncast<<<((NG*HID/4)+255)/256,256,0,stream>>>(gin[r], mstat, NG, HID, Abf);
    gemm_bt<<<dim3((NG+127)/128,4),256,0,stream>>>(Abf, WtR+(size_t)r*HID*HID, Gbf, fc1B[r],
                                                   stats6 + (3+r)*1024, NG, HID, 1);
    readout_final<<<NG,64,0,stream>>>(Gbf, stats6 + (3+r)*1024, invNG, fc2W[r], fc2B[r],
                                      out + (size_t)r*NG*NCLS);
  }
}

// Round 5
// 482.474 us; speedup vs baseline: 2.1289x; 1.3099x over previous
//
#include <hip/hip_runtime.h>
#include <stdint.h>

#define NN 20000
#define NE 160000
#define NG 500
#define FIN 128
#define HID 512
#define NCLS 10
#define BNG 256
#define NB3 32

typedef __attribute__((ext_vector_type(8))) short short8;
typedef __attribute__((ext_vector_type(4))) float f32x4;
typedef __attribute__((ext_vector_type(4))) unsigned short ushort4v;

__device__ __forceinline__ float bf2f(unsigned int u){
  union{unsigned int i; float f;} x; x.i = u<<16; return x.f;
}
__device__ __forceinline__ unsigned short f2bf(float f){
  union{float f; unsigned int i;} x; x.f=f;
  unsigned int r = x.i + 0x7fffu + ((x.i>>16)&1u);
  return (unsigned short)(r>>16);
}
__device__ __forceinline__ unsigned int pk2(float a, float b){
  return (unsigned int)f2bf(a) | ((unsigned int)f2bf(b) << 16);
}

__device__ __forceinline__ void gload16(unsigned short* lds, const unsigned short* g){
  __builtin_amdgcn_global_load_lds((const __attribute__((address_space(1))) unsigned int*)g,
                                   (__attribute__((address_space(3))) unsigned int*)lds,
                                   16, 0, 0);
}

__device__ __forceinline__ void fma8(float* acc, uint4 v, float w){
  acc[0] += w*bf2f(v.x & 0xffffu); acc[1] += w*bf2f(v.x >> 16);
  acc[2] += w*bf2f(v.y & 0xffffu); acc[3] += w*bf2f(v.y >> 16);
  acc[4] += w*bf2f(v.z & 0xffffu); acc[5] += w*bf2f(v.z >> 16);
  acc[6] += w*bf2f(v.w & 0xffffu); acc[7] += w*bf2f(v.w >> 16);
}

__global__ void sentinel_k(float* out){ out[0] = 12345.0f; }

// ---------------- setup: all weight transposes + all init in one dispatch ----------------
struct W2BT { const float* src[9]; unsigned short* dst[9]; };
__global__ void setup_all(W2BT p, int* __restrict__ cnt, int* __restrict__ fillc,
                          float* __restrict__ degc, float* __restrict__ dego,
                          float* __restrict__ Sc, float* __restrict__ So,
                          float* __restrict__ stats6){
  int idx = blockIdx.x*blockDim.x + threadIdx.x;
  if (idx < FIN*HID + 8*HID*HID){
    int seg, off, K;
    if (idx < FIN*HID){ seg = 0; off = idx; K = FIN; }
    else {
      int r = idx - FIN*HID;
      seg = 1 + (r >> 18); off = r & (HID*HID-1); K = HID;
    }
    int k = off >> 9, n = off & 511;
    p.dst[seg][(size_t)n*K + k] = f2bf(p.src[seg][off]);
  }
  if (idx < NN){ cnt[idx]=0; fillc[idx]=0; degc[idx]=1.0f; dego[idx]=1.0f; Sc[idx]=0.f; So[idx]=0.f; }
  if (idx < 6*1024) stats6[idx] = 0.f;
}

// ---------------- BN stats stage 1 (f32 input; conv input only) ----------------
__global__ __launch_bounds__(1024) void bnstats_p(const float* __restrict__ X, int M, int F,
                                                  float* __restrict__ partials){
  __shared__ float lds[1024*9];
  const int t = threadIdx.x;
  const int cg = F >> 2;
  const int cid = t & (cg-1);
  const int rid = t / cg;
  const int rpb = 1024 / cg;
  float s0=0,s1=0,s2=0,s3=0,q0=0,q1=0,q2=0,q3=0;
  const int rowsPer = (M + BNG - 1)/BNG;
  int r0 = blockIdx.x*rowsPer, r1 = r0 + rowsPer; if (r1 > M) r1 = M;
  for (int r = r0 + rid; r < r1; r += rpb){
    float4 v = *(const float4*)&X[(size_t)r*F + cid*4];
    s0+=v.x; q0+=v.x*v.x; s1+=v.y; q1+=v.y*v.y; s2+=v.z; q2+=v.z*v.z; s3+=v.w; q3+=v.w*v.w;
  }
  int base = (rid*cg + cid)*9;
  lds[base+0]=s0; lds[base+1]=s1; lds[base+2]=s2; lds[base+3]=s3;
  lds[base+4]=q0; lds[base+5]=q1; lds[base+6]=q2; lds[base+7]=q3;
  __syncthreads();
  if (t < cg*8){
    int ci = t >> 3, i = t & 7;
    float acc = 0.f;
    for (int g=0; g<rpb; ++g) acc += lds[(g*cg + ci)*9 + i];
    int col = ci*4 + (i & 3);
    partials[(size_t)blockIdx.x*(2*F) + ((i < 4) ? col : F + col)] = acc;
  }
}

// ---------------- dual BN stats on bf16 X ----------------
__global__ __launch_bounds__(1024) void bnstats_dual(const unsigned short* __restrict__ X,
                                                     const float* __restrict__ na,
                                                     float* __restrict__ partials){
  __shared__ float lds[1024*17];
  const int t = threadIdx.x;
  const int cid = t & 127;
  const int rid = t >> 7;
  float sC[4]={0,0,0,0}, qC[4]={0,0,0,0}, sO[4]={0,0,0,0}, qO[4]={0,0,0,0};
  const int rowsPer = (NN + BNG - 1)/BNG;
  int r0 = blockIdx.x*rowsPer, r1 = r0 + rowsPer; if (r1 > NN) r1 = NN;
  for (int r = r0 + rid; r < r1; r += 8){
    float a0 = na[2*r], a1 = na[2*r+1];
    uint2 u = *(const uint2*)&X[(size_t)r*HID + cid*4];
    float e[4] = {bf2f(u.x & 0xffffu), bf2f(u.x >> 16), bf2f(u.y & 0xffffu), bf2f(u.y >> 16)};
#pragma unroll
    for (int i=0;i<4;i++){
      float vc = e[i]*a0, vo = e[i]*a1;
      sC[i]+=vc; qC[i]+=vc*vc; sO[i]+=vo; qO[i]+=vo*vo;
    }
  }
  int base = (rid*128 + cid)*17;
#pragma unroll
  for (int i=0;i<4;i++){
    lds[base+i]=sC[i]; lds[base+4+i]=qC[i]; lds[base+8+i]=sO[i]; lds[base+12+i]=qO[i];
  }
  __syncthreads();
  for (int idx = t; idx < 2048; idx += 1024){
    int ci = idx >> 4, i = idx & 15;
    float acc = 0.f;
    for (int g=0; g<8; ++g) acc += lds[(g*128 + ci)*17 + i];
    int grp = i >> 2, col = ci*4 + (i & 3);
    partials[(size_t)blockIdx.x*2048 + grp*HID + col] = acc;
  }
}

// ---------------- reduce partials -> mean/rstd (conv; 256 blocks, 64 per chunk) ----------------
__global__ void bnfin_red(const float* __restrict__ partials, int stride, int off,
                          int M, int F, float* __restrict__ mstat){
  __shared__ float lds[4][64][2];
  int t = threadIdx.x;
  int cl = t & 63, ch = t >> 6;
  int c = blockIdx.x*64 + cl;
  float s = 0.f, q = 0.f;
  if (c < F){
    for (int b = ch*64; b < ch*64 + 64; ++b){
      s += partials[(size_t)b*stride + off + c];
      q += partials[(size_t)b*stride + off + F + c];
    }
  }
  lds[ch][cl][0] = s; lds[ch][cl][1] = q;
  __syncthreads();
  if (ch == 0 && c < F){
    s = lds[0][cl][0]+lds[1][cl][0]+lds[2][cl][0]+lds[3][cl][0];
    q = lds[0][cl][1]+lds[1][cl][1]+lds[2][cl][1]+lds[3][cl][1];
    float m = s/(float)M;
    float v = q/(float)M - m*m;
    mstat[c] = m;
    mstat[F+c] = rsqrtf(v + 1e-5f);
  }
}

// dual version: grid (8,2); by=0 -> C (off 0), by=1 -> O (off 1024); out mstatCO[by*1024 + ...]
__global__ void bnfin_red2(const float* __restrict__ partials, float* __restrict__ mstatCO){
  __shared__ float lds[4][64][2];
  int t = threadIdx.x;
  int cl = t & 63, ch = t >> 6;
  int c = blockIdx.x*64 + cl;
  int off = blockIdx.y*1024;
  float s = 0.f, q = 0.f;
  for (int b = ch*64; b < ch*64 + 64; ++b){
    s += partials[(size_t)b*2048 + off + c];
    q += partials[(size_t)b*2048 + off + HID + c];
  }
  lds[ch][cl][0] = s; lds[ch][cl][1] = q;
  __syncthreads();
  if (ch == 0){
    s = lds[0][cl][0]+lds[1][cl][0]+lds[2][cl][0]+lds[3][cl][0];
    q = lds[0][cl][1]+lds[1][cl][1]+lds[2][cl][1]+lds[3][cl][1];
    float m = s/(float)NN;
    float v = q/(float)NN - m*m;
    mstatCO[blockIdx.y*1024 + c] = m;
    mstatCO[blockIdx.y*1024 + HID + c] = rsqrtf(v + 1e-5f);
  }
}

// ---------------- BN->bf16 cast (f32 input; conv input only) ----------------
__global__ void bncast(const float* __restrict__ X, const float* __restrict__ mstat,
                       int M, int F, unsigned short* __restrict__ out){
  int idx = blockIdx.x*blockDim.x + threadIdx.x;
  int total4 = M*F/4;
  if (idx >= total4) return;
  int base = idx*4;
  int c = base & (F-1);
  float4 v = *(const float4*)&X[base];
  ushort4v o;
  o[0] = f2bf((v.x - mstat[c+0])*mstat[F+c+0] + 1e-4f);
  o[1] = f2bf((v.y - mstat[c+1])*mstat[F+c+1] + 1e-4f);
  o[2] = f2bf((v.z - mstat[c+2])*mstat[F+c+2] + 1e-4f);
  o[3] = f2bf((v.w - mstat[c+3])*mstat[F+c+3] + 1e-4f);
  *(ushort4v*)&out[base] = o;
}

// ---------------- CSR build ----------------
__global__ void csr_count(const int* __restrict__ ei, int* __restrict__ cnt){
  int e = blockIdx.x*blockDim.x + threadIdx.x;
  if (e < NE) atomicAdd(&cnt[ei[e]], 1);
}

__global__ __launch_bounds__(1024) void scan1(const int* __restrict__ cnt, int* __restrict__ rowp,
                                              float* __restrict__ dis1, int* __restrict__ bsum){
  __shared__ int buf[1024];
  int t = threadIdx.x;
  int i = blockIdx.x*1024 + t;
  int v = 0;
  if (i < NN){ v = cnt[i] + 1; dis1[i] = rsqrtf((float)v); }
  buf[t] = v;
  __syncthreads();
  for (int off=1; off<1024; off<<=1){
    int xv = (t >= off) ? buf[t-off] : 0;
    __syncthreads();
    buf[t] += xv;
    __syncthreads();
  }
  if (i < NN) rowp[i+1] = buf[t];
  if (t == 1023) bsum[blockIdx.x] = buf[1023];
}

// scan3 with inline block-prefix of bsum (drops scan2)
__global__ __launch_bounds__(1024) void scan3(int* __restrict__ rowp, const int* __restrict__ bsum){
  __shared__ int base;
  int bx = blockIdx.x;
  if (threadIdx.x == 0){
    int a = 0;
    for (int b=0; b<bx; ++b) a += bsum[b];
    base = a;
  }
  __syncthreads();
  int i = bx*1024 + threadIdx.x;
  if (i < NN) rowp[i+1] += base;
  if (i == 0) rowp[0] = 0;
}

// csr_fill + w1 fused
__global__ void csr_fill(const int* __restrict__ ei, const int* __restrict__ rowp,
                         const int* __restrict__ cnt, int* __restrict__ fillc,
                         const float* __restrict__ dis1,
                         int* __restrict__ ccol, int* __restrict__ crow, int* __restrict__ ceid,
                         float* __restrict__ w1){
  int id = blockIdx.x*blockDim.x + threadIdx.x;
  if (id < NE){
    int r = ei[id], c = ei[NE + id];
    int pos = atomicAdd(&fillc[r], 1);
    int idx = rowp[r] + pos;
    ccol[idx] = c; crow[idx] = r; ceid[idx] = id;
    w1[idx] = dis1[r]*dis1[c];
  } else if (id < NE + NN){
    int i = id - NE;
    int idx = rowp[i] + cnt[i];
    ccol[idx] = i; crow[idx] = i; ceid[idx] = -1;
    w1[idx] = dis1[i]*dis1[i];
  }
}

// ---------------- attention (bf16 X) ----------------
__global__ void att_node(const unsigned short* __restrict__ X, const float* __restrict__ nW,
                         const float* __restrict__ nb, const float* __restrict__ eW,
                         float* __restrict__ na, float* __restrict__ eab){
  int wv = blockIdx.x*4 + (threadIdx.x >> 6);
  int l = threadIdx.x & 63;
  if (wv >= NN) return;
  uint4 u = ((const uint4*)(X + (size_t)wv*HID))[l];
  float xv[8] = {bf2f(u.x&0xffffu), bf2f(u.x>>16), bf2f(u.y&0xffffu), bf2f(u.y>>16),
                 bf2f(u.z&0xffffu), bf2f(u.z>>16), bf2f(u.w&0xffffu), bf2f(u.w>>16)};
  float s0=0,s1=0,s2=0,s3=0,s4=0,s5=0;
#pragma unroll
  for (int j=0; j<8; ++j){
    int k = l*8 + j;
    float x = xv[j];
    s0 += x * nW[2*k];       s1 += x * nW[2*k+1];
    s2 += x * eW[2*k];       s3 += x * eW[2*k+1];
    s4 += x * eW[2*(512+k)]; s5 += x * eW[2*(512+k)+1];
  }
  for (int m=1; m<64; m<<=1){
    s0 += __shfl_xor(s0,m); s1 += __shfl_xor(s1,m); s2 += __shfl_xor(s2,m);
    s3 += __shfl_xor(s3,m); s4 += __shfl_xor(s4,m); s5 += __shfl_xor(s5,m);
  }
  if (l == 0){
    float z0 = s0 + nb[0], z1 = s1 + nb[1];
    float mx = fmaxf(z0,z1);
    float e0 = expf(z0-mx), e1 = expf(z1-mx);
    float inv = 1.0f/(e0+e1);
    na[2*wv] = e0*inv; na[2*wv+1] = e1*inv;
    eab[4*wv] = s2; eab[4*wv+1] = s3; eab[4*wv+2] = s4; eab[4*wv+3] = s5;
  }
}

__global__ void att_edge(const int* __restrict__ ei, const float* __restrict__ eab,
                         const float* __restrict__ eb, float* __restrict__ att,
                         float* __restrict__ degc, float* __restrict__ dego){
  int e = blockIdx.x*blockDim.x + threadIdx.x;
  if (e >= NE) return;
  int r = ei[e], c = ei[NE+e];
  float z0 = eab[4*r]   + eab[4*c+2] + eb[0];
  float z1 = eab[4*r+1] + eab[4*c+3] + eb[1];
  float mx = fmaxf(z0,z1);
  float e0 = expf(z0-mx), e1 = expf(z1-mx);
  float inv = 1.0f/(e0+e1);
  float a0 = e0*inv, a1 = e1*inv;
  att[2*e] = a0; att[2*e+1] = a1;
  atomicAdd(&degc[r], a0);
  atomicAdd(&dego[r], a1);
}

__global__ void wco_kernel(const int* __restrict__ crow, const int* __restrict__ ccol,
                           const int* __restrict__ ceid, const float* __restrict__ att,
                           const float* __restrict__ degc, const float* __restrict__ dego,
                           const float* __restrict__ na,
                           float* __restrict__ wcv, float* __restrict__ wov,
                           float* __restrict__ Sc, float* __restrict__ So){
  int j = blockIdx.x*blockDim.x + threadIdx.x;
  if (j >= NE + NN) return;
  int r = crow[j], c = ccol[j], e = ceid[j];
  float a0 = (e < 0) ? 1.0f : att[2*e];
  float a1 = (e < 0) ? 1.0f : att[2*e+1];
  float wc = rsqrtf(degc[r]) * a0 * rsqrtf(degc[c]);
  float wo = rsqrtf(dego[r]) * a1 * rsqrtf(dego[c]);
  wcv[j] = wc * na[2*c];
  wov[j] = wo * na[2*c+1];
  atomicAdd(&Sc[r], wc);
  atomicAdd(&So[r], wo);
}

// ---------------- wave-per-row aggregation, BN affine in epilogue ----------------
__global__ __launch_bounds__(256) void aggregate_bn(const unsigned short* __restrict__ A,
                                                    const int* __restrict__ rowp,
                                                    const int* __restrict__ ccol,
                                                    const float* __restrict__ wv,
                                                    const float* __restrict__ stats,
                                                    float invM,
                                                    unsigned short* __restrict__ out){
  int row = blockIdx.x*4 + (threadIdx.x >> 6);
  int l = threadIdx.x & 63;
  const uint4* Av = (const uint4*)A;
  int s = rowp[row], e = rowp[row+1];
  float acc[8] = {0,0,0,0,0,0,0,0};
  float sw = 0.f;
  int j = s;
  for (; j+1 < e; j += 2){
    int c0 = ccol[j], c1 = ccol[j+1];
    float w0 = wv[j], w1 = wv[j+1];
    uint4 v0 = Av[(size_t)c0*64 + l];
    uint4 v1 = Av[(size_t)c1*64 + l];
    fma8(acc, v0, w0);
    fma8(acc, v1, w1);
    sw += w0 + w1;
  }
  if (j < e){
    uint4 v = Av[(size_t)ccol[j]*64 + l];
    fma8(acc, v, wv[j]);
    sw += wv[j];
  }
  float g[8];
#pragma unroll
  for (int i=0;i<8;i++){
    int c = l*8 + i;
    float m = stats[c]*invM;
    float rs = rsqrtf(stats[512+c]*invM - m*m + 1e-5f);
    g[i] = rs*acc[i] + sw*(1e-4f - m*rs);
  }
  uint4 o;
  o.x = pk2(g[0],g[1]); o.y = pk2(g[2],g[3]); o.z = pk2(g[4],g[5]); o.w = pk2(g[6],g[7]);
  ((uint4*)out)[(size_t)row*64 + l] = o;
}

__global__ __launch_bounds__(256) void aggregate_dual(const unsigned short* __restrict__ A,
                                                      const int* __restrict__ rowp,
                                                      const int* __restrict__ ccol,
                                                      const float* __restrict__ wc,
                                                      const float* __restrict__ wo,
                                                      const float* __restrict__ Sc,
                                                      const float* __restrict__ So,
                                                      const float* __restrict__ mstatCO,
                                                      unsigned short* __restrict__ outC,
                                                      unsigned short* __restrict__ outO){
  int row = blockIdx.x*4 + (threadIdx.x >> 6);
  int l = threadIdx.x & 63;
  const uint4* Av = (const uint4*)A;
  int s = rowp[row], e = rowp[row+1];
  float aC[8] = {0,0,0,0,0,0,0,0};
  float aO[8] = {0,0,0,0,0,0,0,0};
  int j = s;
  for (; j+1 < e; j += 2){
    int c0 = ccol[j], c1 = ccol[j+1];
    float wc0 = wc[j], wc1 = wc[j+1];
    float wo0 = wo[j], wo1 = wo[j+1];
    uint4 v0 = Av[(size_t)c0*64 + l];
    uint4 v1 = Av[(size_t)c1*64 + l];
    fma8(aC, v0, wc0); fma8(aO, v0, wo0);
    fma8(aC, v1, wc1); fma8(aO, v1, wo1);
  }
  if (j < e){
    uint4 v = Av[(size_t)ccol[j]*64 + l];
    fma8(aC, v, wc[j]); fma8(aO, v, wo[j]);
  }
  float ScR = Sc[row], SoR = So[row];
  float gC[8], gO[8];
#pragma unroll
  for (int i=0;i<8;i++){
    int c = l*8 + i;
    float mc = mstatCO[c],      rc = mstatCO[512+c];
    float mo = mstatCO[1024+c], ro = mstatCO[1536+c];
    gC[i] = rc*aC[i] + ScR*(1e-4f - mc*rc);
    gO[i] = ro*aO[i] + SoR*(1e-4f - mo*ro);
  }
  uint4 oc, oo;
  oc.x = pk2(gC[0],gC[1]); oc.y = pk2(gC[2],gC[3]); oc.z = pk2(gC[4],gC[5]); oc.w = pk2(gC[6],gC[7]);
  oo.x = pk2(gO[0],gO[1]); oo.y = pk2(gO[2],gO[3]); oo.z = pk2(gO[4],gO[5]); oo.w = pk2(gO[6],gO[7]);
  ((uint4*)outC)[(size_t)row*64 + l] = oc;
  ((uint4*)outO)[(size_t)row*64 + l] = oo;
}

// ---------------- bf16 MFMA GEMM, double-buffered 2-phase; bf16 out; optional col stats ----------------
__global__ __launch_bounds__(256) void gemm_bt(const unsigned short* __restrict__ A,
                                               const unsigned short* __restrict__ Bt,
                                               unsigned short* __restrict__ O,
                                               const float* __restrict__ bias,
                                               float* __restrict__ stats,
                                               int M, int K, int relu){
  __shared__ unsigned short As[2][128*32];
  __shared__ unsigned short Bs[2][128*32];
  const int tid = threadIdx.x;
  const int w = tid >> 6, l = tid & 63;
  const int m0 = blockIdx.x*128, n0 = blockIdx.y*128;
  const int wm = w >> 1, wn = w & 1;
  const int lr = l & 15, lh = l >> 4;

  f32x4 acc[4][4];
#pragma unroll
  for (int i=0;i<4;i++)
#pragma unroll
    for (int j=0;j<4;j++) acc[i][j] = 0.0f;

  const int q0 = w*2, q1 = w*2+1;
  const int sub = l >> 2;
  const int kc  = (l & 3)*8;
  int ma0 = m0 + q0*16 + sub; if (ma0 >= M) ma0 = M-1;
  int ma1 = m0 + q1*16 + sub; if (ma1 >= M) ma1 = M-1;
  const int nb0 = n0 + q0*16 + sub;
  const int nb1 = n0 + q1*16 + sub;
  const unsigned short* Ar0 = A + (size_t)ma0*K + kc;
  const unsigned short* Ar1 = A + (size_t)ma1*K + kc;
  const unsigned short* Br0 = Bt + (size_t)nb0*K + kc;
  const unsigned short* Br1 = Bt + (size_t)nb1*K + kc;

  const int NT = K >> 5;
  // prologue: stage tile 0
  gload16(&As[0][q0*512], Ar0);
  gload16(&As[0][q1*512], Ar1);
  gload16(&Bs[0][q0*512], Br0);
  gload16(&Bs[0][q1*512], Br1);
  __syncthreads();
  int cur = 0;
  for (int t=0; t<NT; ++t){
    if (t+1 < NT){
      int k1 = (t+1) << 5;
      gload16(&As[cur^1][q0*512], Ar0 + k1);
      gload16(&As[cur^1][q1*512], Ar1 + k1);
      gload16(&Bs[cur^1][q0*512], Br0 + k1);
      gload16(&Bs[cur^1][q1*512], Br1 + k1);
    }
    short8 af[4], bfr[4];
#pragma unroll
    for (int fm=0; fm<4; ++fm) af[fm]  = *(const short8*)&As[cur][(wm*64 + fm*16 + lr)*32 + lh*8];
#pragma unroll
    for (int fn=0; fn<4; ++fn) bfr[fn] = *(const short8*)&Bs[cur][(wn*64 + fn*16 + lr)*32 + lh*8];
#pragma unroll
    for (int fm=0; fm<4; ++fm)
#pragma unroll
      for (int fn=0; fn<4; ++fn)
        acc[fm][fn] = __builtin_amdgcn_mfma_f32_16x16x32_bf16(af[fm], bfr[fn], acc[fm][fn], 0, 0, 0);
    __syncthreads();
    cur ^= 1;
  }
  float bv[4], cs[4]={0,0,0,0}, cq[4]={0,0,0,0};
  int col[4];
#pragma unroll
  for (int fn=0; fn<4; ++fn){ col[fn] = n0 + wn*64 + fn*16 + lr; bv[fn] = bias[col[fn]]; }
#pragma unroll
  for (int fm=0; fm<4; ++fm){
#pragma unroll
    for (int j=0; j<4; ++j){
      int row = m0 + wm*64 + fm*16 + lh*4 + j;
      if (row < M){
#pragma unroll
        for (int fn=0; fn<4; ++fn){
          float v = acc[fm][fn][j] + bv[fn];
          if (relu) v = fmaxf(v, 0.f);
          O[(size_t)row*HID + col[fn]] = f2bf(v);
          cs[fn] += v; cq[fn] += v*v;
        }
      }
    }
  }
  if (stats){
#pragma unroll
    for (int m=16; m<64; m<<=1){
#pragma unroll
      for (int fn=0; fn<4; ++fn){ cs[fn] += __shfl_xor(cs[fn], m); cq[fn] += __shfl_xor(cq[fn], m); }
    }
    if (lh == 0){
#pragma unroll
      for (int fn=0; fn<4; ++fn){
        atomicAdd(&stats[col[fn]], cs[fn]);
        atomicAdd(&stats[512+col[fn]], cq[fn]);
      }
    }
  }
}

// batched fc1 gemm: M=1536 (3 branches x 512 rows, rows 500..511 padded zero), branch-indexed weights
struct FC1P { const unsigned short* Bt[3]; const float* bias[3]; };
__global__ __launch_bounds__(256) void gemm_fc1(const unsigned short* __restrict__ A, FC1P p,
                                                unsigned short* __restrict__ O,
                                                float* __restrict__ statsB){
  __shared__ unsigned short As[2][128*32];
  __shared__ unsigned short Bs[2][128*32];
  const int tid = threadIdx.x;
  const int w = tid >> 6, l = tid & 63;
  const int m0 = blockIdx.x*128, n0 = blockIdx.y*128;
  const int branch = blockIdx.x >> 2;
  const unsigned short* Bt = p.Bt[branch];
  const float* bias = p.bias[branch];
  float* stats = statsB + branch*1024;
  const int K = HID;
  const int wm = w >> 1, wn = w & 1;
  const int lr = l & 15, lh = l >> 4;

  f32x4 acc[4][4];
#pragma unroll
  for (int i=0;i<4;i++)
#pragma unroll
    for (int j=0;j<4;j++) acc[i][j] = 0.0f;

  const int q0 = w*2, q1 = w*2+1;
  const int sub = l >> 2;
  const int kc  = (l & 3)*8;
  const int ma0 = m0 + q0*16 + sub;
  const int ma1 = m0 + q1*16 + sub;
  const int nb0 = n0 + q0*16 + sub;
  const int nb1 = n0 + q1*16 + sub;
  const unsigned short* Ar0 = A + (size_t)ma0*K + kc;
  const unsigned short* Ar1 = A + (size_t)ma1*K + kc;
  const unsigned short* Br0 = Bt + (size_t)nb0*K + kc;
  const unsigned short* Br1 = Bt + (size_t)nb1*K + kc;

  const int NT = K >> 5;
  gload16(&As[0][q0*512], Ar0);
  gload16(&As[0][q1*512], Ar1);
  gload16(&Bs[0][q0*512], Br0);
  gload16(&Bs[0][q1*512], Br1);
  __syncthreads();
  int cur = 0;
  for (int t=0; t<NT; ++t){
    if (t+1 < NT){
      int k1 = (t+1) << 5;
      gload16(&As[cur^1][q0*512], Ar0 + k1);
      gload16(&As[cur^1][q1*512], Ar1 + k1);
      gload16(&Bs[cur^1][q0*512], Br0 + k1);
      gload16(&Bs[cur^1][q1*512], Br1 + k1);
    }
    short8 af[4], bfr[4];
#pragma unroll
    for (int fm=0; fm<4; ++fm) af[fm]  = *(const short8*)&As[cur][(wm*64 + fm*16 + lr)*32 + lh*8];
#pragma unroll
    for (int fn=0; fn<4; ++fn) bfr[fn] = *(const short8*)&Bs[cur][(wn*64 + fn*16 + lr)*32 + lh*8];
#pragma unroll
    for (int fm=0; fm<4; ++fm)
#pragma unroll
      for (int fn=0; fn<4; ++fn)
        acc[fm][fn] = __builtin_amdgcn_mfma_f32_16x16x32_bf16(af[fm], bfr[fn], acc[fm][fn], 0, 0, 0);
    __syncthreads();
    cur ^= 1;
  }
  float bv[4], cs[4]={0,0,0,0}, cq[4]={0,0,0,0};
  int col[4];
#pragma unroll
  for (int fn=0; fn<4; ++fn){ col[fn] = n0 + wn*64 + fn*16 + lr; bv[fn] = bias[col[fn]]; }
#pragma unroll
  for (int fm=0; fm<4; ++fm){
#pragma unroll
    for (int j=0; j<4; ++j){
      int row = m0 + wm*64 + fm*16 + lh*4 + j;
      bool real = (row & 511) < NG;
#pragma unroll
      for (int fn=0; fn<4; ++fn){
        float v = fmaxf(acc[fm][fn][j] + bv[fn], 0.f);
        O[(size_t)row*HID + col[fn]] = f2bf(v);
        if (real){ cs[fn] += v; cq[fn] += v*v; }
      }
    }
  }
#pragma unroll
  for (int m=16; m<64; m<<=1){
#pragma unroll
    for (int fn=0; fn<4; ++fn){ cs[fn] += __shfl_xor(cs[fn], m); cq[fn] += __shfl_xor(cq[fn], m); }
  }
  if (lh == 0){
#pragma unroll
    for (int fn=0; fn<4; ++fn){
      atomicAdd(&stats[col[fn]], cs[fn]);
      atomicAdd(&stats[512+col[fn]], cq[fn]);
    }
  }
}

// ---------------- pooling, both branches in one dispatch ----------------
__global__ void pool2(const unsigned short* __restrict__ XC, const unsigned short* __restrict__ XO,
                      const int* __restrict__ batch, float* __restrict__ gc, float* __restrict__ go){
  int g = blockIdx.x;
  int t = threadIdx.x;
  const unsigned short* X = blockIdx.y ? XO : XC;
  float* out = blockIdx.y ? go : gc;
  int lo = 0, hi = NN;
  while (lo < hi){ int mid = (lo+hi) >> 1; if (batch[mid] < g) lo = mid+1; else hi = mid; }
  int s = lo;
  lo = 0; hi = NN;
  while (lo < hi){ int mid = (lo+hi) >> 1; if (batch[mid] < g+1) lo = mid+1; else hi = mid; }
  int e = lo;
  float a0 = 0.f, a1 = 0.f;
  for (int i=s; i<e; ++i){
    unsigned int v = *(const unsigned int*)&X[(size_t)i*HID + t*2];
    a0 += bf2f(v & 0xffffu); a1 += bf2f(v >> 16);
  }
  out[(size_t)g*HID + t*2]     = a0;
  out[(size_t)g*HID + t*2 + 1] = a1;
}

// ---------------- readout BN1: batched 3-branch stats ----------------
__global__ __launch_bounds__(256) void bnstats3(const float* __restrict__ gc, const float* __restrict__ go,
                                                const int* __restrict__ perm, float* __restrict__ partials){
  __shared__ float lds[256*9];
  int br = blockIdx.y;
  int t = threadIdx.x;
  int cid = t & 127, rid = t >> 7;
  float s[4]={0,0,0,0}, q[4]={0,0,0,0};
  const int rowsPer = (NG + NB3 - 1)/NB3;
  int r0 = blockIdx.x*rowsPer, r1 = r0 + rowsPer; if (r1 > NG) r1 = NG;
  for (int r = r0 + rid; r < r1; r += 2){
    float4 v;
    if (br == 0)      v = *(const float4*)&gc[(size_t)r*HID + cid*4];
    else if (br == 1) v = *(const float4*)&go[(size_t)r*HID + cid*4];
    else {
      int ps = perm[r];
      float4 a = *(const float4*)&gc[(size_t)ps*HID + cid*4];
      float4 b = *(const float4*)&go[(size_t)r*HID + cid*4];
      v = make_float4(a.x+b.x, a.y+b.y, a.z+b.z, a.w+b.w);
    }
    float e[4] = {v.x, v.y, v.z, v.w};
#pragma unroll
    for (int i=0;i<4;i++){ s[i]+=e[i]; q[i]+=e[i]*e[i]; }
  }
  int base = (rid*128 + cid)*9;
#pragma unroll
  for (int i=0;i<4;i++){ lds[base+i]=s[i]; lds[base+4+i]=q[i]; }
  __syncthreads();
  for (int o = t; o < 1024; o += 256){
    int issq = o >> 9, col = o & 511;
    int ci = col >> 2, i = col & 3;
    float acc = lds[(0*128 + ci)*9 + issq*4 + i] + lds[(1*128 + ci)*9 + issq*4 + i];
    partials[(size_t)(br*NB3 + blockIdx.x)*1024 + issq*512 + col] = acc;
  }
}

__global__ void bnfin3(const float* __restrict__ partials, float* __restrict__ mstat3){
  __shared__ float lds[4][64][2];
  int t = threadIdx.x;
  int cl = t & 63, ch = t >> 6;
  int c = blockIdx.x*64 + cl;
  int br = blockIdx.y;
  float s = 0.f, q = 0.f;
  for (int b = ch*8; b < ch*8 + 8; ++b){
    s += partials[(size_t)(br*NB3 + b)*1024 + c];
    q += partials[(size_t)(br*NB3 + b)*1024 + 512 + c];
  }
  lds[ch][cl][0] = s; lds[ch][cl][1] = q;
  __syncthreads();
  if (ch == 0){
    s = lds[0][cl][0]+lds[1][cl][0]+lds[2][cl][0]+lds[3][cl][0];
    q = lds[0][cl][1]+lds[1][cl][1]+lds[2][cl][1]+lds[3][cl][1];
    float m = s/(float)NG;
    float v = q/(float)NG - m*m;
    mstat3[br*1024 + c] = m;
    mstat3[br*1024 + 512 + c] = rsqrtf(v + 1e-5f);
  }
}

__global__ void bncast3(const float* __restrict__ gc, const float* __restrict__ go,
                        const int* __restrict__ perm, const float* __restrict__ mstat3,
                        unsigned short* __restrict__ out){
  int idx = blockIdx.x*blockDim.x + threadIdx.x;
  if (idx >= 1536*128) return;
  int r = idx >> 7;
  int cg = idx & 127;
  int br = r >> 9, lr = r & 511;
  ushort4v o;
  if (lr >= NG){ o[0]=0; o[1]=0; o[2]=0; o[3]=0; }
  else {
    float4 v;
    if (br == 0)      v = *(const float4*)&gc[(size_t)lr*HID + cg*4];
    else if (br == 1) v = *(const float4*)&go[(size_t)lr*HID + cg*4];
    else {
      int ps = perm[lr];
      float4 a = *(const float4*)&gc[(size_t)ps*HID + cg*4];
      float4 b = *(const float4*)&go[(size_t)lr*HID + cg*4];
      v = make_float4(a.x+b.x, a.y+b.y, a.z+b.z, a.w+b.w);
    }
    const float* ms = mstat3 + br*1024;
    int c = cg*4;
    o[0] = f2bf((v.x - ms[c+0])*ms[512+c+0] + 1e-4f);
    o[1] = f2bf((v.y - ms[c+1])*ms[512+c+1] + 1e-4f);
    o[2] = f2bf((v.z - ms[c+2])*ms[512+c+2] + 1e-4f);
    o[3] = f2bf((v.w - ms[c+3])*ms[512+c+3] + 1e-4f);
  }
  *(ushort4v*)&out[(size_t)r*HID + cg*4] = o;
}

// ---------------- final: batched BN2 -> fc2 -> log_softmax ----------------
struct ROP { const float* W2[3]; const float* b2[3]; };
__global__ void readout_final3(const unsigned short* __restrict__ T, const float* __restrict__ statsB,
                               float invM, ROP p, float* __restrict__ out){
  int g = blockIdx.x;       // 0..499
  int br = blockIdx.y;      // 0..2
  int l = threadIdx.x;
  const float* stats = statsB + br*1024;
  const float* W2 = p.W2[br];
  const float* b2 = p.b2[br];
  float acc[NCLS];
#pragma unroll
  for (int c=0; c<NCLS; ++c) acc[c] = 0.f;
  uint4 u = ((const uint4*)(T + (size_t)(br*512 + g)*HID))[l];
  float xv[8] = {bf2f(u.x&0xffffu), bf2f(u.x>>16), bf2f(u.y&0xffffu), bf2f(u.y>>16),
                 bf2f(u.z&0xffffu), bf2f(u.z>>16), bf2f(u.w&0xffffu), bf2f(u.w>>16)};
#pragma unroll
  for (int j=0; j<8; ++j){
    int k = l*8 + j;
    float m = stats[k]*invM;
    float rs = rsqrtf(stats[512+k]*invM - m*m + 1e-5f);
    float v = (xv[j] - m)*rs + 1e-4f;
#pragma unroll
    for (int c=0; c<NCLS; ++c) acc[c] += v * W2[k*NCLS + c];
  }
  for (int m=1; m<64; m<<=1){
#pragma unroll
    for (int c=0; c<NCLS; ++c) acc[c] += __shfl_xor(acc[c], m);
  }
  if (l == 0){
    float z[NCLS];
    float mx = -1e30f;
#pragma unroll
    for (int c=0; c<NCLS; ++c){ z[c] = acc[c] + b2[c]; mx = fmaxf(mx, z[c]); }
    float s = 0.f;
#pragma unroll
    for (int c=0; c<NCLS; ++c) s += expf(z[c]-mx);
    float lse = mx + logf(s);
#pragma unroll
    for (int c=0; c<NCLS; ++c) out[(size_t)(br*NG + g)*NCLS + c] = z[c] - lse;
  }
}

extern "C" void kernel_launch(void* const* d_in, const int* in_sizes, int n_in,
                              void* d_out, int out_size, void* d_ws, size_t ws_size,
                              hipStream_t stream){
  (void)in_sizes; (void)n_in; (void)out_size;
  const float* x      = (const float*)d_in[0];
  const int*   ei     = (const int*)d_in[1];
  const int*   batch  = (const int*)d_in[2];
  const int*   perm   = (const int*)d_in[3];
  const float* convfW = (const float*)d_in[4];
  const float* convfB = (const float*)d_in[5];
  const float* convsW = (const float*)d_in[6];
  const float* convsB = (const float*)d_in[7];
  const float* eattW  = (const float*)d_in[8];
  const float* eattB  = (const float*)d_in[9];
  const float* nattW  = (const float*)d_in[10];
  const float* nattB  = (const float*)d_in[11];
  const float* ctxW   = (const float*)d_in[12];
  const float* ctxB   = (const float*)d_in[13];
  const float* objW   = (const float*)d_in[14];
  const float* objB   = (const float*)d_in[15];
  const float* fc1W[3] = {(const float*)d_in[16], (const float*)d_in[20], (const float*)d_in[24]};
  const float* fc1B[3] = {(const float*)d_in[17], (const float*)d_in[21], (const float*)d_in[25]};
  const float* fc2W[3] = {(const float*)d_in[18], (const float*)d_in[22], (const float*)d_in[26]};
  const float* fc2B[3] = {(const float*)d_in[19], (const float*)d_in[23], (const float*)d_in[27]};
  float* out = (float*)d_out;

  char* p = (char*)d_ws;
  auto alloc = [&](size_t bytes)->char*{ char* r = p; p += (bytes + 255) & ~((size_t)255); return r; };
  const int T = NE + NN;
  unsigned short* Xbf = (unsigned short*)alloc((size_t)NN*HID*2);
  unsigned short* Gbf = (unsigned short*)alloc((size_t)NN*HID*2);
  unsigned short* GbfO= (unsigned short*)alloc((size_t)NN*HID*2);
  unsigned short* Abf = (unsigned short*)alloc((size_t)NN*FIN*2);
  unsigned short* WtF = (unsigned short*)alloc((size_t)HID*FIN*2);
  unsigned short* WtL = (unsigned short*)alloc((size_t)3*HID*HID*2);
  unsigned short* WtC = (unsigned short*)alloc((size_t)HID*HID*2);
  unsigned short* WtO = (unsigned short*)alloc((size_t)HID*HID*2);
  unsigned short* WtR = (unsigned short*)alloc((size_t)3*HID*HID*2);
  int* cnt   = (int*)alloc((size_t)NN*4);
  int* fillc = (int*)alloc((size_t)NN*4);
  int* rowp  = (int*)alloc((size_t)(NN+1)*4);
  int* bsum  = (int*)alloc(32*4);
  int* ccol  = (int*)alloc((size_t)T*4);
  int* crow  = (int*)alloc((size_t)T*4);
  int* ceid  = (int*)alloc((size_t)T*4);
  float* w1  = (float*)alloc((size_t)T*4);
  float* wcv = (float*)alloc((size_t)T*4);
  float* wov = (float*)alloc((size_t)T*4);
  float* dis1 = (float*)alloc((size_t)NN*4);
  float* degc = (float*)alloc((size_t)NN*4);
  float* dego = (float*)alloc((size_t)NN*4);
  float* Sc   = (float*)alloc((size_t)NN*4);
  float* So   = (float*)alloc((size_t)NN*4);
  float* stats6 = (float*)alloc(6*1024*4);   // [0]=conv_out [1]=L0 [2]=L1 [3..5]=fc1_c/o/co
  float* mstat  = (float*)alloc(2*HID*4);
  float* mstatCO= (float*)alloc(2*1024*4);
  float* mstat3 = (float*)alloc(3*1024*4);
  float* na   = (float*)alloc((size_t)NN*2*4);
  float* eab  = (float*)alloc((size_t)NN*4*4);
  float* att  = (float*)alloc((size_t)NE*2*4);
  float* gc   = (float*)alloc((size_t)NG*HID*4);
  float* go   = (float*)alloc((size_t)NG*HID*4);
  float* part = (float*)alloc((size_t)BNG*2048*4);
  if ((size_t)(p - (char*)d_ws) > ws_size){
    sentinel_k<<<1,1,0,stream>>>(out);
    return;
  }
  unsigned short* Abf3 = Abf;                 // 1536x512 bf16 (reuse, conv input cast is dead)
  unsigned short* Gbf3 = GbfO;                // fc1 output (reuse)
  const float invNN = 1.0f/(float)NN;
  const float invNG = 1.0f/(float)NG;

  // setup: weights->bf16T + init (one dispatch)
  W2BT wp;
  wp.src[0]=convfW; wp.dst[0]=WtF;
  for (int i=0;i<3;i++){ wp.src[1+i]=convsW+(size_t)i*HID*HID; wp.dst[1+i]=WtL+(size_t)i*HID*HID; }
  wp.src[4]=ctxW; wp.dst[4]=WtC;
  wp.src[5]=objW; wp.dst[5]=WtO;
  for (int i=0;i<3;i++){ wp.src[6+i]=fc1W[i]; wp.dst[6+i]=WtR+(size_t)i*HID*HID; }
  setup_all<<<(FIN*HID + 8*HID*HID + 255)/256, 256, 0, stream>>>(wp, cnt, fillc, degc, dego, Sc, So, stats6);

  // CSR build
  csr_count<<<(NE+255)/256,256,0,stream>>>(ei, cnt);
  scan1<<<(NN+1023)/1024,1024,0,stream>>>(cnt, rowp, dis1, bsum);
  scan3<<<(NN+1023)/1024,1024,0,stream>>>(rowp, bsum);
  csr_fill<<<(T+255)/256,256,0,stream>>>(ei, rowp, cnt, fillc, dis1, ccol, crow, ceid, w1);

  // conv_feat: relu(bn(x) @ Wf + bf) -> Xbf, stats -> stats6[0]
  bnstats_p<<<BNG,1024,0,stream>>>(x, NN, FIN, part);
  bnfin_red<<<(FIN+63)/64,256,0,stream>>>(part, 2*FIN, 0, NN, FIN, mstat);
  bncast<<<((NN*FIN/4)+255)/256,256,0,stream>>>(x, mstat, NN, FIN, Abf);
  gemm_bt<<<dim3((NN+127)/128,4),256,0,stream>>>(Abf, WtF, Xbf, convfB, stats6, NN, FIN, 1);

  // 3 GCN layers
  for (int i=0;i<3;i++){
    aggregate_bn<<<NN/4,256,0,stream>>>(Xbf, rowp, ccol, w1, stats6 + i*1024, invNN, Gbf);
    gemm_bt<<<dim3((NN+127)/128,4),256,0,stream>>>(Gbf, WtL+(size_t)i*HID*HID, Xbf,
                                                   convsB+(size_t)i*HID,
                                                   (i<2) ? (stats6 + (i+1)*1024) : nullptr,
                                                   NN, HID, 1);
  }

  // attention
  att_node<<<(NN+3)/4,256,0,stream>>>(Xbf, nattW, nattB, eattW, na, eab);
  att_edge<<<(NE+255)/256,256,0,stream>>>(ei, eab, eattB, att, degc, dego);
  wco_kernel<<<(T+255)/256,256,0,stream>>>(crow, ccol, ceid, att, degc, dego, na, wcv, wov, Sc, So);

  // ctx + obj: dual stats -> dual agg -> 2 gemms -> 1 pool dispatch
  bnstats_dual<<<BNG,1024,0,stream>>>(Xbf, na, part);
  bnfin_red2<<<dim3(8,2),256,0,stream>>>(part, mstatCO);
  aggregate_dual<<<NN/4,256,0,stream>>>(Xbf, rowp, ccol, wcv, wov, Sc, So, mstatCO, Gbf, GbfO);
  gemm_bt<<<dim3((NN+127)/128,4),256,0,stream>>>(Gbf, WtC, Xbf, ctxB, nullptr, NN, HID, 1);   // ctx -> Xbf
  gemm_bt<<<dim3((NN+127)/128,4),256,0,stream>>>(GbfO, WtO, Gbf, objB, nullptr, NN, HID, 1);  // obj -> Gbf
  pool2<<<dim3(NG,2),256,0,stream>>>(Xbf, Gbf, batch, gc, go);

  // readouts, batched across the 3 branches
  bnstats3<<<dim3(NB3,3),256,0,stream>>>(gc, go, perm, part);
  bnfin3<<<dim3(8,3),256,0,stream>>>(part, mstat3);
  bncast3<<<(1536*128+255)/256,256,0,stream>>>(gc, go, perm, mstat3, Abf3);
  FC1P fp;
  for (int i=0;i<3;i++){ fp.Bt[i] = WtR+(size_t)i*HID*HID; fp.bias[i] = fc1B[i]; }
  gemm_fc1<<<dim3(12,4),256,0,stream>>>(Abf3, fp, Gbf3, stats6 + 3*1024);
  ROP rp;
  for (int i=0;i<3;i++){ rp.W2[i] = fc2W[i]; rp.b2[i] = fc2B[i]; }
  readout_final3<<<dim3(NG,3),64,0,stream>>>(Gbf3, stats6 + 3*1024, invNG, rp, out);
}

// Round 6
// 476.619 us; speedup vs baseline: 2.1550x; 1.0123x over previous
//
#include <hip/hip_runtime.h>
#include <stdint.h>

#define NN 20000
#define NE 160000
#define NG 500
#define FIN 128
#define HID 512
#define NCLS 10
#define BNG 256
#define NB3 32

typedef __attribute__((ext_vector_type(8))) short short8;
typedef __attribute__((ext_vector_type(4))) float f32x4;
typedef __attribute__((ext_vector_type(4))) unsigned short ushort4v;

__device__ __forceinline__ float bf2f(unsigned int u){
  union{unsigned int i; float f;} x; x.i = u<<16; return x.f;
}
__device__ __forceinline__ unsigned short f2bf(float f){
  union{float f; unsigned int i;} x; x.f=f;
  unsigned int r = x.i + 0x7fffu + ((x.i>>16)&1u);
  return (unsigned short)(r>>16);
}
__device__ __forceinline__ unsigned int pk2(float a, float b){
  return (unsigned int)f2bf(a) | ((unsigned int)f2bf(b) << 16);
}

__device__ __forceinline__ void gload16(unsigned short* lds, const unsigned short* g){
  __builtin_amdgcn_global_load_lds((const __attribute__((address_space(1))) unsigned int*)g,
                                   (__attribute__((address_space(3))) unsigned int*)lds,
                                   16, 0, 0);
}

__device__ __forceinline__ void fma8(float* acc, uint4 v, float w){
  acc[0] += w*bf2f(v.x & 0xffffu); acc[1] += w*bf2f(v.x >> 16);
  acc[2] += w*bf2f(v.y & 0xffffu); acc[3] += w*bf2f(v.y >> 16);
  acc[4] += w*bf2f(v.z & 0xffffu); acc[5] += w*bf2f(v.z >> 16);
  acc[6] += w*bf2f(v.w & 0xffffu); acc[7] += w*bf2f(v.w >> 16);
}

__global__ void sentinel_k(float* out){ out[0] = 12345.0f; }

// ---------------- setup: all weight transposes + all init in one dispatch ----------------
struct W2BT { const float* src[9]; unsigned short* dst[9]; };
__global__ void setup_all(W2BT p, int* __restrict__ cnt, int* __restrict__ fillc,
                          float* __restrict__ degc, float* __restrict__ dego,
                          float* __restrict__ Sc, float* __restrict__ So,
                          float* __restrict__ stats6){
  int idx = blockIdx.x*blockDim.x + threadIdx.x;
  if (idx < FIN*HID + 8*HID*HID){
    int seg, off, K;
    if (idx < FIN*HID){ seg = 0; off = idx; K = FIN; }
    else {
      int r = idx - FIN*HID;
      seg = 1 + (r >> 18); off = r & (HID*HID-1); K = HID;
    }
    int k = off >> 9, n = off & 511;
    p.dst[seg][(size_t)n*K + k] = f2bf(p.src[seg][off]);
  }
  if (idx < NN){ cnt[idx]=0; fillc[idx]=0; degc[idx]=1.0f; dego[idx]=1.0f; Sc[idx]=0.f; So[idx]=0.f; }
  if (idx < 6*1024) stats6[idx] = 0.f;
}

// ---------------- BN stats stage 1 (f32 input; conv input only) ----------------
__global__ __launch_bounds__(1024) void bnstats_p(const float* __restrict__ X, int M, int F,
                                                  float* __restrict__ partials){
  __shared__ float lds[1024*9];
  const int t = threadIdx.x;
  const int cg = F >> 2;
  const int cid = t & (cg-1);
  const int rid = t / cg;
  const int rpb = 1024 / cg;
  float s0=0,s1=0,s2=0,s3=0,q0=0,q1=0,q2=0,q3=0;
  const int rowsPer = (M + BNG - 1)/BNG;
  int r0 = blockIdx.x*rowsPer, r1 = r0 + rowsPer; if (r1 > M) r1 = M;
  for (int r = r0 + rid; r < r1; r += rpb){
    float4 v = *(const float4*)&X[(size_t)r*F + cid*4];
    s0+=v.x; q0+=v.x*v.x; s1+=v.y; q1+=v.y*v.y; s2+=v.z; q2+=v.z*v.z; s3+=v.w; q3+=v.w*v.w;
  }
  int base = (rid*cg + cid)*9;
  lds[base+0]=s0; lds[base+1]=s1; lds[base+2]=s2; lds[base+3]=s3;
  lds[base+4]=q0; lds[base+5]=q1; lds[base+6]=q2; lds[base+7]=q3;
  __syncthreads();
  if (t < cg*8){
    int ci = t >> 3, i = t & 7;
    float acc = 0.f;
    for (int g=0; g<rpb; ++g) acc += lds[(g*cg + ci)*9 + i];
    int col = ci*4 + (i & 3);
    partials[(size_t)blockIdx.x*(2*F) + ((i < 4) ? col : F + col)] = acc;
  }
}

// ---------------- dual BN stats on bf16 X ----------------
__global__ __launch_bounds__(1024) void bnstats_dual(const unsigned short* __restrict__ X,
                                                     const float* __restrict__ na,
                                                     float* __restrict__ partials){
  __shared__ float lds[1024*17];
  const int t = threadIdx.x;
  const int cid = t & 127;
  const int rid = t >> 7;
  float sC[4]={0,0,0,0}, qC[4]={0,0,0,0}, sO[4]={0,0,0,0}, qO[4]={0,0,0,0};
  const int rowsPer = (NN + BNG - 1)/BNG;
  int r0 = blockIdx.x*rowsPer, r1 = r0 + rowsPer; if (r1 > NN) r1 = NN;
  for (int r = r0 + rid; r < r1; r += 8){
    float a0 = na[2*r], a1 = na[2*r+1];
    uint2 u = *(const uint2*)&X[(size_t)r*HID + cid*4];
    float e[4] = {bf2f(u.x & 0xffffu), bf2f(u.x >> 16), bf2f(u.y & 0xffffu), bf2f(u.y >> 16)};
#pragma unroll
    for (int i=0;i<4;i++){
      float vc = e[i]*a0, vo = e[i]*a1;
      sC[i]+=vc; qC[i]+=vc*vc; sO[i]+=vo; qO[i]+=vo*vo;
    }
  }
  int base = (rid*128 + cid)*17;
#pragma unroll
  for (int i=0;i<4;i++){
    lds[base+i]=sC[i]; lds[base+4+i]=qC[i]; lds[base+8+i]=sO[i]; lds[base+12+i]=qO[i];
  }
  __syncthreads();
  for (int idx = t; idx < 2048; idx += 1024){
    int ci = idx >> 4, i = idx & 15;
    float acc = 0.f;
    for (int g=0; g<8; ++g) acc += lds[(g*128 + ci)*17 + i];
    int grp = i >> 2, col = ci*4 + (i & 3);
    partials[(size_t)blockIdx.x*2048 + grp*HID + col] = acc;
  }
}

// ---------------- reduce partials -> mean/rstd ----------------
__global__ void bnfin_red(const float* __restrict__ partials, int stride, int off,
                          int M, int F, float* __restrict__ mstat){
  __shared__ float lds[4][64][2];
  int t = threadIdx.x;
  int cl = t & 63, ch = t >> 6;
  int c = blockIdx.x*64 + cl;
  float s = 0.f, q = 0.f;
  if (c < F){
    for (int b = ch*64; b < ch*64 + 64; ++b){
      s += partials[(size_t)b*stride + off + c];
      q += partials[(size_t)b*stride + off + F + c];
    }
  }
  lds[ch][cl][0] = s; lds[ch][cl][1] = q;
  __syncthreads();
  if (ch == 0 && c < F){
    s = lds[0][cl][0]+lds[1][cl][0]+lds[2][cl][0]+lds[3][cl][0];
    q = lds[0][cl][1]+lds[1][cl][1]+lds[2][cl][1]+lds[3][cl][1];
    float m = s/(float)M;
    float v = q/(float)M - m*m;
    mstat[c] = m;
    mstat[F+c] = rsqrtf(v + 1e-5f);
  }
}

__global__ void bnfin_red2(const float* __restrict__ partials, float* __restrict__ mstatCO){
  __shared__ float lds[4][64][2];
  int t = threadIdx.x;
  int cl = t & 63, ch = t >> 6;
  int c = blockIdx.x*64 + cl;
  int off = blockIdx.y*1024;
  float s = 0.f, q = 0.f;
  for (int b = ch*64; b < ch*64 + 64; ++b){
    s += partials[(size_t)b*2048 + off + c];
    q += partials[(size_t)b*2048 + off + HID + c];
  }
  lds[ch][cl][0] = s; lds[ch][cl][1] = q;
  __syncthreads();
  if (ch == 0){
    s = lds[0][cl][0]+lds[1][cl][0]+lds[2][cl][0]+lds[3][cl][0];
    q = lds[0][cl][1]+lds[1][cl][1]+lds[2][cl][1]+lds[3][cl][1];
    float m = s/(float)NN;
    float v = q/(float)NN - m*m;
    mstatCO[blockIdx.y*1024 + c] = m;
    mstatCO[blockIdx.y*1024 + HID + c] = rsqrtf(v + 1e-5f);
  }
}

// ---------------- BN->bf16 cast (f32 input; conv input only) ----------------
__global__ void bncast(const float* __restrict__ X, const float* __restrict__ mstat,
                       int M, int F, unsigned short* __restrict__ out){
  int idx = blockIdx.x*blockDim.x + threadIdx.x;
  int total4 = M*F/4;
  if (idx >= total4) return;
  int base = idx*4;
  int c = base & (F-1);
  float4 v = *(const float4*)&X[base];
  ushort4v o;
  o[0] = f2bf((v.x - mstat[c+0])*mstat[F+c+0] + 1e-4f);
  o[1] = f2bf((v.y - mstat[c+1])*mstat[F+c+1] + 1e-4f);
  o[2] = f2bf((v.z - mstat[c+2])*mstat[F+c+2] + 1e-4f);
  o[3] = f2bf((v.w - mstat[c+3])*mstat[F+c+3] + 1e-4f);
  *(ushort4v*)&out[base] = o;
}

// ---------------- CSR build ----------------
__global__ void csr_count(const int* __restrict__ ei, int* __restrict__ cnt){
  int e = blockIdx.x*blockDim.x + threadIdx.x;
  if (e < NE) atomicAdd(&cnt[ei[e]], 1);
}

__global__ __launch_bounds__(1024) void scan1(const int* __restrict__ cnt, int* __restrict__ rowp,
                                              float* __restrict__ dis1, int* __restrict__ bsum){
  __shared__ int buf[1024];
  int t = threadIdx.x;
  int i = blockIdx.x*1024 + t;
  int v = 0;
  if (i < NN){ v = cnt[i] + 1; dis1[i] = rsqrtf((float)v); }
  buf[t] = v;
  __syncthreads();
  for (int off=1; off<1024; off<<=1){
    int xv = (t >= off) ? buf[t-off] : 0;
    __syncthreads();
    buf[t] += xv;
    __syncthreads();
  }
  if (i < NN) rowp[i+1] = buf[t];
  if (t == 1023) bsum[blockIdx.x] = buf[1023];
}

__global__ __launch_bounds__(1024) void scan3(int* __restrict__ rowp, const int* __restrict__ bsum){
  __shared__ int base;
  int bx = blockIdx.x;
  if (threadIdx.x == 0){
    int a = 0;
    for (int b=0; b<bx; ++b) a += bsum[b];
    base = a;
  }
  __syncthreads();
  int i = bx*1024 + threadIdx.x;
  if (i < NN) rowp[i+1] += base;
  if (i == 0) rowp[0] = 0;
}

// csr_fill + w1 fused; also builds interleaved {col, w1} pairs
__global__ void csr_fill(const int* __restrict__ ei, const int* __restrict__ rowp,
                         const int* __restrict__ cnt, int* __restrict__ fillc,
                         const float* __restrict__ dis1,
                         int* __restrict__ ccol, int* __restrict__ crow, int* __restrict__ ceid,
                         int2* __restrict__ cw1){
  int id = blockIdx.x*blockDim.x + threadIdx.x;
  if (id < NE){
    int r = ei[id], c = ei[NE + id];
    int pos = atomicAdd(&fillc[r], 1);
    int idx = rowp[r] + pos;
    ccol[idx] = c; crow[idx] = r; ceid[idx] = id;
    cw1[idx] = make_int2(c, __float_as_int(dis1[r]*dis1[c]));
  } else if (id < NE + NN){
    int i = id - NE;
    int idx = rowp[i] + cnt[i];
    ccol[idx] = i; crow[idx] = i; ceid[idx] = -1;
    cw1[idx] = make_int2(i, __float_as_int(dis1[i]*dis1[i]));
  }
}

// ---------------- attention (bf16 X), weights staged in LDS ----------------
__global__ void att_node(const unsigned short* __restrict__ X, const float* __restrict__ nW,
                         const float* __restrict__ nb, const float* __restrict__ eW,
                         float* __restrict__ na, float* __restrict__ eab){
  __shared__ float wnl[1024], wet[1024], web[1024];
  int t = threadIdx.x;
  for (int i=t; i<1024; i+=256){ wnl[i]=nW[i]; wet[i]=eW[i]; web[i]=eW[1024+i]; }
  __syncthreads();
  int wv = blockIdx.x*4 + (t >> 6);
  int l = t & 63;
  uint4 u = ((const uint4*)(X + (size_t)wv*HID))[l];
  float xv[8] = {bf2f(u.x&0xffffu), bf2f(u.x>>16), bf2f(u.y&0xffffu), bf2f(u.y>>16),
                 bf2f(u.z&0xffffu), bf2f(u.z>>16), bf2f(u.w&0xffffu), bf2f(u.w>>16)};
  float s0=0,s1=0,s2=0,s3=0,s4=0,s5=0;
#pragma unroll
  for (int j=0; j<8; ++j){
    int k = l*8 + j;
    float x = xv[j];
    s0 += x * wnl[2*k];   s1 += x * wnl[2*k+1];
    s2 += x * wet[2*k];   s3 += x * wet[2*k+1];
    s4 += x * web[2*k];   s5 += x * web[2*k+1];
  }
  for (int m=1; m<64; m<<=1){
    s0 += __shfl_xor(s0,m); s1 += __shfl_xor(s1,m); s2 += __shfl_xor(s2,m);
    s3 += __shfl_xor(s3,m); s4 += __shfl_xor(s4,m); s5 += __shfl_xor(s5,m);
  }
  if (l == 0){
    float z0 = s0 + nb[0], z1 = s1 + nb[1];
    float mx = fmaxf(z0,z1);
    float e0 = expf(z0-mx), e1 = expf(z1-mx);
    float inv = 1.0f/(e0+e1);
    na[2*wv] = e0*inv; na[2*wv+1] = e1*inv;
    eab[4*wv] = s2; eab[4*wv+1] = s3; eab[4*wv+2] = s4; eab[4*wv+3] = s5;
  }
}

__global__ void att_edge(const int* __restrict__ ei, const float* __restrict__ eab,
                         const float* __restrict__ eb, float* __restrict__ att,
                         float* __restrict__ degc, float* __restrict__ dego){
  int e = blockIdx.x*blockDim.x + threadIdx.x;
  if (e >= NE) return;
  int r = ei[e], c = ei[NE+e];
  float z0 = eab[4*r]   + eab[4*c+2] + eb[0];
  float z1 = eab[4*r+1] + eab[4*c+3] + eb[1];
  float mx = fmaxf(z0,z1);
  float e0 = expf(z0-mx), e1 = expf(z1-mx);
  float inv = 1.0f/(e0+e1);
  float a0 = e0*inv, a1 = e1*inv;
  att[2*e] = a0; att[2*e+1] = a1;
  atomicAdd(&degc[r], a0);
  atomicAdd(&dego[r], a1);
}

__global__ void wco_kernel(const int* __restrict__ crow, const int* __restrict__ ccol,
                           const int* __restrict__ ceid, const float* __restrict__ att,
                           const float* __restrict__ degc, const float* __restrict__ dego,
                           const float* __restrict__ na,
                           float* __restrict__ wcv, float* __restrict__ wov,
                           float* __restrict__ Sc, float* __restrict__ So){
  int j = blockIdx.x*blockDim.x + threadIdx.x;
  if (j >= NE + NN) return;
  int r = crow[j], c = ccol[j], e = ceid[j];
  float a0 = (e < 0) ? 1.0f : att[2*e];
  float a1 = (e < 0) ? 1.0f : att[2*e+1];
  float wc = rsqrtf(degc[r]) * a0 * rsqrtf(degc[c]);
  float wo = rsqrtf(dego[r]) * a1 * rsqrtf(dego[c]);
  wcv[j] = wc * na[2*c];
  wov[j] = wo * na[2*c+1];
  atomicAdd(&Sc[r], wc);
  atomicAdd(&So[r], wo);
}

// ---------------- wave-per-row aggregation (int2 pairs), 4-deep, BN affine epilogue ----------------
__global__ __launch_bounds__(256) void aggregate_bn(const unsigned short* __restrict__ A,
                                                    const int* __restrict__ rowp,
                                                    const int2* __restrict__ cw,
                                                    const float* __restrict__ stats,
                                                    float invM,
                                                    unsigned short* __restrict__ out){
  int row = blockIdx.x*4 + (threadIdx.x >> 6);
  int l = threadIdx.x & 63;
  const uint4* Av = (const uint4*)A;
  int s = rowp[row], e = rowp[row+1];
  float acc[8] = {0,0,0,0,0,0,0,0};
  float sw = 0.f;
  int j = s;
  for (; j+3 < e; j += 4){
    int2 p0 = cw[j], p1 = cw[j+1], p2 = cw[j+2], p3 = cw[j+3];
    float w0 = __int_as_float(p0.y), w1 = __int_as_float(p1.y);
    float w2 = __int_as_float(p2.y), w3 = __int_as_float(p3.y);
    uint4 v0 = Av[(size_t)p0.x*64 + l];
    uint4 v1 = Av[(size_t)p1.x*64 + l];
    uint4 v2 = Av[(size_t)p2.x*64 + l];
    uint4 v3 = Av[(size_t)p3.x*64 + l];
    fma8(acc, v0, w0); fma8(acc, v1, w1); fma8(acc, v2, w2); fma8(acc, v3, w3);
    sw += w0 + w1 + w2 + w3;
  }
  for (; j < e; ++j){
    int2 p = cw[j];
    float w = __int_as_float(p.y);
    uint4 v = Av[(size_t)p.x*64 + l];
    fma8(acc, v, w);
    sw += w;
  }
  float g[8];
#pragma unroll
  for (int i=0;i<8;i++){
    int c = l*8 + i;
    float m = stats[c]*invM;
    float rs = rsqrtf(stats[512+c]*invM - m*m + 1e-5f);
    g[i] = rs*acc[i] + sw*(1e-4f - m*rs);
  }
  uint4 o;
  o.x = pk2(g[0],g[1]); o.y = pk2(g[2],g[3]); o.z = pk2(g[4],g[5]); o.w = pk2(g[6],g[7]);
  ((uint4*)out)[(size_t)row*64 + l] = o;
}

__global__ __launch_bounds__(256) void aggregate_dual(const unsigned short* __restrict__ A,
                                                      const int* __restrict__ rowp,
                                                      const int* __restrict__ ccol,
                                                      const float* __restrict__ wc,
                                                      const float* __restrict__ wo,
                                                      const float* __restrict__ Sc,
                                                      const float* __restrict__ So,
                                                      const float* __restrict__ mstatCO,
                                                      unsigned short* __restrict__ outC,
                                                      unsigned short* __restrict__ outO){
  int row = blockIdx.x*4 + (threadIdx.x >> 6);
  int l = threadIdx.x & 63;
  const uint4* Av = (const uint4*)A;
  int s = rowp[row], e = rowp[row+1];
  float aC[8] = {0,0,0,0,0,0,0,0};
  float aO[8] = {0,0,0,0,0,0,0,0};
  int j = s;
  for (; j+3 < e; j += 4){
    int c0 = ccol[j], c1 = ccol[j+1], c2 = ccol[j+2], c3 = ccol[j+3];
    float wc0=wc[j], wc1=wc[j+1], wc2=wc[j+2], wc3=wc[j+3];
    float wo0=wo[j], wo1=wo[j+1], wo2=wo[j+2], wo3=wo[j+3];
    uint4 v0 = Av[(size_t)c0*64 + l];
    uint4 v1 = Av[(size_t)c1*64 + l];
    uint4 v2 = Av[(size_t)c2*64 + l];
    uint4 v3 = Av[(size_t)c3*64 + l];
    fma8(aC, v0, wc0); fma8(aO, v0, wo0);
    fma8(aC, v1, wc1); fma8(aO, v1, wo1);
    fma8(aC, v2, wc2); fma8(aO, v2, wo2);
    fma8(aC, v3, wc3); fma8(aO, v3, wo3);
  }
  for (; j < e; ++j){
    uint4 v = Av[(size_t)ccol[j]*64 + l];
    fma8(aC, v, wc[j]); fma8(aO, v, wo[j]);
  }
  float ScR = Sc[row], SoR = So[row];
  float gC[8], gO[8];
#pragma unroll
  for (int i=0;i<8;i++){
    int c = l*8 + i;
    float mc = mstatCO[c],      rc = mstatCO[512+c];
    float mo = mstatCO[1024+c], ro = mstatCO[1536+c];
    gC[i] = rc*aC[i] + ScR*(1e-4f - mc*rc);
    gO[i] = ro*aO[i] + SoR*(1e-4f - mo*ro);
  }
  uint4 oc, oo;
  oc.x = pk2(gC[0],gC[1]); oc.y = pk2(gC[2],gC[3]); oc.z = pk2(gC[4],gC[5]); oc.w = pk2(gC[6],gC[7]);
  oo.x = pk2(gO[0],gO[1]); oo.y = pk2(gO[2],gO[3]); oo.z = pk2(gO[4],gO[5]); oo.w = pk2(gO[6],gO[7]);
  ((uint4*)outC)[(size_t)row*64 + l] = oc;
  ((uint4*)outO)[(size_t)row*64 + l] = oo;
}

// ---------------- bf16 MFMA GEMM, dbuf + counted-vmcnt barriers; optional 2nd problem ----------------
__global__ __launch_bounds__(256) void gemm_bt(const unsigned short* __restrict__ A,
                                               const unsigned short* __restrict__ Bt,
                                               unsigned short* __restrict__ O,
                                               const float* __restrict__ bias,
                                               float* __restrict__ stats,
                                               int M, int K, int relu, int split,
                                               const unsigned short* A2,
                                               const unsigned short* Bt2,
                                               unsigned short* O2,
                                               const float* bias2){
  __shared__ unsigned short As[2][128*32];
  __shared__ unsigned short Bs[2][128*32];
  const int tid = threadIdx.x;
  const int w = tid >> 6, l = tid & 63;
  int bx = blockIdx.x;
  if (split && bx >= split){ A = A2; Bt = Bt2; O = O2; bias = bias2; bx -= split; }
  const int m0 = bx*128, n0 = blockIdx.y*128;
  const int wm = w >> 1, wn = w & 1;
  const int lr = l & 15, lh = l >> 4;

  f32x4 acc[4][4];
#pragma unroll
  for (int i=0;i<4;i++)
#pragma unroll
    for (int j=0;j<4;j++) acc[i][j] = 0.0f;

  const int q0 = w*2, q1 = w*2+1;
  const int sub = l >> 2;
  const int kc  = (l & 3)*8;
  int ma0 = m0 + q0*16 + sub; if (ma0 >= M) ma0 = M-1;
  int ma1 = m0 + q1*16 + sub; if (ma1 >= M) ma1 = M-1;
  const int nb0 = n0 + q0*16 + sub;
  const int nb1 = n0 + q1*16 + sub;
  const unsigned short* Ar0 = A + (size_t)ma0*K + kc;
  const unsigned short* Ar1 = A + (size_t)ma1*K + kc;
  const unsigned short* Br0 = Bt + (size_t)nb0*K + kc;
  const unsigned short* Br1 = Bt + (size_t)nb1*K + kc;

  const int NT = K >> 5;
  gload16(&As[0][q0*512], Ar0);
  gload16(&As[0][q1*512], Ar1);
  gload16(&Bs[0][q0*512], Br0);
  gload16(&Bs[0][q1*512], Br1);
  int cur = 0;
  for (int t=0; t<NT; ++t){
    if (t+1 < NT){
      int k1 = (t+1) << 5;
      gload16(&As[cur^1][q0*512], Ar0 + k1);
      gload16(&As[cur^1][q1*512], Ar1 + k1);
      gload16(&Bs[cur^1][q0*512], Br0 + k1);
      gload16(&Bs[cur^1][q1*512], Br1 + k1);
      asm volatile("s_waitcnt vmcnt(4)" ::: "memory");   // prev tile's 4 loads landed; 4 new stay in flight
    } else {
      asm volatile("s_waitcnt vmcnt(0)" ::: "memory");
    }
    __builtin_amdgcn_s_barrier();
    asm volatile("" ::: "memory");
    short8 af[4], bfr[4];
#pragma unroll
    for (int fm=0; fm<4; ++fm) af[fm]  = *(const short8*)&As[cur][(wm*64 + fm*16 + lr)*32 + lh*8];
#pragma unroll
    for (int fn=0; fn<4; ++fn) bfr[fn] = *(const short8*)&Bs[cur][(wn*64 + fn*16 + lr)*32 + lh*8];
#pragma unroll
    for (int fm=0; fm<4; ++fm)
#pragma unroll
      for (int fn=0; fn<4; ++fn)
        acc[fm][fn] = __builtin_amdgcn_mfma_f32_16x16x32_bf16(af[fm], bfr[fn], acc[fm][fn], 0, 0, 0);
    asm volatile("" ::: "memory");
    __builtin_amdgcn_s_barrier();
    asm volatile("" ::: "memory");
    cur ^= 1;
  }
  float bv[4], cs[4]={0,0,0,0}, cq[4]={0,0,0,0};
  int col[4];
#pragma unroll
  for (int fn=0; fn<4; ++fn){ col[fn] = n0 + wn*64 + fn*16 + lr; bv[fn] = bias[col[fn]]; }
#pragma unroll
  for (int fm=0; fm<4; ++fm){
#pragma unroll
    for (int j=0; j<4; ++j){
      int row = m0 + wm*64 + fm*16 + lh*4 + j;
      if (row < M){
#pragma unroll
        for (int fn=0; fn<4; ++fn){
          float v = acc[fm][fn][j] + bv[fn];
          if (relu) v = fmaxf(v, 0.f);
          O[(size_t)row*HID + col[fn]] = f2bf(v);
          cs[fn] += v; cq[fn] += v*v;
        }
      }
    }
  }
  if (stats){
#pragma unroll
    for (int m=16; m<64; m<<=1){
#pragma unroll
      for (int fn=0; fn<4; ++fn){ cs[fn] += __shfl_xor(cs[fn], m); cq[fn] += __shfl_xor(cq[fn], m); }
    }
    if (lh == 0){
#pragma unroll
      for (int fn=0; fn<4; ++fn){
        atomicAdd(&stats[col[fn]], cs[fn]);
        atomicAdd(&stats[512+col[fn]], cq[fn]);
      }
    }
  }
}

// batched fc1 gemm: M=1536 (3 branches x 512 rows), branch-indexed weights
struct FC1P { const unsigned short* Bt[3]; const float* bias[3]; };
__global__ __launch_bounds__(256) void gemm_fc1(const unsigned short* __restrict__ A, FC1P p,
                                                unsigned short* __restrict__ O,
                                                float* __restrict__ statsB){
  __shared__ unsigned short As[2][128*32];
  __shared__ unsigned short Bs[2][128*32];
  const int tid = threadIdx.x;
  const int w = tid >> 6, l = tid & 63;
  const int m0 = blockIdx.x*128, n0 = blockIdx.y*128;
  const int branch = blockIdx.x >> 2;
  const unsigned short* Bt = p.Bt[branch];
  const float* bias = p.bias[branch];
  float* stats = statsB + branch*1024;
  const int K = HID;
  const int wm = w >> 1, wn = w & 1;
  const int lr = l & 15, lh = l >> 4;

  f32x4 acc[4][4];
#pragma unroll
  for (int i=0;i<4;i++)
#pragma unroll
    for (int j=0;j<4;j++) acc[i][j] = 0.0f;

  const int q0 = w*2, q1 = w*2+1;
  const int sub = l >> 2;
  const int kc  = (l & 3)*8;
  const int ma0 = m0 + q0*16 + sub;
  const int ma1 = m0 + q1*16 + sub;
  const int nb0 = n0 + q0*16 + sub;
  const int nb1 = n0 + q1*16 + sub;
  const unsigned short* Ar0 = A + (size_t)ma0*K + kc;
  const unsigned short* Ar1 = A + (size_t)ma1*K + kc;
  const unsigned short* Br0 = Bt + (size_t)nb0*K + kc;
  const unsigned short* Br1 = Bt + (size_t)nb1*K + kc;

  const int NT = K >> 5;
  gload16(&As[0][q0*512], Ar0);
  gload16(&As[0][q1*512], Ar1);
  gload16(&Bs[0][q0*512], Br0);
  gload16(&Bs[0][q1*512], Br1);
  int cur = 0;
  for (int t=0; t<NT; ++t){
    if (t+1 < NT){
      int k1 = (t+1) << 5;
      gload16(&As[cur^1][q0*512], Ar0 + k1);
      gload16(&As[cur^1][q1*512], Ar1 + k1);
      gload16(&Bs[cur^1][q0*512], Br0 + k1);
      gload16(&Bs[cur^1][q1*512], Br1 + k1);
      asm volatile("s_waitcnt vmcnt(4)" ::: "memory");
    } else {
      asm volatile("s_waitcnt vmcnt(0)" ::: "memory");
    }
    __builtin_amdgcn_s_barrier();
    asm volatile("" ::: "memory");
    short8 af[4], bfr[4];
#pragma unroll
    for (int fm=0; fm<4; ++fm) af[fm]  = *(const short8*)&As[cur][(wm*64 + fm*16 + lr)*32 + lh*8];
#pragma unroll
    for (int fn=0; fn<4; ++fn) bfr[fn] = *(const short8*)&Bs[cur][(wn*64 + fn*16 + lr)*32 + lh*8];
#pragma unroll
    for (int fm=0; fm<4; ++fm)
#pragma unroll
      for (int fn=0; fn<4; ++fn)
        acc[fm][fn] = __builtin_amdgcn_mfma_f32_16x16x32_bf16(af[fm], bfr[fn], acc[fm][fn], 0, 0, 0);
    asm volatile("" ::: "memory");
    __builtin_amdgcn_s_barrier();
    asm volatile("" ::: "memory");
    cur ^= 1;
  }
  float bv[4], cs[4]={0,0,0,0}, cq[4]={0,0,0,0};
  int col[4];
#pragma unroll
  for (int fn=0; fn<4; ++fn){ col[fn] = n0 + wn*64 + fn*16 + lr; bv[fn] = bias[col[fn]]; }
#pragma unroll
  for (int fm=0; fm<4; ++fm){
#pragma unroll
    for (int j=0; j<4; ++j){
      int row = m0 + wm*64 + fm*16 + lh*4 + j;
      bool real = (row & 511) < NG;
#pragma unroll
      for (int fn=0; fn<4; ++fn){
        float v = fmaxf(acc[fm][fn][j] + bv[fn], 0.f);
        O[(size_t)row*HID + col[fn]] = f2bf(v);
        if (real){ cs[fn] += v; cq[fn] += v*v; }
      }
    }
  }
#pragma unroll
  for (int m=16; m<64; m<<=1){
#pragma unroll
    for (int fn=0; fn<4; ++fn){ cs[fn] += __shfl_xor(cs[fn], m); cq[fn] += __shfl_xor(cq[fn], m); }
  }
  if (lh == 0){
#pragma unroll
    for (int fn=0; fn<4; ++fn){
      atomicAdd(&stats[col[fn]], cs[fn]);
      atomicAdd(&stats[512+col[fn]], cq[fn]);
    }
  }
}

// ---------------- pooling, both branches in one dispatch ----------------
__global__ void pool2(const unsigned short* __restrict__ XC, const unsigned short* __restrict__ XO,
                      const int* __restrict__ batch, float* __restrict__ gc, float* __restrict__ go){
  int g = blockIdx.x;
  int t = threadIdx.x;
  const unsigned short* X = blockIdx.y ? XO : XC;
  float* out = blockIdx.y ? go : gc;
  int lo = 0, hi = NN;
  while (lo < hi){ int mid = (lo+hi) >> 1; if (batch[mid] < g) lo = mid+1; else hi = mid; }
  int s = lo;
  lo = 0; hi = NN;
  while (lo < hi){ int mid = (lo+hi) >> 1; if (batch[mid] < g+1) lo = mid+1; else hi = mid; }
  int e = lo;
  float a0 = 0.f, a1 = 0.f;
  for (int i=s; i<e; ++i){
    unsigned int v = *(const unsigned int*)&X[(size_t)i*HID + t*2];
    a0 += bf2f(v & 0xffffu); a1 += bf2f(v >> 16);
  }
  out[(size_t)g*HID + t*2]     = a0;
  out[(size_t)g*HID + t*2 + 1] = a1;
}

// ---------------- readout BN1: batched 3-branch stats ----------------
__global__ __launch_bounds__(256) void bnstats3(const float* __restrict__ gc, const float* __restrict__ go,
                                                const int* __restrict__ perm, float* __restrict__ partials){
  __shared__ float lds[256*9];
  int br = blockIdx.y;
  int t = threadIdx.x;
  int cid = t & 127, rid = t >> 7;
  float s[4]={0,0,0,0}, q[4]={0,0,0,0};
  const int rowsPer = (NG + NB3 - 1)/NB3;
  int r0 = blockIdx.x*rowsPer, r1 = r0 + rowsPer; if (r1 > NG) r1 = NG;
  for (int r = r0 + rid; r < r1; r += 2){
    float4 v;
    if (br == 0)      v = *(const float4*)&gc[(size_t)r*HID + cid*4];
    else if (br == 1) v = *(const float4*)&go[(size_t)r*HID + cid*4];
    else {
      int ps = perm[r];
      float4 a = *(const float4*)&gc[(size_t)ps*HID + cid*4];
      float4 b = *(const float4*)&go[(size_t)r*HID + cid*4];
      v = make_float4(a.x+b.x, a.y+b.y, a.z+b.z, a.w+b.w);
    }
    float e[4] = {v.x, v.y, v.z, v.w};
#pragma unroll
    for (int i=0;i<4;i++){ s[i]+=e[i]; q[i]+=e[i]*e[i]; }
  }
  int base = (rid*128 + cid)*9;
#pragma unroll
  for (int i=0;i<4;i++){ lds[base+i]=s[i]; lds[base+4+i]=q[i]; }
  __syncthreads();
  for (int o = t; o < 1024; o += 256){
    int issq = o >> 9, col = o & 511;
    int ci = col >> 2, i = col & 3;
    float acc = lds[(0*128 + ci)*9 + issq*4 + i] + lds[(1*128 + ci)*9 + issq*4 + i];
    partials[(size_t)(br*NB3 + blockIdx.x)*1024 + issq*512 + col] = acc;
  }
}

__global__ void bnfin3(const float* __restrict__ partials, float* __restrict__ mstat3){
  __shared__ float lds[4][64][2];
  int t = threadIdx.x;
  int cl = t & 63, ch = t >> 6;
  int c = blockIdx.x*64 + cl;
  int br = blockIdx.y;
  float s = 0.f, q = 0.f;
  for (int b = ch*8; b < ch*8 + 8; ++b){
    s += partials[(size_t)(br*NB3 + b)*1024 + c];
    q += partials[(size_t)(br*NB3 + b)*1024 + 512 + c];
  }
  lds[ch][cl][0] = s; lds[ch][cl][1] = q;
  __syncthreads();
  if (ch == 0){
    s = lds[0][cl][0]+lds[1][cl][0]+lds[2][cl][0]+lds[3][cl][0];
    q = lds[0][cl][1]+lds[1][cl][1]+lds[2][cl][1]+lds[3][cl][1];
    float m = s/(float)NG;
    float v = q/(float)NG - m*m;
    mstat3[br*1024 + c] = m;
    mstat3[br*1024 + 512 + c] = rsqrtf(v + 1e-5f);
  }
}

__global__ void bncast3(const float* __restrict__ gc, const float* __restrict__ go,
                        const int* __restrict__ perm, const float* __restrict__ mstat3,
                        unsigned short* __restrict__ out){
  int idx = blockIdx.x*blockDim.x + threadIdx.x;
  if (idx >= 1536*128) return;
  int r = idx >> 7;
  int cg = idx & 127;
  int br = r >> 9, lr = r & 511;
  ushort4v o;
  if (lr >= NG){ o[0]=0; o[1]=0; o[2]=0; o[3]=0; }
  else {
    float4 v;
    if (br == 0)      v = *(const float4*)&gc[(size_t)lr*HID + cg*4];
    else if (br == 1) v = *(const float4*)&go[(size_t)lr*HID + cg*4];
    else {
      int ps = perm[lr];
      float4 a = *(const float4*)&gc[(size_t)ps*HID + cg*4];
      float4 b = *(const float4*)&go[(size_t)lr*HID + cg*4];
      v = make_float4(a.x+b.x, a.y+b.y, a.z+b.z, a.w+b.w);
    }
    const float* ms = mstat3 + br*1024;
    int c = cg*4;
    o[0] = f2bf((v.x - ms[c+0])*ms[512+c+0] + 1e-4f);
    o[1] = f2bf((v.y - ms[c+1])*ms[512+c+1] + 1e-4f);
    o[2] = f2bf((v.z - ms[c+2])*ms[512+c+2] + 1e-4f);
    o[3] = f2bf((v.w - ms[c+3])*ms[512+c+3] + 1e-4f);
  }
  *(ushort4v*)&out[(size_t)r*HID + cg*4] = o;
}

// ---------------- final: batched BN2 -> fc2 -> log_softmax ----------------
struct ROP { const float* W2[3]; const float* b2[3]; };
__global__ void readout_final3(const unsigned short* __restrict__ T, const float* __restrict__ statsB,
                               float invM, ROP p, float* __restrict__ out){
  int g = blockIdx.x;
  int br = blockIdx.y;
  int l = threadIdx.x;
  const float* stats = statsB + br*1024;
  const float* W2 = p.W2[br];
  const float* b2 = p.b2[br];
  float acc[NCLS];
#pragma unroll
  for (int c=0; c<NCLS; ++c) acc[c] = 0.f;
  uint4 u = ((const uint4*)(T + (size_t)(br*512 + g)*HID))[l];
  float xv[8] = {bf2f(u.x&0xffffu), bf2f(u.x>>16), bf2f(u.y&0xffffu), bf2f(u.y>>16),
                 bf2f(u.z&0xffffu), bf2f(u.z>>16), bf2f(u.w&0xffffu), bf2f(u.w>>16)};
#pragma unroll
  for (int j=0; j<8; ++j){
    int k = l*8 + j;
    float m = stats[k]*invM;
    float rs = rsqrtf(stats[512+k]*invM - m*m + 1e-5f);
    float v = (xv[j] - m)*rs + 1e-4f;
#pragma unroll
    for (int c=0; c<NCLS; ++c) acc[c] += v * W2[k*NCLS + c];
  }
  for (int m=1; m<64; m<<=1){
#pragma unroll
    for (int c=0; c<NCLS; ++c) acc[c] += __shfl_xor(acc[c], m);
  }
  if (l == 0){
    float z[NCLS];
    float mx = -1e30f;
#pragma unroll
    for (int c=0; c<NCLS; ++c){ z[c] = acc[c] + b2[c]; mx = fmaxf(mx, z[c]); }
    float s = 0.f;
#pragma unroll
    for (int c=0; c<NCLS; ++c) s += expf(z[c]-mx);
    float lse = mx + logf(s);
#pragma unroll
    for (int c=0; c<NCLS; ++c) out[(size_t)(br*NG + g)*NCLS + c] = z[c] - lse;
  }
}

extern "C" void kernel_launch(void* const* d_in, const int* in_sizes, int n_in,
                              void* d_out, int out_size, void* d_ws, size_t ws_size,
                              hipStream_t stream){
  (void)in_sizes; (void)n_in; (void)out_size;
  const float* x      = (const float*)d_in[0];
  const int*   ei     = (const int*)d_in[1];
  const int*   batch  = (const int*)d_in[2];
  const int*   perm   = (const int*)d_in[3];
  const float* convfW = (const float*)d_in[4];
  const float* convfB = (const float*)d_in[5];
  const float* convsW = (const float*)d_in[6];
  const float* convsB = (const float*)d_in[7];
  const float* eattW  = (const float*)d_in[8];
  const float* eattB  = (const float*)d_in[9];
  const float* nattW  = (const float*)d_in[10];
  const float* nattB  = (const float*)d_in[11];
  const float* ctxW   = (const float*)d_in[12];
  const float* ctxB   = (const float*)d_in[13];
  const float* objW   = (const float*)d_in[14];
  const float* objB   = (const float*)d_in[15];
  const float* fc1W[3] = {(const float*)d_in[16], (const float*)d_in[20], (const float*)d_in[24]};
  const float* fc1B[3] = {(const float*)d_in[17], (const float*)d_in[21], (const float*)d_in[25]};
  const float* fc2W[3] = {(const float*)d_in[18], (const float*)d_in[22], (const float*)d_in[26]};
  const float* fc2B[3] = {(const float*)d_in[19], (const float*)d_in[23], (const float*)d_in[27]};
  float* out = (float*)d_out;

  char* p = (char*)d_ws;
  auto alloc = [&](size_t bytes)->char*{ char* r = p; p += (bytes + 255) & ~((size_t)255); return r; };
  const int T = NE + NN;
  unsigned short* Xbf = (unsigned short*)alloc((size_t)NN*HID*2);
  unsigned short* Gbf = (unsigned short*)alloc((size_t)NN*HID*2);
  unsigned short* GbfO= (unsigned short*)alloc((size_t)NN*HID*2);
  unsigned short* XbfO= (unsigned short*)alloc((size_t)NN*HID*2);
  unsigned short* Abf = (unsigned short*)alloc((size_t)NN*FIN*2);
  unsigned short* WtF = (unsigned short*)alloc((size_t)HID*FIN*2);
  unsigned short* WtL = (unsigned short*)alloc((size_t)3*HID*HID*2);
  unsigned short* WtC = (unsigned short*)alloc((size_t)HID*HID*2);
  unsigned short* WtO = (unsigned short*)alloc((size_t)HID*HID*2);
  unsigned short* WtR = (unsigned short*)alloc((size_t)3*HID*HID*2);
  int* cnt   = (int*)alloc((size_t)NN*4);
  int* fillc = (int*)alloc((size_t)NN*4);
  int* rowp  = (int*)alloc((size_t)(NN+1)*4);
  int* bsum  = (int*)alloc(32*4);
  int* ccol  = (int*)alloc((size_t)T*4);
  int* crow  = (int*)alloc((size_t)T*4);
  int* ceid  = (int*)alloc((size_t)T*4);
  int2* cw1  = (int2*)alloc((size_t)T*8);
  float* wcv = (float*)alloc((size_t)T*4);
  float* wov = (float*)alloc((size_t)T*4);
  float* dis1 = (float*)alloc((size_t)NN*4);
  float* degc = (float*)alloc((size_t)NN*4);
  float* dego = (float*)alloc((size_t)NN*4);
  float* Sc   = (float*)alloc((size_t)NN*4);
  float* So   = (float*)alloc((size_t)NN*4);
  float* stats6 = (float*)alloc(6*1024*4);
  float* mstat  = (float*)alloc(2*HID*4);
  float* mstatCO= (float*)alloc(2*1024*4);
  float* mstat3 = (float*)alloc(3*1024*4);
  float* na   = (float*)alloc((size_t)NN*2*4);
  float* eab  = (float*)alloc((size_t)NN*4*4);
  float* att  = (float*)alloc((size_t)NE*2*4);
  float* gc   = (float*)alloc((size_t)NG*HID*4);
  float* go   = (float*)alloc((size_t)NG*HID*4);
  float* part = (float*)alloc((size_t)BNG*2048*4);
  if ((size_t)(p - (char*)d_ws) > ws_size){
    sentinel_k<<<1,1,0,stream>>>(out);
    return;
  }
  unsigned short* Abf3 = Abf;
  unsigned short* Gbf3 = GbfO;
  const float invNN = 1.0f/(float)NN;
  const float invNG = 1.0f/(float)NG;

  // setup
  W2BT wp;
  wp.src[0]=convfW; wp.dst[0]=WtF;
  for (int i=0;i<3;i++){ wp.src[1+i]=convsW+(size_t)i*HID*HID; wp.dst[1+i]=WtL+(size_t)i*HID*HID; }
  wp.src[4]=ctxW; wp.dst[4]=WtC;
  wp.src[5]=objW; wp.dst[5]=WtO;
  for (int i=0;i<3;i++){ wp.src[6+i]=fc1W[i]; wp.dst[6+i]=WtR+(size_t)i*HID*HID; }
  setup_all<<<(FIN*HID + 8*HID*HID + 255)/256, 256, 0, stream>>>(wp, cnt, fillc, degc, dego, Sc, So, stats6);

  // CSR build
  csr_count<<<(NE+255)/256,256,0,stream>>>(ei, cnt);
  scan1<<<(NN+1023)/1024,1024,0,stream>>>(cnt, rowp, dis1, bsum);
  scan3<<<(NN+1023)/1024,1024,0,stream>>>(rowp, bsum);
  csr_fill<<<(T+255)/256,256,0,stream>>>(ei, rowp, cnt, fillc, dis1, ccol, crow, ceid, cw1);

  // conv_feat
  bnstats_p<<<BNG,1024,0,stream>>>(x, NN, FIN, part);
  bnfin_red<<<(FIN+63)/64,256,0,stream>>>(part, 2*FIN, 0, NN, FIN, mstat);
  bncast<<<((NN*FIN/4)+255)/256,256,0,stream>>>(x, mstat, NN, FIN, Abf);
  gemm_bt<<<dim3((NN+127)/128,4),256,0,stream>>>(Abf, WtF, Xbf, convfB, stats6, NN, FIN, 1,
                                                 0, nullptr, nullptr, nullptr, nullptr);

  // 3 GCN layers
  for (int i=0;i<3;i++){
    aggregate_bn<<<NN/4,256,0,stream>>>(Xbf, rowp, cw1, stats6 + i*1024, invNN, Gbf);
    gemm_bt<<<dim3((NN+127)/128,4),256,0,stream>>>(Gbf, WtL+(size_t)i*HID*HID, Xbf,
                                                   convsB+(size_t)i*HID,
                                                   (i<2) ? (stats6 + (i+1)*1024) : nullptr,
                                                   NN, HID, 1, 0, nullptr, nullptr, nullptr, nullptr);
  }

  // attention
  att_node<<<NN/4,256,0,stream>>>(Xbf, nattW, nattB, eattW, na, eab);
  att_edge<<<(NE+255)/256,256,0,stream>>>(ei, eab, eattB, att, degc, dego);
  wco_kernel<<<(T+255)/256,256,0,stream>>>(crow, ccol, ceid, att, degc, dego, na, wcv, wov, Sc, So);

  // ctx + obj: dual stats -> dual agg -> batched 2-GEMM dispatch -> 1 pool dispatch
  bnstats_dual<<<BNG,1024,0,stream>>>(Xbf, na, part);
  bnfin_red2<<<dim3(8,2),256,0,stream>>>(part, mstatCO);
  aggregate_dual<<<NN/4,256,0,stream>>>(Xbf, rowp, ccol, wcv, wov, Sc, So, mstatCO, Gbf, GbfO);
  {
    const int gx = (NN+127)/128;
    gemm_bt<<<dim3(2*gx,4),256,0,stream>>>(Gbf, WtC, Xbf, ctxB, nullptr, NN, HID, 1,
                                           gx, GbfO, WtO, XbfO, objB);
  }
  pool2<<<dim3(NG,2),256,0,stream>>>(Xbf, XbfO, batch, gc, go);

  // readouts, batched across the 3 branches
  bnstats3<<<dim3(NB3,3),256,0,stream>>>(gc, go, perm, part);
  bnfin3<<<dim3(8,3),256,0,stream>>>(part, mstat3);
  bncast3<<<(1536*128+255)/256,256,0,stream>>>(gc, go, perm, mstat3, Abf3);
  FC1P fp;
  for (int i=0;i<3;i++){ fp.Bt[i] = WtR+(size_t)i*HID*HID; fp.bias[i] = fc1B[i]; }
  gemm_fc1<<<dim3(12,4),256,0,stream>>>(Abf3, fp, Gbf3, stats6 + 3*1024);
  ROP rp;
  for (int i=0;i<3;i++){ rp.W2[i] = fc2W[i]; rp.b2[i] = fc2B[i]; }
  readout_final3<<<dim3(NG,3),64,0,stream>>>(Gbf3, stats6 + 3*1024, invNG, rp, out);
}

// Round 7
// 442.611 us; speedup vs baseline: 2.3206x; 1.0768x over previous
//
#include <hip/hip_runtime.h>
#include <stdint.h>

#define NN 20000
#define NE 160000
#define NG 500
#define FIN 128
#define HID 512
#define NCLS 10
#define BNG 256
#define NB3 32

typedef __attribute__((ext_vector_type(8))) short short8;
typedef __attribute__((ext_vector_type(4))) float f32x4;
typedef __attribute__((ext_vector_type(4))) unsigned short ushort4v;

__device__ __forceinline__ float bf2f(unsigned int u){
  union{unsigned int i; float f;} x; x.i = u<<16; return x.f;
}
__device__ __forceinline__ unsigned short f2bf(float f){
  union{float f; unsigned int i;} x; x.f=f;
  unsigned int r = x.i + 0x7fffu + ((x.i>>16)&1u);
  return (unsigned short)(r>>16);
}
__device__ __forceinline__ unsigned int pk2(float a, float b){
  return (unsigned int)f2bf(a) | ((unsigned int)f2bf(b) << 16);
}

__device__ __forceinline__ void gload16(unsigned short* lds, const unsigned short* g){
  __builtin_amdgcn_global_load_lds((const __attribute__((address_space(1))) unsigned int*)g,
                                   (__attribute__((address_space(3))) unsigned int*)lds,
                                   16, 0, 0);
}

__device__ __forceinline__ void fma8(float* acc, uint4 v, float w){
  acc[0] += w*bf2f(v.x & 0xffffu); acc[1] += w*bf2f(v.x >> 16);
  acc[2] += w*bf2f(v.y & 0xffffu); acc[3] += w*bf2f(v.y >> 16);
  acc[4] += w*bf2f(v.z & 0xffffu); acc[5] += w*bf2f(v.z >> 16);
  acc[6] += w*bf2f(v.w & 0xffffu); acc[7] += w*bf2f(v.w >> 16);
}

__global__ void sentinel_k(float* out){ out[0] = 12345.0f; }

// ---------------- setup: all weight transposes + all init in one dispatch ----------------
struct W2BT { const float* src[9]; unsigned short* dst[9]; };
__global__ void setup_all(W2BT p, int* __restrict__ cnt, int* __restrict__ fillc,
                          float* __restrict__ degc, float* __restrict__ dego,
                          float* __restrict__ Sc, float* __restrict__ So,
                          float* __restrict__ stats6){
  int idx = blockIdx.x*blockDim.x + threadIdx.x;
  if (idx < FIN*HID + 8*HID*HID){
    int seg, off, K;
    if (idx < FIN*HID){ seg = 0; off = idx; K = FIN; }
    else {
      int r = idx - FIN*HID;
      seg = 1 + (r >> 18); off = r & (HID*HID-1); K = HID;
    }
    int k = off >> 9, n = off & 511;
    p.dst[seg][(size_t)n*K + k] = f2bf(p.src[seg][off]);
  }
  if (idx < NN){ cnt[idx]=0; fillc[idx]=0; degc[idx]=1.0f; dego[idx]=1.0f; Sc[idx]=0.f; So[idx]=0.f; }
  if (idx < 6*1024) stats6[idx] = 0.f;
}

// ---------------- BN stats stage 1 (f32 input; conv input only) ----------------
__global__ __launch_bounds__(1024) void bnstats_p(const float* __restrict__ X, int M, int F,
                                                  float* __restrict__ partials){
  __shared__ float lds[1024*9];
  const int t = threadIdx.x;
  const int cg = F >> 2;
  const int cid = t & (cg-1);
  const int rid = t / cg;
  const int rpb = 1024 / cg;
  float s0=0,s1=0,s2=0,s3=0,q0=0,q1=0,q2=0,q3=0;
  const int rowsPer = (M + BNG - 1)/BNG;
  int r0 = blockIdx.x*rowsPer, r1 = r0 + rowsPer; if (r1 > M) r1 = M;
  for (int r = r0 + rid; r < r1; r += rpb){
    float4 v = *(const float4*)&X[(size_t)r*F + cid*4];
    s0+=v.x; q0+=v.x*v.x; s1+=v.y; q1+=v.y*v.y; s2+=v.z; q2+=v.z*v.z; s3+=v.w; q3+=v.w*v.w;
  }
  int base = (rid*cg + cid)*9;
  lds[base+0]=s0; lds[base+1]=s1; lds[base+2]=s2; lds[base+3]=s3;
  lds[base+4]=q0; lds[base+5]=q1; lds[base+6]=q2; lds[base+7]=q3;
  __syncthreads();
  if (t < cg*8){
    int ci = t >> 3, i = t & 7;
    float acc = 0.f;
    for (int g=0; g<rpb; ++g) acc += lds[(g*cg + ci)*9 + i];
    int col = ci*4 + (i & 3);
    partials[(size_t)blockIdx.x*(2*F) + ((i < 4) ? col : F + col)] = acc;
  }
}

// ---------------- dual BN stats on bf16 X ----------------
__global__ __launch_bounds__(1024) void bnstats_dual(const unsigned short* __restrict__ X,
                                                     const float* __restrict__ na,
                                                     float* __restrict__ partials){
  __shared__ float lds[1024*17];
  const int t = threadIdx.x;
  const int cid = t & 127;
  const int rid = t >> 7;
  float sC[4]={0,0,0,0}, qC[4]={0,0,0,0}, sO[4]={0,0,0,0}, qO[4]={0,0,0,0};
  const int rowsPer = (NN + BNG - 1)/BNG;
  int r0 = blockIdx.x*rowsPer, r1 = r0 + rowsPer; if (r1 > NN) r1 = NN;
  for (int r = r0 + rid; r < r1; r += 8){
    float a0 = na[2*r], a1 = na[2*r+1];
    uint2 u = *(const uint2*)&X[(size_t)r*HID + cid*4];
    float e[4] = {bf2f(u.x & 0xffffu), bf2f(u.x >> 16), bf2f(u.y & 0xffffu), bf2f(u.y >> 16)};
#pragma unroll
    for (int i=0;i<4;i++){
      float vc = e[i]*a0, vo = e[i]*a1;
      sC[i]+=vc; qC[i]+=vc*vc; sO[i]+=vo; qO[i]+=vo*vo;
    }
  }
  int base = (rid*128 + cid)*17;
#pragma unroll
  for (int i=0;i<4;i++){
    lds[base+i]=sC[i]; lds[base+4+i]=qC[i]; lds[base+8+i]=sO[i]; lds[base+12+i]=qO[i];
  }
  __syncthreads();
  for (int idx = t; idx < 2048; idx += 1024){
    int ci = idx >> 4, i = idx & 15;
    float acc = 0.f;
    for (int g=0; g<8; ++g) acc += lds[(g*128 + ci)*17 + i];
    int grp = i >> 2, col = ci*4 + (i & 3);
    partials[(size_t)blockIdx.x*2048 + grp*HID + col] = acc;
  }
}

// ---------------- reduce partials -> mean/rstd ----------------
__global__ void bnfin_red(const float* __restrict__ partials, int stride, int off,
                          int M, int F, float* __restrict__ mstat){
  __shared__ float lds[4][64][2];
  int t = threadIdx.x;
  int cl = t & 63, ch = t >> 6;
  int c = blockIdx.x*64 + cl;
  float s = 0.f, q = 0.f;
  if (c < F){
    for (int b = ch*64; b < ch*64 + 64; ++b){
      s += partials[(size_t)b*stride + off + c];
      q += partials[(size_t)b*stride + off + F + c];
    }
  }
  lds[ch][cl][0] = s; lds[ch][cl][1] = q;
  __syncthreads();
  if (ch == 0 && c < F){
    s = lds[0][cl][0]+lds[1][cl][0]+lds[2][cl][0]+lds[3][cl][0];
    q = lds[0][cl][1]+lds[1][cl][1]+lds[2][cl][1]+lds[3][cl][1];
    float m = s/(float)M;
    float v = q/(float)M - m*m;
    mstat[c] = m;
    mstat[F+c] = rsqrtf(v + 1e-5f);
  }
}

__global__ void bnfin_red2(const float* __restrict__ partials, float* __restrict__ mstatCO){
  __shared__ float lds[4][64][2];
  int t = threadIdx.x;
  int cl = t & 63, ch = t >> 6;
  int c = blockIdx.x*64 + cl;
  int off = blockIdx.y*1024;
  float s = 0.f, q = 0.f;
  for (int b = ch*64; b < ch*64 + 64; ++b){
    s += partials[(size_t)b*2048 + off + c];
    q += partials[(size_t)b*2048 + off + HID + c];
  }
  lds[ch][cl][0] = s; lds[ch][cl][1] = q;
  __syncthreads();
  if (ch == 0){
    s = lds[0][cl][0]+lds[1][cl][0]+lds[2][cl][0]+lds[3][cl][0];
    q = lds[0][cl][1]+lds[1][cl][1]+lds[2][cl][1]+lds[3][cl][1];
    float m = s/(float)NN;
    float v = q/(float)NN - m*m;
    mstatCO[blockIdx.y*1024 + c] = m;
    mstatCO[blockIdx.y*1024 + HID + c] = rsqrtf(v + 1e-5f);
  }
}

// ---------------- BN->bf16 cast (f32 input; conv input only) ----------------
__global__ void bncast(const float* __restrict__ X, const float* __restrict__ mstat,
                       int M, int F, unsigned short* __restrict__ out){
  int idx = blockIdx.x*blockDim.x + threadIdx.x;
  int total4 = M*F/4;
  if (idx >= total4) return;
  int base = idx*4;
  int c = base & (F-1);
  float4 v = *(const float4*)&X[base];
  ushort4v o;
  o[0] = f2bf((v.x - mstat[c+0])*mstat[F+c+0] + 1e-4f);
  o[1] = f2bf((v.y - mstat[c+1])*mstat[F+c+1] + 1e-4f);
  o[2] = f2bf((v.z - mstat[c+2])*mstat[F+c+2] + 1e-4f);
  o[3] = f2bf((v.w - mstat[c+3])*mstat[F+c+3] + 1e-4f);
  *(ushort4v*)&out[base] = o;
}

// ---------------- CSR build ----------------
__global__ void csr_count(const int* __restrict__ ei, int* __restrict__ cnt){
  int e = blockIdx.x*blockDim.x + threadIdx.x;
  if (e < NE) atomicAdd(&cnt[ei[e]], 1);
}

__global__ __launch_bounds__(1024) void scan1(const int* __restrict__ cnt, int* __restrict__ rowp,
                                              float* __restrict__ dis1, int* __restrict__ bsum){
  __shared__ int buf[1024];
  int t = threadIdx.x;
  int i = blockIdx.x*1024 + t;
  int v = 0;
  if (i < NN){ v = cnt[i] + 1; dis1[i] = rsqrtf((float)v); }
  buf[t] = v;
  __syncthreads();
  for (int off=1; off<1024; off<<=1){
    int xv = (t >= off) ? buf[t-off] : 0;
    __syncthreads();
    buf[t] += xv;
    __syncthreads();
  }
  if (i < NN) rowp[i+1] = buf[t];
  if (t == 1023) bsum[blockIdx.x] = buf[1023];
}

__global__ __launch_bounds__(1024) void scan3(int* __restrict__ rowp, const int* __restrict__ bsum){
  __shared__ int base;
  int bx = blockIdx.x;
  if (threadIdx.x == 0){
    int a = 0;
    for (int b=0; b<bx; ++b) a += bsum[b];
    base = a;
  }
  __syncthreads();
  int i = bx*1024 + threadIdx.x;
  if (i < NN) rowp[i+1] += base;
  if (i == 0) rowp[0] = 0;
}

// csr_fill + w1 fused; also builds interleaved {col, w1} pairs
__global__ void csr_fill(const int* __restrict__ ei, const int* __restrict__ rowp,
                         const int* __restrict__ cnt, int* __restrict__ fillc,
                         const float* __restrict__ dis1,
                         int* __restrict__ ccol, int* __restrict__ crow, int* __restrict__ ceid,
                         int2* __restrict__ cw1){
  int id = blockIdx.x*blockDim.x + threadIdx.x;
  if (id < NE){
    int r = ei[id], c = ei[NE + id];
    int pos = atomicAdd(&fillc[r], 1);
    int idx = rowp[r] + pos;
    ccol[idx] = c; crow[idx] = r; ceid[idx] = id;
    cw1[idx] = make_int2(c, __float_as_int(dis1[r]*dis1[c]));
  } else if (id < NE + NN){
    int i = id - NE;
    int idx = rowp[i] + cnt[i];
    ccol[idx] = i; crow[idx] = i; ceid[idx] = -1;
    cw1[idx] = make_int2(i, __float_as_int(dis1[i]*dis1[i]));
  }
}

// ---------------- attention (bf16 X), weights staged in LDS ----------------
__global__ void att_node(const unsigned short* __restrict__ X, const float* __restrict__ nW,
                         const float* __restrict__ nb, const float* __restrict__ eW,
                         float* __restrict__ na, float* __restrict__ eab){
  __shared__ float wnl[1024], wet[1024], web[1024];
  int t = threadIdx.x;
  for (int i=t; i<1024; i+=256){ wnl[i]=nW[i]; wet[i]=eW[i]; web[i]=eW[1024+i]; }
  __syncthreads();
  int wv = blockIdx.x*4 + (t >> 6);
  int l = t & 63;
  uint4 u = ((const uint4*)(X + (size_t)wv*HID))[l];
  float xv[8] = {bf2f(u.x&0xffffu), bf2f(u.x>>16), bf2f(u.y&0xffffu), bf2f(u.y>>16),
                 bf2f(u.z&0xffffu), bf2f(u.z>>16), bf2f(u.w&0xffffu), bf2f(u.w>>16)};
  float s0=0,s1=0,s2=0,s3=0,s4=0,s5=0;
#pragma unroll
  for (int j=0; j<8; ++j){
    int k = l*8 + j;
    float x = xv[j];
    s0 += x * wnl[2*k];   s1 += x * wnl[2*k+1];
    s2 += x * wet[2*k];   s3 += x * wet[2*k+1];
    s4 += x * web[2*k];   s5 += x * web[2*k+1];
  }
  for (int m=1; m<64; m<<=1){
    s0 += __shfl_xor(s0,m); s1 += __shfl_xor(s1,m); s2 += __shfl_xor(s2,m);
    s3 += __shfl_xor(s3,m); s4 += __shfl_xor(s4,m); s5 += __shfl_xor(s5,m);
  }
  if (l == 0){
    float z0 = s0 + nb[0], z1 = s1 + nb[1];
    float mx = fmaxf(z0,z1);
    float e0 = expf(z0-mx), e1 = expf(z1-mx);
    float inv = 1.0f/(e0+e1);
    na[2*wv] = e0*inv; na[2*wv+1] = e1*inv;
    eab[4*wv] = s2; eab[4*wv+1] = s3; eab[4*wv+2] = s4; eab[4*wv+3] = s5;
  }
}

__global__ void att_edge(const int* __restrict__ ei, const float* __restrict__ eab,
                         const float* __restrict__ eb, float* __restrict__ att,
                         float* __restrict__ degc, float* __restrict__ dego){
  int e = blockIdx.x*blockDim.x + threadIdx.x;
  if (e >= NE) return;
  int r = ei[e], c = ei[NE+e];
  float z0 = eab[4*r]   + eab[4*c+2] + eb[0];
  float z1 = eab[4*r+1] + eab[4*c+3] + eb[1];
  float mx = fmaxf(z0,z1);
  float e0 = expf(z0-mx), e1 = expf(z1-mx);
  float inv = 1.0f/(e0+e1);
  float a0 = e0*inv, a1 = e1*inv;
  att[2*e] = a0; att[2*e+1] = a1;
  atomicAdd(&degc[r], a0);
  atomicAdd(&dego[r], a1);
}

__global__ void wco_kernel(const int* __restrict__ crow, const int* __restrict__ ccol,
                           const int* __restrict__ ceid, const float* __restrict__ att,
                           const float* __restrict__ degc, const float* __restrict__ dego,
                           const float* __restrict__ na,
                           float* __restrict__ wcv, float* __restrict__ wov,
                           float* __restrict__ Sc, float* __restrict__ So){
  int j = blockIdx.x*blockDim.x + threadIdx.x;
  if (j >= NE + NN) return;
  int r = crow[j], c = ccol[j], e = ceid[j];
  float a0 = (e < 0) ? 1.0f : att[2*e];
  float a1 = (e < 0) ? 1.0f : att[2*e+1];
  float wc = rsqrtf(degc[r]) * a0 * rsqrtf(degc[c]);
  float wo = rsqrtf(dego[r]) * a1 * rsqrtf(dego[c]);
  wcv[j] = wc * na[2*c];
  wov[j] = wo * na[2*c+1];
  atomicAdd(&Sc[r], wc);
  atomicAdd(&So[r], wo);
}

// ---------------- wave-per-row aggregation (int2 pairs), 4-deep, BN affine epilogue ----------------
__global__ __launch_bounds__(256) void aggregate_bn(const unsigned short* __restrict__ A,
                                                    const int* __restrict__ rowp,
                                                    const int2* __restrict__ cw,
                                                    const float* __restrict__ stats,
                                                    float invM,
                                                    unsigned short* __restrict__ out){
  int row = blockIdx.x*4 + (threadIdx.x >> 6);
  int l = threadIdx.x & 63;
  const uint4* Av = (const uint4*)A;
  int s = rowp[row], e = rowp[row+1];
  float acc[8] = {0,0,0,0,0,0,0,0};
  float sw = 0.f;
  int j = s;
  for (; j+3 < e; j += 4){
    int2 p0 = cw[j], p1 = cw[j+1], p2 = cw[j+2], p3 = cw[j+3];
    float w0 = __int_as_float(p0.y), w1 = __int_as_float(p1.y);
    float w2 = __int_as_float(p2.y), w3 = __int_as_float(p3.y);
    uint4 v0 = Av[(size_t)p0.x*64 + l];
    uint4 v1 = Av[(size_t)p1.x*64 + l];
    uint4 v2 = Av[(size_t)p2.x*64 + l];
    uint4 v3 = Av[(size_t)p3.x*64 + l];
    fma8(acc, v0, w0); fma8(acc, v1, w1); fma8(acc, v2, w2); fma8(acc, v3, w3);
    sw += w0 + w1 + w2 + w3;
  }
  for (; j < e; ++j){
    int2 p = cw[j];
    float w = __int_as_float(p.y);
    uint4 v = Av[(size_t)p.x*64 + l];
    fma8(acc, v, w);
    sw += w;
  }
  float g[8];
#pragma unroll
  for (int i=0;i<8;i++){
    int c = l*8 + i;
    float m = stats[c]*invM;
    float rs = rsqrtf(stats[512+c]*invM - m*m + 1e-5f);
    g[i] = rs*acc[i] + sw*(1e-4f - m*rs);
  }
  uint4 o;
  o.x = pk2(g[0],g[1]); o.y = pk2(g[2],g[3]); o.z = pk2(g[4],g[5]); o.w = pk2(g[6],g[7]);
  ((uint4*)out)[(size_t)row*64 + l] = o;
}

__global__ __launch_bounds__(256) void aggregate_dual(const unsigned short* __restrict__ A,
                                                      const int* __restrict__ rowp,
                                                      const int* __restrict__ ccol,
                                                      const float* __restrict__ wc,
                                                      const float* __restrict__ wo,
                                                      const float* __restrict__ Sc,
                                                      const float* __restrict__ So,
                                                      const float* __restrict__ mstatCO,
                                                      unsigned short* __restrict__ outC,
                                                      unsigned short* __restrict__ outO){
  int row = blockIdx.x*4 + (threadIdx.x >> 6);
  int l = threadIdx.x & 63;
  const uint4* Av = (const uint4*)A;
  int s = rowp[row], e = rowp[row+1];
  float aC[8] = {0,0,0,0,0,0,0,0};
  float aO[8] = {0,0,0,0,0,0,0,0};
  int j = s;
  for (; j+3 < e; j += 4){
    int c0 = ccol[j], c1 = ccol[j+1], c2 = ccol[j+2], c3 = ccol[j+3];
    float wc0=wc[j], wc1=wc[j+1], wc2=wc[j+2], wc3=wc[j+3];
    float wo0=wo[j], wo1=wo[j+1], wo2=wo[j+2], wo3=wo[j+3];
    uint4 v0 = Av[(size_t)c0*64 + l];
    uint4 v1 = Av[(size_t)c1*64 + l];
    uint4 v2 = Av[(size_t)c2*64 + l];
    uint4 v3 = Av[(size_t)c3*64 + l];
    fma8(aC, v0, wc0); fma8(aO, v0, wo0);
    fma8(aC, v1, wc1); fma8(aO, v1, wo1);
    fma8(aC, v2, wc2); fma8(aO, v2, wo2);
    fma8(aC, v3, wc3); fma8(aO, v3, wo3);
  }
  for (; j < e; ++j){
    uint4 v = Av[(size_t)ccol[j]*64 + l];
    fma8(aC, v, wc[j]); fma8(aO, v, wo[j]);
  }
  float ScR = Sc[row], SoR = So[row];
  float gC[8], gO[8];
#pragma unroll
  for (int i=0;i<8;i++){
    int c = l*8 + i;
    float mc = mstatCO[c],      rc = mstatCO[512+c];
    float mo = mstatCO[1024+c], ro = mstatCO[1536+c];
    gC[i] = rc*aC[i] + ScR*(1e-4f - mc*rc);
    gO[i] = ro*aO[i] + SoR*(1e-4f - mo*ro);
  }
  uint4 oc, oo;
  oc.x = pk2(gC[0],gC[1]); oc.y = pk2(gC[2],gC[3]); oc.z = pk2(gC[4],gC[5]); oc.w = pk2(gC[6],gC[7]);
  oo.x = pk2(gO[0],gO[1]); oo.y = pk2(gO[2],gO[3]); oo.z = pk2(gO[4],gO[5]); oo.w = pk2(gO[6],gO[7]);
  ((uint4*)outC)[(size_t)row*64 + l] = oc;
  ((uint4*)outO)[(size_t)row*64 + l] = oo;
}

// ---------------- bf16 MFMA GEMM: 1D XCD-chunked grid, dbuf+counted-vmcnt, LDS-staged C ----------------
// grid = (#mstrips*4) per problem (×2 if split). smem: As/Bs dbuf (32KB) aliased with Cs (34.8KB).
__global__ __launch_bounds__(256) void gemm_bt(const unsigned short* __restrict__ A,
                                               const unsigned short* __restrict__ Bt,
                                               unsigned short* __restrict__ O,
                                               const float* __restrict__ bias,
                                               float* __restrict__ stats,
                                               int M, int K, int relu, int split,
                                               const unsigned short* A2,
                                               const unsigned short* Bt2,
                                               unsigned short* O2,
                                               const float* bias2){
  extern __shared__ unsigned short smem[];
  unsigned short* As0 = smem;            // [2][4096]
  unsigned short* Bs0 = smem + 8192;     // [2][4096]
  unsigned short* Cs  = smem;            // [128][136] (reused after k-loop)
  const int tid = threadIdx.x;
  const int w = tid >> 6, l = tid & 63;

  // bijective XCD-chunked swizzle (m204)
  int lin = blockIdx.x;
  int total = gridDim.x;
  int q = total >> 3, r = total & 7;
  int xcd = lin & 7, idx = lin >> 3;
  int swz = (xcd < r ? xcd*(q+1) : r*(q+1) + (xcd - r)*q) + idx;
  if (split && swz >= split){ A = A2; Bt = Bt2; O = O2; bias = bias2; swz -= split; }
  const int m0 = (swz >> 2)*128, n0 = (swz & 3)*128;

  const int wm = w >> 1, wn = w & 1;
  const int lr = l & 15, lh = l >> 4;

  f32x4 acc[4][4];
#pragma unroll
  for (int i=0;i<4;i++)
#pragma unroll
    for (int j=0;j<4;j++) acc[i][j] = 0.0f;

  const int q0 = w*2, q1 = w*2+1;
  const int sub = l >> 2;
  const int kc  = (l & 3)*8;
  int ma0 = m0 + q0*16 + sub; if (ma0 >= M) ma0 = M-1;
  int ma1 = m0 + q1*16 + sub; if (ma1 >= M) ma1 = M-1;
  const int nb0 = n0 + q0*16 + sub;
  const int nb1 = n0 + q1*16 + sub;
  const unsigned short* Ar0 = A + (size_t)ma0*K + kc;
  const unsigned short* Ar1 = A + (size_t)ma1*K + kc;
  const unsigned short* Br0 = Bt + (size_t)nb0*K + kc;
  const unsigned short* Br1 = Bt + (size_t)nb1*K + kc;

  const int NT = K >> 5;
  gload16(&As0[q0*512], Ar0);
  gload16(&As0[q1*512], Ar1);
  gload16(&Bs0[q0*512], Br0);
  gload16(&Bs0[q1*512], Br1);
  int cur = 0;
  for (int t=0; t<NT; ++t){
    if (t+1 < NT){
      int k1 = (t+1) << 5;
      gload16(&As0[(cur^1)*4096 + q0*512], Ar0 + k1);
      gload16(&As0[(cur^1)*4096 + q1*512], Ar1 + k1);
      gload16(&Bs0[(cur^1)*4096 + q0*512], Br0 + k1);
      gload16(&Bs0[(cur^1)*4096 + q1*512], Br1 + k1);
      asm volatile("s_waitcnt vmcnt(4)" ::: "memory");
    } else {
      asm volatile("s_waitcnt vmcnt(0)" ::: "memory");
    }
    __builtin_amdgcn_s_barrier();
    asm volatile("" ::: "memory");
    short8 af[4], bfr[4];
#pragma unroll
    for (int fm=0; fm<4; ++fm) af[fm]  = *(const short8*)&As0[cur*4096 + (wm*64 + fm*16 + lr)*32 + lh*8];
#pragma unroll
    for (int fn=0; fn<4; ++fn) bfr[fn] = *(const short8*)&Bs0[cur*4096 + (wn*64 + fn*16 + lr)*32 + lh*8];
#pragma unroll
    for (int fm=0; fm<4; ++fm)
#pragma unroll
      for (int fn=0; fn<4; ++fn)
        acc[fm][fn] = __builtin_amdgcn_mfma_f32_16x16x32_bf16(af[fm], bfr[fn], acc[fm][fn], 0, 0, 0);
    asm volatile("" ::: "memory");
    __builtin_amdgcn_s_barrier();
    asm volatile("" ::: "memory");
    cur ^= 1;
  }
  // epilogue: bias+relu -> Cs (padded 136) -> coalesced global stores
  float bv[4], cs[4]={0,0,0,0}, cq[4]={0,0,0,0};
  int col[4];
#pragma unroll
  for (int fn=0; fn<4; ++fn){ col[fn] = n0 + wn*64 + fn*16 + lr; bv[fn] = bias[col[fn]]; }
#pragma unroll
  for (int fm=0; fm<4; ++fm){
#pragma unroll
    for (int j=0; j<4; ++j){
      int trow = wm*64 + fm*16 + lh*4 + j;
      bool valid = (m0 + trow) < M;
#pragma unroll
      for (int fn=0; fn<4; ++fn){
        float v = acc[fm][fn][j] + bv[fn];
        if (relu) v = fmaxf(v, 0.f);
        Cs[trow*136 + wn*64 + fn*16 + lr] = f2bf(v);
        if (valid){ cs[fn] += v; cq[fn] += v*v; }
      }
    }
  }
  __syncthreads();
#pragma unroll
  for (int i=0;i<8;i++){
    int trow = i*16 + (tid>>4);
    int colb = (tid&15)*8;
    uint4 vv = *(const uint4*)&Cs[trow*136 + colb];
    int grow = m0 + trow;
    if (grow < M) *(uint4*)&O[(size_t)grow*HID + n0 + colb] = vv;
  }
  if (stats){
#pragma unroll
    for (int m=16; m<64; m<<=1){
#pragma unroll
      for (int fn=0; fn<4; ++fn){ cs[fn] += __shfl_xor(cs[fn], m); cq[fn] += __shfl_xor(cq[fn], m); }
    }
    if (lh == 0){
#pragma unroll
      for (int fn=0; fn<4; ++fn){
        atomicAdd(&stats[col[fn]], cs[fn]);
        atomicAdd(&stats[512+col[fn]], cq[fn]);
      }
    }
  }
}

// batched fc1 gemm: M=1536 (3 branches x 512 rows), branch-indexed weights (small; unchanged path)
struct FC1P { const unsigned short* Bt[3]; const float* bias[3]; };
__global__ __launch_bounds__(256) void gemm_fc1(const unsigned short* __restrict__ A, FC1P p,
                                                unsigned short* __restrict__ O,
                                                float* __restrict__ statsB){
  __shared__ unsigned short As[2][128*32];
  __shared__ unsigned short Bs[2][128*32];
  const int tid = threadIdx.x;
  const int w = tid >> 6, l = tid & 63;
  const int m0 = blockIdx.x*128, n0 = blockIdx.y*128;
  const int branch = blockIdx.x >> 2;
  const unsigned short* Bt = p.Bt[branch];
  const float* bias = p.bias[branch];
  float* stats = statsB + branch*1024;
  const int K = HID;
  const int wm = w >> 1, wn = w & 1;
  const int lr = l & 15, lh = l >> 4;

  f32x4 acc[4][4];
#pragma unroll
  for (int i=0;i<4;i++)
#pragma unroll
    for (int j=0;j<4;j++) acc[i][j] = 0.0f;

  const int q0 = w*2, q1 = w*2+1;
  const int sub = l >> 2;
  const int kc  = (l & 3)*8;
  const int ma0 = m0 + q0*16 + sub;
  const int ma1 = m0 + q1*16 + sub;
  const int nb0 = n0 + q0*16 + sub;
  const int nb1 = n0 + q1*16 + sub;
  const unsigned short* Ar0 = A + (size_t)ma0*K + kc;
  const unsigned short* Ar1 = A + (size_t)ma1*K + kc;
  const unsigned short* Br0 = Bt + (size_t)nb0*K + kc;
  const unsigned short* Br1 = Bt + (size_t)nb1*K + kc;

  const int NT = K >> 5;
  gload16(&As[0][q0*512], Ar0);
  gload16(&As[0][q1*512], Ar1);
  gload16(&Bs[0][q0*512], Br0);
  gload16(&Bs[0][q1*512], Br1);
  int cur = 0;
  for (int t=0; t<NT; ++t){
    if (t+1 < NT){
      int k1 = (t+1) << 5;
      gload16(&As[cur^1][q0*512], Ar0 + k1);
      gload16(&As[cur^1][q1*512], Ar1 + k1);
      gload16(&Bs[cur^1][q0*512], Br0 + k1);
      gload16(&Bs[cur^1][q1*512], Br1 + k1);
      asm volatile("s_waitcnt vmcnt(4)" ::: "memory");
    } else {
      asm volatile("s_waitcnt vmcnt(0)" ::: "memory");
    }
    __builtin_amdgcn_s_barrier();
    asm volatile("" ::: "memory");
    short8 af[4], bfr[4];
#pragma unroll
    for (int fm=0; fm<4; ++fm) af[fm]  = *(const short8*)&As[cur][(wm*64 + fm*16 + lr)*32 + lh*8];
#pragma unroll
    for (int fn=0; fn<4; ++fn) bfr[fn] = *(const short8*)&Bs[cur][(wn*64 + fn*16 + lr)*32 + lh*8];
#pragma unroll
    for (int fm=0; fm<4; ++fm)
#pragma unroll
      for (int fn=0; fn<4; ++fn)
        acc[fm][fn] = __builtin_amdgcn_mfma_f32_16x16x32_bf16(af[fm], bfr[fn], acc[fm][fn], 0, 0, 0);
    asm volatile("" ::: "memory");
    __builtin_amdgcn_s_barrier();
    asm volatile("" ::: "memory");
    cur ^= 1;
  }
  float bv[4], cs[4]={0,0,0,0}, cq[4]={0,0,0,0};
  int col[4];
#pragma unroll
  for (int fn=0; fn<4; ++fn){ col[fn] = n0 + wn*64 + fn*16 + lr; bv[fn] = bias[col[fn]]; }
#pragma unroll
  for (int fm=0; fm<4; ++fm){
#pragma unroll
    for (int j=0; j<4; ++j){
      int row = m0 + wm*64 + fm*16 + lh*4 + j;
      bool real = (row & 511) < NG;
#pragma unroll
      for (int fn=0; fn<4; ++fn){
        float v = fmaxf(acc[fm][fn][j] + bv[fn], 0.f);
        O[(size_t)row*HID + col[fn]] = f2bf(v);
        if (real){ cs[fn] += v; cq[fn] += v*v; }
      }
    }
  }
#pragma unroll
  for (int m=16; m<64; m<<=1){
#pragma unroll
    for (int fn=0; fn<4; ++fn){ cs[fn] += __shfl_xor(cs[fn], m); cq[fn] += __shfl_xor(cq[fn], m); }
  }
  if (lh == 0){
#pragma unroll
    for (int fn=0; fn<4; ++fn){
      atomicAdd(&stats[col[fn]], cs[fn]);
      atomicAdd(&stats[512+col[fn]], cq[fn]);
    }
  }
}

// ---------------- pooling, both branches in one dispatch ----------------
__global__ void pool2(const unsigned short* __restrict__ XC, const unsigned short* __restrict__ XO,
                      const int* __restrict__ batch, float* __restrict__ gc, float* __restrict__ go){
  int g = blockIdx.x;
  int t = threadIdx.x;
  const unsigned short* X = blockIdx.y ? XO : XC;
  float* out = blockIdx.y ? go : gc;
  int lo = 0, hi = NN;
  while (lo < hi){ int mid = (lo+hi) >> 1; if (batch[mid] < g) lo = mid+1; else hi = mid; }
  int s = lo;
  lo = 0; hi = NN;
  while (lo < hi){ int mid = (lo+hi) >> 1; if (batch[mid] < g+1) lo = mid+1; else hi = mid; }
  int e = lo;
  float a0 = 0.f, a1 = 0.f;
  for (int i=s; i<e; ++i){
    unsigned int v = *(const unsigned int*)&X[(size_t)i*HID + t*2];
    a0 += bf2f(v & 0xffffu); a1 += bf2f(v >> 16);
  }
  out[(size_t)g*HID + t*2]     = a0;
  out[(size_t)g*HID + t*2 + 1] = a1;
}

// ---------------- readout BN1: batched 3-branch stats ----------------
__global__ __launch_bounds__(256) void bnstats3(const float* __restrict__ gc, const float* __restrict__ go,
                                                const int* __restrict__ perm, float* __restrict__ partials){
  __shared__ float lds[256*9];
  int br = blockIdx.y;
  int t = threadIdx.x;
  int cid = t & 127, rid = t >> 7;
  float s[4]={0,0,0,0}, q[4]={0,0,0,0};
  const int rowsPer = (NG + NB3 - 1)/NB3;
  int r0 = blockIdx.x*rowsPer, r1 = r0 + rowsPer; if (r1 > NG) r1 = NG;
  for (int r = r0 + rid; r < r1; r += 2){
    float4 v;
    if (br == 0)      v = *(const float4*)&gc[(size_t)r*HID + cid*4];
    else if (br == 1) v = *(const float4*)&go[(size_t)r*HID + cid*4];
    else {
      int ps = perm[r];
      float4 a = *(const float4*)&gc[(size_t)ps*HID + cid*4];
      float4 b = *(const float4*)&go[(size_t)r*HID + cid*4];
      v = make_float4(a.x+b.x, a.y+b.y, a.z+b.z, a.w+b.w);
    }
    float e[4] = {v.x, v.y, v.z, v.w};
#pragma unroll
    for (int i=0;i<4;i++){ s[i]+=e[i]; q[i]+=e[i]*e[i]; }
  }
  int base = (rid*128 + cid)*9;
#pragma unroll
  for (int i=0;i<4;i++){ lds[base+i]=s[i]; lds[base+4+i]=q[i]; }
  __syncthreads();
  for (int o = t; o < 1024; o += 256){
    int issq = o >> 9, col = o & 511;
    int ci = col >> 2, i = col & 3;
    float acc = lds[(0*128 + ci)*9 + issq*4 + i] + lds[(1*128 + ci)*9 + issq*4 + i];
    partials[(size_t)(br*NB3 + blockIdx.x)*1024 + issq*512 + col] = acc;
  }
}

__global__ void bnfin3(const float* __restrict__ partials, float* __restrict__ mstat3){
  __shared__ float lds[4][64][2];
  int t = threadIdx.x;
  int cl = t & 63, ch = t >> 6;
  int c = blockIdx.x*64 + cl;
  int br = blockIdx.y;
  float s = 0.f, q = 0.f;
  for (int b = ch*8; b < ch*8 + 8; ++b){
    s += partials[(size_t)(br*NB3 + b)*1024 + c];
    q += partials[(size_t)(br*NB3 + b)*1024 + 512 + c];
  }
  lds[ch][cl][0] = s; lds[ch][cl][1] = q;
  __syncthreads();
  if (ch == 0){
    s = lds[0][cl][0]+lds[1][cl][0]+lds[2][cl][0]+lds[3][cl][0];
    q = lds[0][cl][1]+lds[1][cl][1]+lds[2][cl][1]+lds[3][cl][1];
    float m = s/(float)NG;
    float v = q/(float)NG - m*m;
    mstat3[br*1024 + c] = m;
    mstat3[br*1024 + 512 + c] = rsqrtf(v + 1e-5f);
  }
}

__global__ void bncast3(const float* __restrict__ gc, const float* __restrict__ go,
                        const int* __restrict__ perm, const float* __restrict__ mstat3,
                        unsigned short* __restrict__ out){
  int idx = blockIdx.x*blockDim.x + threadIdx.x;
  if (idx >= 1536*128) return;
  int r = idx >> 7;
  int cg = idx & 127;
  int br = r >> 9, lr = r & 511;
  ushort4v o;
  if (lr >= NG){ o[0]=0; o[1]=0; o[2]=0; o[3]=0; }
  else {
    float4 v;
    if (br == 0)      v = *(const float4*)&gc[(size_t)lr*HID + cg*4];
    else if (br == 1) v = *(const float4*)&go[(size_t)lr*HID + cg*4];
    else {
      int ps = perm[lr];
      float4 a = *(const float4*)&gc[(size_t)ps*HID + cg*4];
      float4 b = *(const float4*)&go[(size_t)lr*HID + cg*4];
      v = make_float4(a.x+b.x, a.y+b.y, a.z+b.z, a.w+b.w);
    }
    const float* ms = mstat3 + br*1024;
    int c = cg*4;
    o[0] = f2bf((v.x - ms[c+0])*ms[512+c+0] + 1e-4f);
    o[1] = f2bf((v.y - ms[c+1])*ms[512+c+1] + 1e-4f);
    o[2] = f2bf((v.z - ms[c+2])*ms[512+c+2] + 1e-4f);
    o[3] = f2bf((v.w - ms[c+3])*ms[512+c+3] + 1e-4f);
  }
  *(ushort4v*)&out[(size_t)r*HID + cg*4] = o;
}

// ---------------- final: batched BN2 -> fc2 -> log_softmax ----------------
struct ROP { const float* W2[3]; const float* b2[3]; };
__global__ void readout_final3(const unsigned short* __restrict__ T, const float* __restrict__ statsB,
                               float invM, ROP p, float* __restrict__ out){
  int g = blockIdx.x;
  int br = blockIdx.y;
  int l = threadIdx.x;
  const float* stats = statsB + br*1024;
  const float* W2 = p.W2[br];
  const float* b2 = p.b2[br];
  float acc[NCLS];
#pragma unroll
  for (int c=0; c<NCLS; ++c) acc[c] = 0.f;
  uint4 u = ((const uint4*)(T + (size_t)(br*512 + g)*HID))[l];
  float xv[8] = {bf2f(u.x&0xffffu), bf2f(u.x>>16), bf2f(u.y&0xffffu), bf2f(u.y>>16),
                 bf2f(u.z&0xffffu), bf2f(u.z>>16), bf2f(u.w&0xffffu), bf2f(u.w>>16)};
#pragma unroll
  for (int j=0; j<8; ++j){
    int k = l*8 + j;
    float m = stats[k]*invM;
    float rs = rsqrtf(stats[512+k]*invM - m*m + 1e-5f);
    float v = (xv[j] - m)*rs + 1e-4f;
#pragma unroll
    for (int c=0; c<NCLS; ++c) acc[c] += v * W2[k*NCLS + c];
  }
  for (int m=1; m<64; m<<=1){
#pragma unroll
    for (int c=0; c<NCLS; ++c) acc[c] += __shfl_xor(acc[c], m);
  }
  if (l == 0){
    float z[NCLS];
    float mx = -1e30f;
#pragma unroll
    for (int c=0; c<NCLS; ++c){ z[c] = acc[c] + b2[c]; mx = fmaxf(mx, z[c]); }
    float s = 0.f;
#pragma unroll
    for (int c=0; c<NCLS; ++c) s += expf(z[c]-mx);
    float lse = mx + logf(s);
#pragma unroll
    for (int c=0; c<NCLS; ++c) out[(size_t)(br*NG + g)*NCLS + c] = z[c] - lse;
  }
}

extern "C" void kernel_launch(void* const* d_in, const int* in_sizes, int n_in,
                              void* d_out, int out_size, void* d_ws, size_t ws_size,
                              hipStream_t stream){
  (void)in_sizes; (void)n_in; (void)out_size;
  const float* x      = (const float*)d_in[0];
  const int*   ei     = (const int*)d_in[1];
  const int*   batch  = (const int*)d_in[2];
  const int*   perm   = (const int*)d_in[3];
  const float* convfW = (const float*)d_in[4];
  const float* convfB = (const float*)d_in[5];
  const float* convsW = (const float*)d_in[6];
  const float* convsB = (const float*)d_in[7];
  const float* eattW  = (const float*)d_in[8];
  const float* eattB  = (const float*)d_in[9];
  const float* nattW  = (const float*)d_in[10];
  const float* nattB  = (const float*)d_in[11];
  const float* ctxW   = (const float*)d_in[12];
  const float* ctxB   = (const float*)d_in[13];
  const float* objW   = (const float*)d_in[14];
  const float* objB   = (const float*)d_in[15];
  const float* fc1W[3] = {(const float*)d_in[16], (const float*)d_in[20], (const float*)d_in[24]};
  const float* fc1B[3] = {(const float*)d_in[17], (const float*)d_in[21], (const float*)d_in[25]};
  const float* fc2W[3] = {(const float*)d_in[18], (const float*)d_in[22], (const float*)d_in[26]};
  const float* fc2B[3] = {(const float*)d_in[19], (const float*)d_in[23], (const float*)d_in[27]};
  float* out = (float*)d_out;

  char* p = (char*)d_ws;
  auto alloc = [&](size_t bytes)->char*{ char* r = p; p += (bytes + 255) & ~((size_t)255); return r; };
  const int T = NE + NN;
  unsigned short* Xbf = (unsigned short*)alloc((size_t)NN*HID*2);
  unsigned short* Gbf = (unsigned short*)alloc((size_t)NN*HID*2);
  unsigned short* GbfO= (unsigned short*)alloc((size_t)NN*HID*2);
  unsigned short* XbfO= (unsigned short*)alloc((size_t)NN*HID*2);
  unsigned short* Abf = (unsigned short*)alloc((size_t)NN*FIN*2);
  unsigned short* WtF = (unsigned short*)alloc((size_t)HID*FIN*2);
  unsigned short* WtL = (unsigned short*)alloc((size_t)3*HID*HID*2);
  unsigned short* WtC = (unsigned short*)alloc((size_t)HID*HID*2);
  unsigned short* WtO = (unsigned short*)alloc((size_t)HID*HID*2);
  unsigned short* WtR = (unsigned short*)alloc((size_t)3*HID*HID*2);
  int* cnt   = (int*)alloc((size_t)NN*4);
  int* fillc = (int*)alloc((size_t)NN*4);
  int* rowp  = (int*)alloc((size_t)(NN+1)*4);
  int* bsum  = (int*)alloc(32*4);
  int* ccol  = (int*)alloc((size_t)T*4);
  int* crow  = (int*)alloc((size_t)T*4);
  int* ceid  = (int*)alloc((size_t)T*4);
  int2* cw1  = (int2*)alloc((size_t)T*8);
  float* wcv = (float*)alloc((size_t)T*4);
  float* wov = (float*)alloc((size_t)T*4);
  float* dis1 = (float*)alloc((size_t)NN*4);
  float* degc = (float*)alloc((size_t)NN*4);
  float* dego = (float*)alloc((size_t)NN*4);
  float* Sc   = (float*)alloc((size_t)NN*4);
  float* So   = (float*)alloc((size_t)NN*4);
  float* stats6 = (float*)alloc(6*1024*4);
  float* mstat  = (float*)alloc(2*HID*4);
  float* mstatCO= (float*)alloc(2*1024*4);
  float* mstat3 = (float*)alloc(3*1024*4);
  float* na   = (float*)alloc((size_t)NN*2*4);
  float* eab  = (float*)alloc((size_t)NN*4*4);
  float* att  = (float*)alloc((size_t)NE*2*4);
  float* gc   = (float*)alloc((size_t)NG*HID*4);
  float* go   = (float*)alloc((size_t)NG*HID*4);
  float* part = (float*)alloc((size_t)BNG*2048*4);
  if ((size_t)(p - (char*)d_ws) > ws_size){
    sentinel_k<<<1,1,0,stream>>>(out);
    return;
  }
  unsigned short* Abf3 = Abf;
  unsigned short* Gbf3 = GbfO;
  const float invNN = 1.0f/(float)NN;
  const float invNG = 1.0f/(float)NG;
  const int GEMM_LDS = 128*136*2;   // 34816 B dynamic shared for gemm_bt

  // setup
  W2BT wp;
  wp.src[0]=convfW; wp.dst[0]=WtF;
  for (int i=0;i<3;i++){ wp.src[1+i]=convsW+(size_t)i*HID*HID; wp.dst[1+i]=WtL+(size_t)i*HID*HID; }
  wp.src[4]=ctxW; wp.dst[4]=WtC;
  wp.src[5]=objW; wp.dst[5]=WtO;
  for (int i=0;i<3;i++){ wp.src[6+i]=fc1W[i]; wp.dst[6+i]=WtR+(size_t)i*HID*HID; }
  setup_all<<<(FIN*HID + 8*HID*HID + 255)/256, 256, 0, stream>>>(wp, cnt, fillc, degc, dego, Sc, So, stats6);

  // CSR build
  csr_count<<<(NE+255)/256,256,0,stream>>>(ei, cnt);
  scan1<<<(NN+1023)/1024,1024,0,stream>>>(cnt, rowp, dis1, bsum);
  scan3<<<(NN+1023)/1024,1024,0,stream>>>(rowp, bsum);
  csr_fill<<<(T+255)/256,256,0,stream>>>(ei, rowp, cnt, fillc, dis1, ccol, crow, ceid, cw1);

  const int NBLK = ((NN+127)/128)*4;   // 628

  // conv_feat
  bnstats_p<<<BNG,1024,0,stream>>>(x, NN, FIN, part);
  bnfin_red<<<(FIN+63)/64,256,0,stream>>>(part, 2*FIN, 0, NN, FIN, mstat);
  bncast<<<((NN*FIN/4)+255)/256,256,0,stream>>>(x, mstat, NN, FIN, Abf);
  gemm_bt<<<NBLK,256,GEMM_LDS,stream>>>(Abf, WtF, Xbf, convfB, stats6, NN, FIN, 1,
                                        0, nullptr, nullptr, nullptr, nullptr);

  // 3 GCN layers
  for (int i=0;i<3;i++){
    aggregate_bn<<<NN/4,256,0,stream>>>(Xbf, rowp, cw1, stats6 + i*1024, invNN, Gbf);
    gemm_bt<<<NBLK,256,GEMM_LDS,stream>>>(Gbf, WtL+(size_t)i*HID*HID, Xbf,
                                          convsB+(size_t)i*HID,
                                          (i<2) ? (stats6 + (i+1)*1024) : nullptr,
                                          NN, HID, 1, 0, nullptr, nullptr, nullptr, nullptr);
  }

  // attention
  att_node<<<NN/4,256,0,stream>>>(Xbf, nattW, nattB, eattW, na, eab);
  att_edge<<<(NE+255)/256,256,0,stream>>>(ei, eab, eattB, att, degc, dego);
  wco_kernel<<<(T+255)/256,256,0,stream>>>(crow, ccol, ceid, att, degc, dego, na, wcv, wov, Sc, So);

  // ctx + obj: dual stats -> dual agg -> batched 2-problem GEMM -> 1 pool dispatch
  bnstats_dual<<<BNG,1024,0,stream>>>(Xbf, na, part);
  bnfin_red2<<<dim3(8,2),256,0,stream>>>(part, mstatCO);
  aggregate_dual<<<NN/4,256,0,stream>>>(Xbf, rowp, ccol, wcv, wov, Sc, So, mstatCO, Gbf, GbfO);
  gemm_bt<<<2*NBLK,256,GEMM_LDS,stream>>>(Gbf, WtC, Xbf, ctxB, nullptr, NN, HID, 1,
                                          NBLK, GbfO, WtO, XbfO, objB);
  pool2<<<dim3(NG,2),256,0,stream>>>(Xbf, XbfO, batch, gc, go);

  // readouts, batched across the 3 branches
  bnstats3<<<dim3(NB3,3),256,0,stream>>>(gc, go, perm, part);
  bnfin3<<<dim3(8,3),256,0,stream>>>(part, mstat3);
  bncast3<<<(1536*128+255)/256,256,0,stream>>>(gc, go, perm, mstat3, Abf3);
  FC1P fp;
  for (int i=0;i<3;i++){ fp.Bt[i] = WtR+(size_t)i*HID*HID; fp.bias[i] = fc1B[i]; }
  gemm_fc1<<<dim3(12,4),256,0,stream>>>(Abf3, fp, Gbf3, stats6 + 3*1024);
  ROP rp;
  for (int i=0;i<3;i++){ rp.W2[i] = fc2W[i]; rp.b2[i] = fc2B[i]; }
  readout_final3<<<dim3(NG,3),64,0,stream>>>(Gbf3, stats6 + 3*1024, invNG, rp, out);
}